// Round 10
// baseline (180.760 us; speedup 1.0000x reference)
//
#include <hip/hip_runtime.h>
#include <cstdint>

// ---------------------------------------------------------------------------
// SAGAN self-attention block, bf16-MFMA pipeline, flash-fused attention.
// GEMMs are NT form: C[m,n] = sum_k Arow[m][k] * Brow[n][k].
// Verified fragment conventions (R2-passing gemm, 16x16x32):
//   A-frag: lane holds A[row = lane&15][k = (lane>>4)*8 + q], q=0..7
//   B-frag: lane holds B[col = lane&15][k = (lane>>4)*8 + q]
//   C/D:    lane holds C[row = (lane>>4)*4 + r][col = lane&15], r=0..3
// For 16x16x16 (K=16): A/B k = (lane>>4)*4 + q, q=0..3 (2 VGPR) — pattern-
// consistent with the K-doubled shapes; C/D layout is shape-determined.
// ---------------------------------------------------------------------------

typedef short s8v __attribute__((ext_vector_type(8)));   // 8 bf16 bits (4 VGPR)
typedef short s4v __attribute__((ext_vector_type(4)));   // 4 bf16 bits (2 VGPR)
typedef float f32x4 __attribute__((ext_vector_type(4)));

#define DEVI static __device__ __forceinline__

DEVI unsigned short f2bf(float f) {
  union { float f; uint32_t u; } x; x.f = f;
  uint32_t u = x.u;
  return (unsigned short)((u + 0x7fffu + ((u >> 16) & 1u)) >> 16);  // RNE
}

DEVI f32x4 mfma16(s4v a, s4v b, f32x4 c) {
#if __has_builtin(__builtin_amdgcn_mfma_f32_16x16x16_bf16)
  return __builtin_amdgcn_mfma_f32_16x16x16_bf16(a, b, c, 0, 0, 0);
#elif __has_builtin(__builtin_amdgcn_mfma_f32_16x16x16bf16_1k)
  return __builtin_amdgcn_mfma_f32_16x16x16bf16_1k(a, b, c, 0, 0, 0);
#else
  asm("s_nop 1\n\tv_mfma_f32_16x16x16_bf16 %0, %1, %2, %0"
      : "+v"(c) : "v"(a), "v"(b));
  return c;
#endif
}

DEVI void gl_lds16(const void* g, void* l) {
  // async global->LDS, 16B per lane; LDS dest must be wave-uniform base.
  __builtin_amdgcn_global_load_lds(
      (const __attribute__((address_space(1))) void*)g,
      (__attribute__((address_space(3))) void*)l,
      16, 0, 0);
}

// Stage a [64 rows][32 k] bf16 tile (4KB), linear LDS layout (gemm_nt).
DEVI void stage(const unsigned short* src, int ld, unsigned short* lds, int t) {
  gl_lds16(src + (long)(t >> 2) * ld + (t & 3) * 8, lds + (t >> 6) * 512);
}

// ---------------------------------------------------------------------------
// NT GEMM: 128x128 tile, 4 waves (2x2), each wave 64x64 = 4x4 frags of
// 16x16x32 bf16 MFMA. (Unchanged from R2/R3 passing version.)
// ---------------------------------------------------------------------------
template <int OBF, int BIAS, int PEM, int SILU>
__global__ __launch_bounds__(256) void gemm_nt(
    const unsigned short* __restrict__ A, const unsigned short* __restrict__ B,
    void* __restrict__ Cp, int K, int N, int ld, long sA, long sB, long sC,
    const float* __restrict__ bias, const float* __restrict__ pe, float scale) {
  const int bz = blockIdx.z;
  const unsigned short* Ab = A + (long)bz * sA;
  const unsigned short* Bb = B + (long)bz * sB;
  const int m0 = blockIdx.x * 128, n0 = blockIdx.y * 128;
  __shared__ __align__(16) unsigned short As[4096], Bs[4096];  // [128][32]
  const int t = threadIdx.x;
  const int wave = t >> 6, lane = t & 63;
  const int wr = wave >> 1, wc = wave & 1;

  f32x4 acc[4][4];
#pragma unroll
  for (int i = 0; i < 4; i++)
#pragma unroll
    for (int j = 0; j < 4; j++) acc[i][j] = f32x4{0.f, 0.f, 0.f, 0.f};

  const int rl = lane & 15, kp = (lane >> 4) * 8;

  for (int k0 = 0; k0 < K; k0 += 32) {
    stage(Ab + (long)m0 * ld + k0, ld, As, t);
    stage(Ab + (long)(m0 + 64) * ld + k0, ld, As + 2048, t);
    stage(Bb + (long)n0 * ld + k0, ld, Bs, t);
    stage(Bb + (long)(n0 + 64) * ld + k0, ld, Bs + 2048, t);
    __syncthreads();  // drains vmcnt before barrier -> LDS valid

    s8v af[4], bfr[4];
#pragma unroll
    for (int i = 0; i < 4; i++)
      af[i] = *(const s8v*)(As + (wr * 64 + i * 16 + rl) * 32 + kp);
#pragma unroll
    for (int j = 0; j < 4; j++)
      bfr[j] = *(const s8v*)(Bs + (wc * 64 + j * 16 + rl) * 32 + kp);
#pragma unroll
    for (int i = 0; i < 4; i++)
#pragma unroll
      for (int j = 0; j < 4; j++)
        acc[i][j] = __builtin_amdgcn_mfma_f32_16x16x32_bf16(af[i], bfr[j],
                                                            acc[i][j], 0, 0, 0);
    __syncthreads();
  }

  const long cb = (long)bz * sC;
#pragma unroll
  for (int i = 0; i < 4; i++) {
    const int r0 = m0 + wr * 64 + i * 16 + (lane >> 4) * 4;
#pragma unroll
    for (int j = 0; j < 4; j++) {
      const int col = n0 + wc * 64 + j * 16 + (lane & 15);
#pragma unroll
      for (int r = 0; r < 4; r++) {
        const int row = r0 + r;
        float val = acc[i][j][r] * scale;
        if (BIAS == 1) val += bias[row];
        if (BIAS == 2) val += bias[col];
        if (PEM == 1) val += pe[(long)row * 4096 + col];
        if (PEM == 2) val += pe[(long)col * 4096 + row];
        if (SILU) val = val / (1.0f + __expf(-val));
        const long ci = cb + (long)row * N + col;
        if (OBF)
          ((unsigned short*)Cp)[ci] = f2bf(val);
        else
          ((float*)Cp)[ci] = val;
      }
    }
  }
}

// ---------------------------------------------------------------------------
// Flash-fused attention v7: v6 tiling (256 blocks, 128j x 2048i, 8 waves =
// (jq 0..3, ch 0..1): 32 j-rows, i-subhalf 32 of 64i tile) but P NEVER
// touches LDS:
//   QK swapped:  S^T = mfma32(A=Q_frag, B=K_frag)  -> lane holds
//                S[i = ch*32+if*16+4g+r][j = lane&15] (C rows = i).
//   PV via K=16: B-frag of mfma16 needs k = (lane>>4)*4+q  == the C-row
//                grouping, so pb[kk][jf] = pack4(exp2(sa[kk][jf][0..3])) is a
//                pure per-lane pack. A = V (ds_read_b64). O^T[c][j] in regs.
// One __syncthreads per iter; same staging/swizzle as v6; no pL, no mid
// chains. Epilogue: lsum butterfly over g (xor 16,32), ch-pair merge via LDS
// alias, fp32 O-partials + lsum partials (combine_o unchanged).
// ---------------------------------------------------------------------------
__global__ __launch_bounds__(512, 2) void flash_attn(
    const unsigned short* __restrict__ qTp, const unsigned short* __restrict__ kTp,
    const unsigned short* __restrict__ vBp, float* __restrict__ oPart,
    float* __restrict__ lPart) {
  const int bid = blockIdx.x;
  const int xcd = bid & 7;
  const int b = xcd >> 1, ihalf = xcd & 1;
  const int j0 = (bid >> 3) * 128;
  const long S = 1048576;
  const long ibase = (long)ihalf * 2048;
  const unsigned short* q = qTp + (long)b * S;
  const unsigned short* k = kTp + (long)b * S;
  const unsigned short* v = vBp + (long)b * S;
  const int ob = b * 2 + ihalf;  // output plane

  // LDS: [0,64K) qL dbuf, [64K,128K) vL dbuf.
  // Epilogue aliases: [0,128K) = O exchange (fp32), [128K,+512) = lsum exch.
  __shared__ __align__(16) unsigned char ldsb[131584];

  const int t = threadIdx.x;
  const int wave = t >> 6, lane = t & 63;
  const int jq = wave & 3, ch = wave >> 2;
  const int rl = lane & 15, g = lane >> 4;
  const int kp = g * 8;
  const int ksw = ((g ^ ((rl >> 1) & 3)) << 3);          // swizzled k-offset
  const int th = t >> 8, tt = t & 255;                   // staging split

  // K-strip -> registers (B-frag: col j = lane&15): wave rows j0+jq*32+jf*16.
  const unsigned short* krow = k + (long)(j0 + jq * 32 + rl) * 256 + kp;
  s8v kreg[2][8];
#pragma unroll
  for (int jf = 0; jf < 2; jf++)
#pragma unroll
    for (int s = 0; s < 8; s++)
      kreg[jf][s] = *(const s8v*)(krow + jf * 16 * 256 + s * 32);

  f32x4 oacc[16][2];  // O^T: [cf][jf], C rows = c = cf*16+4g+r, cols = j
#pragma unroll
  for (int cf = 0; cf < 16; cf++)
#pragma unroll
    for (int jf = 0; jf < 2; jf++) oacc[cf][jf] = f32x4{0.f, 0.f, 0.f, 0.f};
  float plsum[2] = {0.f, 0.f};

  // Pre-swizzled, pre-offset staging pointers (bumped per call; source
  // swizzle: slot chunk c holds global chunk c ^ ((row>>1)&3); LDS linear).
  const int tr = tt >> 2, tc = tt & 3;
  const int sc = (tc ^ ((tr >> 1) & 3)) * 8;
  const unsigned short* qsrc[4];
  const unsigned short* vsrc[4];
  const int dsto = (tt >> 6) * 512;  // wave-uniform LDS sub-offset
#pragma unroll
  for (int ss = 0; ss < 4; ss++) {
    const int s_ = ss * 2 + th;
    qsrc[ss] = q + ibase * 256 + s_ * 32 + (long)tr * 256 + sc;
    vsrc[ss] = v + (long)((s_ >> 1) * 64) * 4096 + ibase + (s_ & 1) * 32 +
               (long)tr * 4096 + sc;
  }

#define STAGE_QV(bufsel)                                                     \
  {                                                                          \
    unsigned short* qD = (unsigned short*)(ldsb + ((bufsel) << 15));         \
    unsigned short* vD = (unsigned short*)(ldsb + 65536 + ((bufsel) << 15)); \
    _Pragma("unroll") for (int ss = 0; ss < 4; ss++) {                       \
      const int s_ = ss * 2 + th;                                            \
      gl_lds16(qsrc[ss], qD + s_ * 2048 + dsto);                             \
      gl_lds16(vsrc[ss], vD + s_ * 2048 + dsto);                             \
      qsrc[ss] += 16384;  /* next i-tile: +64*256 elems */                   \
      vsrc[ss] += 64;     /* next i-tile: +64 elems     */                   \
    }                                                                        \
  }

  STAGE_QV(0)  // tile 0 -> buf 0

  for (int n = 0; n < 32; ++n) {
    const int cur = n & 1;
    __syncthreads();  // tile n staged in buf[cur]; buf[cur^1] free
    STAGE_QV(cur ^ 1)  // tile n+1 (n=31: redundant, never consumed)

    // QK^T swapped: sa[if][jf], A = Q (rows i), B = K (cols j).
    f32x4 sa[2][2];
#pragma unroll
    for (int f = 0; f < 2; f++)
#pragma unroll
      for (int jf = 0; jf < 2; jf++) sa[f][jf] = f32x4{0.f, 0.f, 0.f, 0.f};
    const unsigned short* qbase =
        (const unsigned short*)(ldsb + (cur << 15)) + (ch * 32 + rl) * 32 + ksw;
#pragma unroll
    for (int s = 0; s < 8; s++) {
#pragma unroll
      for (int f = 0; f < 2; f++) {
        s8v qf = *(const s8v*)(qbase + s * 2048 + f * 512);
        sa[f][0] = __builtin_amdgcn_mfma_f32_16x16x32_bf16(qf, kreg[0][s],
                                                           sa[f][0], 0, 0, 0);
        sa[f][1] = __builtin_amdgcn_mfma_f32_16x16x32_bf16(qf, kreg[1][s],
                                                           sa[f][1], 0, 0, 0);
      }
    }

    // Static-max softmax (|logit| << 88): p = 2^(s*0.0625*log2 e).
    // pb[kk][jf] = 4 bf16 = P rows (i = ch*32+kk*16+4g+0..3) at col j.
    s4v pb[2][2];
#pragma unroll
    for (int kk = 0; kk < 2; kk++)
#pragma unroll
      for (int jf = 0; jf < 2; jf++) {
        const float p0 = exp2f(sa[kk][jf][0] * 0.09016844005556021f);
        const float p1 = exp2f(sa[kk][jf][1] * 0.09016844005556021f);
        const float p2 = exp2f(sa[kk][jf][2] * 0.09016844005556021f);
        const float p3 = exp2f(sa[kk][jf][3] * 0.09016844005556021f);
        plsum[jf] += (p0 + p1) + (p2 + p3);
        s4v pk;
        pk[0] = (short)f2bf(p0); pk[1] = (short)f2bf(p1);
        pk[2] = (short)f2bf(p2); pk[3] = (short)f2bf(p3);
        pb[kk][jf] = pk;
      }

    // PV: O^T[c][j] += V[c][i16] x P[i16][j], two K=16 steps (kk).
    const unsigned short* vLb =
        (const unsigned short*)(ldsb + 65536 + (cur << 15));
#pragma unroll
    for (int cf = 0; cf < 16; cf++) {
      const int vrow = (cf >> 2) * 4096 + ch * 2048 + ((cf & 3) * 16 + rl) * 32;
#pragma unroll
      for (int kk = 0; kk < 2; kk++) {
        const int swz = (((2 * kk + (g >> 1)) ^ ((rl >> 1) & 3)) << 3) +
                        ((g & 1) << 2);
        s4v va = *(const s4v*)(vLb + vrow + swz);
        oacc[cf][0] = mfma16(va, pb[kk][0], oacc[cf][0]);
        oacc[cf][1] = mfma16(va, pb[kk][1], oacc[cf][1]);
      }
    }
  }
  asm volatile("s_nop 7\n\ts_nop 7");  // MFMA->VALU guard (asm fallback path)

  // Deferred lsum: butterfly over the 4 g-groups (cols j are lane&15).
#pragma unroll
  for (int jf = 0; jf < 2; jf++) {
    plsum[jf] += __shfl_xor(plsum[jf], 16);
    plsum[jf] += __shfl_xor(plsum[jf], 32);
  }

  // Merge ch-pairs (complementary i-subhalves) through LDS, then write
  // unnormalized O-partials + lsum partials (same outputs as before).
  __syncthreads();  // loop LDS dead; safe to alias
  float4* ex = (float4*)ldsb;           // [4 jq][32 j][64 c4]
  float* exl = (float*)(ldsb + 131072); // [4 jq][32 j]
  if (ch == 1) {
#pragma unroll
    for (int jf = 0; jf < 2; jf++) {
#pragma unroll
      for (int cf = 0; cf < 16; cf++)
        ex[jq * 2048 + (jf * 16 + rl) * 64 + cf * 4 + g] =
            float4{oacc[cf][jf][0], oacc[cf][jf][1], oacc[cf][jf][2],
                   oacc[cf][jf][3]};
      if (g == 0) exl[jq * 32 + jf * 16 + rl] = plsum[jf];
    }
  }
  __syncthreads();
  if (ch == 0) {
    float4* op4 = (float4*)(oPart + (long)ob * 1048576);
#pragma unroll
    for (int jf = 0; jf < 2; jf++) {
      const int jl = jq * 32 + jf * 16 + rl;
      if (g == 0)
        lPart[(long)ob * 4096 + j0 + jl] = plsum[jf] + exl[jl];
#pragma unroll
      for (int cf = 0; cf < 16; cf++) {
        const float4 o = ex[jq * 2048 + (jf * 16 + rl) * 64 + cf * 4 + g];
        op4[(long)(j0 + jl) * 64 + cf * 4 + g] =
            float4{oacc[cf][jf][0] + o.x, oacc[cf][jf][1] + o.y,
                   oacc[cf][jf][2] + o.z, oacc[cf][jf][3] + o.w};
      }
    }
  }
#undef STAGE_QV
}

// Combine the two i-half partials: rT[b][j][c] = (O0+O1)/(l0+l1) -> bf16.
__global__ __launch_bounds__(256) void combine_o(
    const float* __restrict__ oPart, const float* __restrict__ lPart,
    unsigned short* __restrict__ rT) {
  const long idx = (long)blockIdx.x * 256 + threadIdx.x;  // float4 units
  const int c4 = idx & 63;
  const int j = (idx >> 6) & 4095;
  const int b = idx >> 18;
  const long p0 = ((long)(b * 2) * 1048576 + (long)j * 256) / 4 + c4;
  const float4 a = ((const float4*)oPart)[p0];
  const float4 d = ((const float4*)oPart)[p0 + 262144];
  const float l = lPart[(long)(b * 2) * 4096 + j] +
                  lPart[(long)(b * 2 + 1) * 4096 + j];
  const float inv = 1.0f / l;
  ushort4 o;
  o.x = f2bf((a.x + d.x) * inv);
  o.y = f2bf((a.y + d.y) * inv);
  o.z = f2bf((a.z + d.z) * inv);
  o.w = f2bf((a.w + d.w) * inv);
  ((ushort4*)rT)[(long)b * 262144 + (long)j * 64 + c4] = o;
}

// Convert the six 256x256 fp32 weight matrices to bf16 (contiguous dst).
__global__ __launch_bounds__(256) void convert6(
    const float* __restrict__ a0, const float* __restrict__ a1,
    const float* __restrict__ a2, const float* __restrict__ a3,
    const float* __restrict__ a4, const float* __restrict__ a5,
    unsigned short* __restrict__ dst) {
  int idx = blockIdx.x * 256 + threadIdx.x;
  int m = idx >> 16, r = idx & 65535;
  const float* s;
  switch (m) {
    case 0: s = a0; break;
    case 1: s = a1; break;
    case 2: s = a2; break;
    case 3: s = a3; break;
    case 4: s = a4; break;
    default: s = a5; break;
  }
  dst[idx] = f2bf(s[r]);
}

// Sinusoidal table: embed[t,d] = sin/cos(t * 10000^(-d/128)), d even->sin.
__global__ __launch_bounds__(256) void embed_k(unsigned short* __restrict__ e) {
  int idx = blockIdx.x * 256 + threadIdx.x;
  int t = idx >> 8, d = idx & 255;
  float freq = powf(10000.0f, -(float)d * (1.0f / 128.0f));
  float w = (float)t * freq;
  float r = (d & 1) ? cosf(w) : sinf(w);
  e[idx] = f2bf(r);
}

// x [4][256][4096] fp32  ->  XT [4][4096][256] bf16
__global__ void transpose_x(const float* __restrict__ x,
                            unsigned short* __restrict__ xt) {
  __shared__ float tile[32][33];
  const int b = blockIdx.z;
  const int s0 = blockIdx.x * 32, c0 = blockIdx.y * 32;
  const int tx = threadIdx.x, ty = threadIdx.y;
  const float* xb = x + (long)b * 256 * 4096;
#pragma unroll
  for (int r = 0; r < 32; r += 8)
    tile[ty + r][tx] = xb[(long)(c0 + ty + r) * 4096 + s0 + tx];
  __syncthreads();
  unsigned short* xtb = xt + (long)b * 4096 * 256;
#pragma unroll
  for (int r = 0; r < 32; r += 8)
    xtb[(long)(s0 + ty + r) * 256 + c0 + tx] = f2bf(tile[tx][ty + r]);
}

// ---------------------------------------------------------------------------
extern "C" void kernel_launch(void* const* d_in, const int* in_sizes, int n_in,
                              void* d_out, int out_size, void* d_ws,
                              size_t ws_size, hipStream_t stream) {
  const float* x  = (const float*)d_in[0];
  const float* wq = (const float*)d_in[1];
  const float* bq = (const float*)d_in[2];
  const float* wk = (const float*)d_in[3];
  const float* bk = (const float*)d_in[4];
  const float* wv = (const float*)d_in[5];
  const float* bv = (const float*)d_in[6];
  const float* wo = (const float*)d_in[7];
  const float* bo = (const float*)d_in[8];
  const float* w1 = (const float*)d_in[9];
  const float* b1 = (const float*)d_in[10];
  const float* w2 = (const float*)d_in[11];
  const float* b2 = (const float*)d_in[12];
  float* out = (float*)d_out;

  char* ws = (char*)d_ws;
  unsigned short* wqb = (unsigned short*)(ws + 0);         // 6x 256x256 bf16
  unsigned short* wkb = (unsigned short*)(ws + 131072);
  unsigned short* wvb = (unsigned short*)(ws + 262144);
  unsigned short* wob = (unsigned short*)(ws + 393216);
  unsigned short* w1b = (unsigned short*)(ws + 524288);
  unsigned short* w2b = (unsigned short*)(ws + 655360);
  unsigned short* emb = (unsigned short*)(ws + 786432);    // [4096][256] bf16
  unsigned short* h1b = (unsigned short*)(ws + 2883584);   // [4096][256] bf16
  float*          peF = (float*)(ws + 4980736);            // [4096][256] fp32
  unsigned short* XT  = (unsigned short*)(ws + 9175040);   // [4][4096][256]
  unsigned short* qT  = (unsigned short*)(ws + 17563648);  // [4][4096][256]
  unsigned short* kT  = (unsigned short*)(ws + 25952256);  // [4][4096][256]
  unsigned short* vB  = (unsigned short*)(ws + 34340864);  // [4][256][4096]
  unsigned short* rT  = (unsigned short*)(ws + 42729472);  // [4][4096][256]
  float*          oP  = (float*)(ws + 51118080);           // [8][4096][256] f32
  float*          lP  = (float*)(ws + 84672512);           // [8][4096] f32
  (void)ws_size; (void)in_sizes; (void)n_in; (void)out_size;

  const dim3 B256(256);
  const long S = 1048576;  // 4096*256 (= 256*4096) element batch stride

  convert6<<<1536, B256, 0, stream>>>(wq, wk, wv, wo, w1, w2, wqb);
  embed_k<<<4096, B256, 0, stream>>>(emb);
  // pe MLP: h1 = silu(embed @ w1^T + b1); peF = h1 @ w2^T + b2  (fp32 out)
  gemm_nt<1, 2, 0, 1><<<dim3(32, 2, 1), B256, 0, stream>>>(
      emb, w1b, h1b, 256, 256, 256, 0, 0, 0, b1, nullptr, 1.0f);
  gemm_nt<0, 2, 0, 0><<<dim3(32, 2, 1), B256, 0, stream>>>(
      h1b, w2b, peF, 256, 256, 256, 0, 0, 0, b2, nullptr, 1.0f);
  transpose_x<<<dim3(128, 8, 4), dim3(32, 8), 0, stream>>>(x, XT);
  // qT[s,o] = XT.wq + bq[o] + pe[o*4096+s]   (pe mode 2: col-major index)
  gemm_nt<1, 2, 2, 0><<<dim3(32, 2, 4), B256, 0, stream>>>(
      XT, wqb, qT, 256, 256, 256, S, 0, S, bq, peF, 1.0f);
  gemm_nt<1, 2, 2, 0><<<dim3(32, 2, 4), B256, 0, stream>>>(
      XT, wkb, kT, 256, 256, 256, S, 0, S, bk, peF, 1.0f);
  // v[o,s] = wv.XT + bv[o] + pe[o*4096+s]    (pe mode 1: row-major index)
  gemm_nt<1, 1, 1, 0><<<dim3(2, 32, 4), B256, 0, stream>>>(
      wvb, XT, vB, 256, 4096, 256, 0, S, S, bv, peF, 1.0f);

  // Fused attention: logits + softmax(axis i) + PV; i split across 2 blocks.
  flash_attn<<<256, dim3(512), 0, stream>>>(qT, kT, vB, oP, lP);
  combine_o<<<4096, B256, 0, stream>>>(oP, lP, rT);

  // out[o,s] = wout . resT + b_out[o]  (fp32 -> d_out)
  gemm_nt<0, 1, 0, 0><<<dim3(2, 32, 4), B256, 0, stream>>>(
      wob, rT, out, 256, 4096, 256, 0, S, S, bo, nullptr, 1.0f);
}

// Round 11
// 167.223 us; speedup vs baseline: 1.0809x; 1.0809x over previous
//
#include <hip/hip_runtime.h>
#include <cstdint>

// ---------------------------------------------------------------------------
// SAGAN self-attention block, bf16-MFMA pipeline, flash-fused attention.
// GEMMs are NT form: C[m,n] = sum_k Arow[m][k] * Brow[n][k].
// Verified fragment conventions (R2-passing gemm, 16x16x32):
//   A-frag: lane holds A[row = lane&15][k = (lane>>4)*8 + q], q=0..7
//   B-frag: lane holds B[col = lane&15][k = (lane>>4)*8 + q]
//   C/D:    lane holds C[row = (lane>>4)*4 + r][col = lane&15], r=0..3
// ---------------------------------------------------------------------------

typedef short s8v __attribute__((ext_vector_type(8)));   // 8 bf16 bits (4 VGPR)
typedef float f32x4 __attribute__((ext_vector_type(4)));
typedef unsigned int u32x2 __attribute__((ext_vector_type(2)));
typedef unsigned int u32x4 __attribute__((ext_vector_type(4)));

#define DEVI static __device__ __forceinline__

DEVI unsigned short f2bf(float f) {
  union { float f; uint32_t u; } x; x.f = f;
  uint32_t u = x.u;
  return (unsigned short)((u + 0x7fffu + ((u >> 16) & 1u)) >> 16);  // RNE
}

// v_permlane32_swap_b32: a' = [a(0:31)|b(0:31)], b' = [a(32:63)|b(32:63)].
DEVI void pl32swap(uint32_t& a, uint32_t& b) {
#if __has_builtin(__builtin_amdgcn_permlane32_swap)
  u32x2 r = __builtin_amdgcn_permlane32_swap(a, b, false, false);
  a = r[0]; b = r[1];
#else
  asm("v_permlane32_swap_b32 %0, %1" : "+v"(a), "+v"(b));
#endif
}

DEVI void gl_lds16(const void* g, void* l) {
  // async global->LDS, 16B per lane; LDS dest must be wave-uniform base.
  __builtin_amdgcn_global_load_lds(
      (const __attribute__((address_space(1))) void*)g,
      (__attribute__((address_space(3))) void*)l,
      16, 0, 0);
}

// Stage a [64 rows][32 k] bf16 tile (4KB), linear LDS layout (gemm_nt).
DEVI void stage(const unsigned short* src, int ld, unsigned short* lds, int t) {
  gl_lds16(src + (long)(t >> 2) * ld + (t & 3) * 8, lds + (t >> 6) * 512);
}

// ---------------------------------------------------------------------------
// NT GEMM: 128x128 tile, 4 waves (2x2), each wave 64x64 = 4x4 frags of
// 16x16x32 bf16 MFMA. (Unchanged from R2/R3 passing version.)
// ---------------------------------------------------------------------------
template <int OBF, int BIAS, int PEM, int SILU>
__global__ __launch_bounds__(256) void gemm_nt(
    const unsigned short* __restrict__ A, const unsigned short* __restrict__ B,
    void* __restrict__ Cp, int K, int N, int ld, long sA, long sB, long sC,
    const float* __restrict__ bias, const float* __restrict__ pe, float scale) {
  const int bz = blockIdx.z;
  const unsigned short* Ab = A + (long)bz * sA;
  const unsigned short* Bb = B + (long)bz * sB;
  const int m0 = blockIdx.x * 128, n0 = blockIdx.y * 128;
  __shared__ __align__(16) unsigned short As[4096], Bs[4096];  // [128][32]
  const int t = threadIdx.x;
  const int wave = t >> 6, lane = t & 63;
  const int wr = wave >> 1, wc = wave & 1;

  f32x4 acc[4][4];
#pragma unroll
  for (int i = 0; i < 4; i++)
#pragma unroll
    for (int j = 0; j < 4; j++) acc[i][j] = f32x4{0.f, 0.f, 0.f, 0.f};

  const int rl = lane & 15, kp = (lane >> 4) * 8;

  for (int k0 = 0; k0 < K; k0 += 32) {
    stage(Ab + (long)m0 * ld + k0, ld, As, t);
    stage(Ab + (long)(m0 + 64) * ld + k0, ld, As + 2048, t);
    stage(Bb + (long)n0 * ld + k0, ld, Bs, t);
    stage(Bb + (long)(n0 + 64) * ld + k0, ld, Bs + 2048, t);
    __syncthreads();  // drains vmcnt before barrier -> LDS valid

    s8v af[4], bfr[4];
#pragma unroll
    for (int i = 0; i < 4; i++)
      af[i] = *(const s8v*)(As + (wr * 64 + i * 16 + rl) * 32 + kp);
#pragma unroll
    for (int j = 0; j < 4; j++)
      bfr[j] = *(const s8v*)(Bs + (wc * 64 + j * 16 + rl) * 32 + kp);
#pragma unroll
    for (int i = 0; i < 4; i++)
#pragma unroll
      for (int j = 0; j < 4; j++)
        acc[i][j] = __builtin_amdgcn_mfma_f32_16x16x32_bf16(af[i], bfr[j],
                                                            acc[i][j], 0, 0, 0);
    __syncthreads();
  }

  const long cb = (long)bz * sC;
#pragma unroll
  for (int i = 0; i < 4; i++) {
    const int r0 = m0 + wr * 64 + i * 16 + (lane >> 4) * 4;
#pragma unroll
    for (int j = 0; j < 4; j++) {
      const int col = n0 + wc * 64 + j * 16 + (lane & 15);
#pragma unroll
      for (int r = 0; r < 4; r++) {
        const int row = r0 + r;
        float val = acc[i][j][r] * scale;
        if (BIAS == 1) val += bias[row];
        if (BIAS == 2) val += bias[col];
        if (PEM == 1) val += pe[(long)row * 4096 + col];
        if (PEM == 2) val += pe[(long)col * 4096 + row];
        if (SILU) val = val / (1.0f + __expf(-val));
        const long ci = cb + (long)row * N + col;
        if (OBF)
          ((unsigned short*)Cp)[ci] = f2bf(val);
        else
          ((float*)Cp)[ci] = val;
      }
    }
  }
}

// ---------------------------------------------------------------------------
// Fused q+k projections: same structure as gemm_nt (BIAS=2, PEM=2, OBF=1)
// but ONE staging of the A (XT) tile feeds both weight matrices.
// qT[s,o] = XT[s,:].wq[o,:] + bq[o] + pe[o*4096+s]; same for k.
// ---------------------------------------------------------------------------
__global__ __launch_bounds__(256) void gemm_qk(
    const unsigned short* __restrict__ XT, const unsigned short* __restrict__ wqb,
    const unsigned short* __restrict__ wkb, unsigned short* __restrict__ qT,
    unsigned short* __restrict__ kT, const float* __restrict__ bq,
    const float* __restrict__ bk, const float* __restrict__ pe) {
  const int bz = blockIdx.z;
  const unsigned short* Ab = XT + (long)bz * 1048576;
  const int m0 = blockIdx.x * 128, n0 = blockIdx.y * 128;
  __shared__ __align__(16) unsigned short As[4096], Bq[4096], Bk[4096];
  const int t = threadIdx.x;
  const int wave = t >> 6, lane = t & 63;
  const int wr = wave >> 1, wc = wave & 1;

  f32x4 aq[4][4], ak[4][4];
#pragma unroll
  for (int i = 0; i < 4; i++)
#pragma unroll
    for (int j = 0; j < 4; j++) {
      aq[i][j] = f32x4{0.f, 0.f, 0.f, 0.f};
      ak[i][j] = f32x4{0.f, 0.f, 0.f, 0.f};
    }

  const int rl = lane & 15, kp = (lane >> 4) * 8;

  for (int k0 = 0; k0 < 256; k0 += 32) {
    stage(Ab + (long)m0 * 256 + k0, 256, As, t);
    stage(Ab + (long)(m0 + 64) * 256 + k0, 256, As + 2048, t);
    stage(wqb + (long)n0 * 256 + k0, 256, Bq, t);
    stage(wqb + (long)(n0 + 64) * 256 + k0, 256, Bq + 2048, t);
    stage(wkb + (long)n0 * 256 + k0, 256, Bk, t);
    stage(wkb + (long)(n0 + 64) * 256 + k0, 256, Bk + 2048, t);
    __syncthreads();

    s8v af[4], bq4[4], bk4[4];
#pragma unroll
    for (int i = 0; i < 4; i++)
      af[i] = *(const s8v*)(As + (wr * 64 + i * 16 + rl) * 32 + kp);
#pragma unroll
    for (int j = 0; j < 4; j++) {
      bq4[j] = *(const s8v*)(Bq + (wc * 64 + j * 16 + rl) * 32 + kp);
      bk4[j] = *(const s8v*)(Bk + (wc * 64 + j * 16 + rl) * 32 + kp);
    }
#pragma unroll
    for (int i = 0; i < 4; i++)
#pragma unroll
      for (int j = 0; j < 4; j++) {
        aq[i][j] = __builtin_amdgcn_mfma_f32_16x16x32_bf16(af[i], bq4[j],
                                                           aq[i][j], 0, 0, 0);
        ak[i][j] = __builtin_amdgcn_mfma_f32_16x16x32_bf16(af[i], bk4[j],
                                                           ak[i][j], 0, 0, 0);
      }
    __syncthreads();
  }

  const long cb = (long)bz * 1048576;
#pragma unroll
  for (int i = 0; i < 4; i++) {
    const int r0 = m0 + wr * 64 + i * 16 + (lane >> 4) * 4;
#pragma unroll
    for (int j = 0; j < 4; j++) {
      const int col = n0 + wc * 64 + j * 16 + (lane & 15);
#pragma unroll
      for (int r = 0; r < 4; r++) {
        const int row = r0 + r;
        const float p = pe[(long)col * 4096 + row];
        qT[cb + (long)row * 256 + col] = f2bf(aq[i][j][r] + bq[col] + p);
        kT[cb + (long)row * 256 + col] = f2bf(ak[i][j][r] + bk[col] + p);
      }
    }
  }
}

// ---------------------------------------------------------------------------
// Flash-fused attention v8: R8/v5 base (256 blocks x 512 thr; block =
// (jblk, ihalf, b) = 128 j x 2048 i; wave = (jq,ch) = 32 j-rows, i-subhalf;
// one __syncthreads/iter; dbuf staging w/ pre-swizzled sources) but P stays
// IN REGISTERS:
//   QK swapped: S^T = mfma32(A=Q, B=kreg); A-frag q-rows loaded BIT-SWAPPED
//   (bs: bit2<->bit3 of rl) which relabels i as i = 16kk + 4*[0,2,1,3][g]+r.
//   Under that labeling, v_permlane32_swap_b32(pd[kk0], pd[kk1]) directly
//   yields the PV B-frag halves: a'=[lo|lo] -> k 8g'+0..3, b'=[hi|hi] ->
//   k 8g'+4..7, consistent with V's A-frag k = i (identity).
//   PV: O^T[c][j] = mfma32(A=V b128 reads (R8 pattern), B=P) -> oacc[cf][jf].
// No P LDS traffic, no write->lgkmcnt->read chain, K=32 PV (32 MFMA).
// ---------------------------------------------------------------------------
__global__ __launch_bounds__(512, 2) void flash_attn(
    const unsigned short* __restrict__ qTp, const unsigned short* __restrict__ kTp,
    const unsigned short* __restrict__ vBp, float* __restrict__ oPart,
    float* __restrict__ lPart) {
  const int bid = blockIdx.x;
  const int xcd = bid & 7;
  const int b = xcd >> 1, ihalf = xcd & 1;
  const int j0 = (bid >> 3) * 128;
  const long S = 1048576;
  const long ibase = (long)ihalf * 2048;
  const unsigned short* q = qTp + (long)b * S;
  const unsigned short* k = kTp + (long)b * S;
  const unsigned short* v = vBp + (long)b * S;
  const int ob = b * 2 + ihalf;  // output plane

  // LDS: [0,64K) qL dbuf, [64K,128K) vL dbuf.
  // Epilogue aliases: [0,128K) = O exchange (fp32), [128K,+512) = lsum exch.
  __shared__ __align__(16) unsigned char ldsb[131584];

  const int t = threadIdx.x;
  const int wave = t >> 6, lane = t & 63;
  const int jq = wave & 3, ch = wave >> 2;
  const int rl = lane & 15, g = lane >> 4;
  const int kp = g * 8;
  const int ksw = ((g ^ ((rl >> 1) & 3)) << 3);   // swizzled k-off (row=rl)
  const int qrow = (rl & 3) | ((rl & 4) << 1) | ((rl & 8) >> 1);  // bs(rl)
  const int kswq = ((g ^ ((qrow >> 1) & 3)) << 3);
  const int th = t >> 8, tt = t & 255;            // staging split

  // K-strip -> registers (B-frag: col j = rl): wave rows j0 + jq*32 + jf*16.
  const unsigned short* krow = k + (long)(j0 + jq * 32 + rl) * 256 + kp;
  s8v kreg[2][8];
#pragma unroll
  for (int jf = 0; jf < 2; jf++)
#pragma unroll
    for (int s = 0; s < 8; s++)
      kreg[jf][s] = *(const s8v*)(krow + jf * 16 * 256 + s * 32);

  f32x4 oacc[16][2];  // O^T: rows c = cf*16+4g+r, cols j = jq*32+jf*16+rl
#pragma unroll
  for (int cf = 0; cf < 16; cf++)
#pragma unroll
    for (int jf = 0; jf < 2; jf++) oacc[cf][jf] = f32x4{0.f, 0.f, 0.f, 0.f};
  float plsum[2] = {0.f, 0.f};

  // Pre-swizzled, pre-offset staging pointers (bumped per call; source
  // swizzle: slot chunk c holds global chunk c ^ ((row>>1)&3); LDS linear).
  const int tr = tt >> 2, tc = tt & 3;
  const int sc = (tc ^ ((tr >> 1) & 3)) * 8;
  const unsigned short* qsrc[4];
  const unsigned short* vsrc[4];
  const int dsto = (tt >> 6) * 512;  // wave-uniform LDS sub-offset
#pragma unroll
  for (int ss = 0; ss < 4; ss++) {
    const int s_ = ss * 2 + th;
    qsrc[ss] = q + ibase * 256 + s_ * 32 + (long)tr * 256 + sc;
    vsrc[ss] = v + (long)((s_ >> 1) * 64) * 4096 + ibase + (s_ & 1) * 32 +
               (long)tr * 4096 + sc;
  }

#define STAGE_QV(bufsel)                                                     \
  {                                                                          \
    unsigned short* qD = (unsigned short*)(ldsb + ((bufsel) << 15));         \
    unsigned short* vD = (unsigned short*)(ldsb + 65536 + ((bufsel) << 15)); \
    _Pragma("unroll") for (int ss = 0; ss < 4; ss++) {                       \
      const int s_ = ss * 2 + th;                                            \
      gl_lds16(qsrc[ss], qD + s_ * 2048 + dsto);                             \
      gl_lds16(vsrc[ss], vD + s_ * 2048 + dsto);                             \
      qsrc[ss] += 16384;  /* next i-tile: +64*256 elems */                   \
      vsrc[ss] += 64;     /* next i-tile: +64 elems     */                   \
    }                                                                        \
  }

  STAGE_QV(0)  // tile 0 -> buf 0

  for (int n = 0; n < 32; ++n) {
    const int cur = n & 1;
    __syncthreads();  // tile n staged in buf[cur]; buf[cur^1] free
    STAGE_QV(cur ^ 1)  // tile n+1 (n=31: redundant, never consumed)

    // QK^T swapped: sa[kk][jf]; A = Q (bit-swapped rows), B = kreg.
    f32x4 sa[2][2];
#pragma unroll
    for (int kk = 0; kk < 2; kk++)
#pragma unroll
      for (int jf = 0; jf < 2; jf++) sa[kk][jf] = f32x4{0.f, 0.f, 0.f, 0.f};
    const unsigned short* qbase =
        (const unsigned short*)(ldsb + (cur << 15)) +
        (ch * 32 + qrow) * 32 + kswq;
#pragma unroll
    for (int s = 0; s < 8; s++) {
      s8v qf0 = *(const s8v*)(qbase + s * 2048);
      s8v qf1 = *(const s8v*)(qbase + s * 2048 + 512);
      sa[0][0] = __builtin_amdgcn_mfma_f32_16x16x32_bf16(qf0, kreg[0][s],
                                                         sa[0][0], 0, 0, 0);
      sa[0][1] = __builtin_amdgcn_mfma_f32_16x16x32_bf16(qf0, kreg[1][s],
                                                         sa[0][1], 0, 0, 0);
      sa[1][0] = __builtin_amdgcn_mfma_f32_16x16x32_bf16(qf1, kreg[0][s],
                                                         sa[1][0], 0, 0, 0);
      sa[1][1] = __builtin_amdgcn_mfma_f32_16x16x32_bf16(qf1, kreg[1][s],
                                                         sa[1][1], 0, 0, 0);
    }

    // Static-max softmax (|logit| << 88): p = 2^(s * 0.0625*log2 e).
    uint32_t pd[2][2][2];
#pragma unroll
    for (int kk = 0; kk < 2; kk++)
#pragma unroll
      for (int jf = 0; jf < 2; jf++) {
        const float p0 = exp2f(sa[kk][jf][0] * 0.09016844005556021f);
        const float p1 = exp2f(sa[kk][jf][1] * 0.09016844005556021f);
        const float p2 = exp2f(sa[kk][jf][2] * 0.09016844005556021f);
        const float p3 = exp2f(sa[kk][jf][3] * 0.09016844005556021f);
        plsum[jf] += (p0 + p1) + (p2 + p3);
        pd[kk][jf][0] = (uint32_t)f2bf(p0) | ((uint32_t)f2bf(p1) << 16);
        pd[kk][jf][1] = (uint32_t)f2bf(p2) | ((uint32_t)f2bf(p3) << 16);
      }

    // Cross-half exchange -> PV B-frags (2 permlane32_swap per jf).
    s8v pB[2];
#pragma unroll
    for (int jf = 0; jf < 2; jf++) {
      uint32_t a0 = pd[0][jf][0], b0 = pd[1][jf][0];
      uint32_t a1 = pd[0][jf][1], b1 = pd[1][jf][1];
      pl32swap(a0, b0);
      pl32swap(a1, b1);
      u32x4 w4 = {a0, a1, b0, b1};
      pB[jf] = __builtin_bit_cast(s8v, w4);
    }

    // PV: O^T[c][j] += V x P, K=32; A = V (b128, R8's exact read pattern).
    const unsigned short* vbase =
        (const unsigned short*)(ldsb + 65536 + (cur << 15)) + ch * 2048 +
        rl * 32 + ksw;
#pragma unroll
    for (int cf = 0; cf < 16; cf++) {
      s8v vb = *(const s8v*)(vbase + (cf >> 2) * 4096 + (cf & 3) * 512);
      oacc[cf][0] = __builtin_amdgcn_mfma_f32_16x16x32_bf16(vb, pB[0],
                                                            oacc[cf][0], 0, 0, 0);
      oacc[cf][1] = __builtin_amdgcn_mfma_f32_16x16x32_bf16(vb, pB[1],
                                                            oacc[cf][1], 0, 0, 0);
    }
  }

  // Deferred lsum: butterfly over the 4 g-groups (cols j are lane&15).
#pragma unroll
  for (int jf = 0; jf < 2; jf++) {
    plsum[jf] += __shfl_xor(plsum[jf], 16);
    plsum[jf] += __shfl_xor(plsum[jf], 32);
  }

  // Merge ch-pairs (complementary i-subhalves) through LDS, then write
  // unnormalized O-partials + lsum partials (same outputs as before).
  __syncthreads();  // loop LDS dead; safe to alias
  float4* ex = (float4*)ldsb;           // [4 jq][32 j][64 c4]
  float* exl = (float*)(ldsb + 131072); // [4 jq][32 j]
  if (ch == 1) {
#pragma unroll
    for (int jf = 0; jf < 2; jf++) {
#pragma unroll
      for (int cf = 0; cf < 16; cf++)
        ex[jq * 2048 + (jf * 16 + rl) * 64 + cf * 4 + g] =
            float4{oacc[cf][jf][0], oacc[cf][jf][1], oacc[cf][jf][2],
                   oacc[cf][jf][3]};
      if (g == 0) exl[jq * 32 + jf * 16 + rl] = plsum[jf];
    }
  }
  __syncthreads();
  if (ch == 0) {
    float4* op4 = (float4*)(oPart + (long)ob * 1048576);
#pragma unroll
    for (int jf = 0; jf < 2; jf++) {
      const int jl = jq * 32 + jf * 16 + rl;
      if (g == 0)
        lPart[(long)ob * 4096 + j0 + jl] = plsum[jf] + exl[jl];
#pragma unroll
      for (int cf = 0; cf < 16; cf++) {
        const float4 o = ex[jq * 2048 + (jf * 16 + rl) * 64 + cf * 4 + g];
        op4[(long)(j0 + jl) * 64 + cf * 4 + g] =
            float4{oacc[cf][jf][0] + o.x, oacc[cf][jf][1] + o.y,
                   oacc[cf][jf][2] + o.z, oacc[cf][jf][3] + o.w};
      }
    }
  }
#undef STAGE_QV
}

// Combine the two i-half partials: rT[b][j][c] = (O0+O1)/(l0+l1) -> bf16.
__global__ __launch_bounds__(256) void combine_o(
    const float* __restrict__ oPart, const float* __restrict__ lPart,
    unsigned short* __restrict__ rT) {
  const long idx = (long)blockIdx.x * 256 + threadIdx.x;  // float4 units
  const int c4 = idx & 63;
  const int j = (idx >> 6) & 4095;
  const int b = idx >> 18;
  const long p0 = ((long)(b * 2) * 1048576 + (long)j * 256) / 4 + c4;
  const float4 a = ((const float4*)oPart)[p0];
  const float4 d = ((const float4*)oPart)[p0 + 262144];
  const float l = lPart[(long)(b * 2) * 4096 + j] +
                  lPart[(long)(b * 2 + 1) * 4096 + j];
  const float inv = 1.0f / l;
  ushort4 o;
  o.x = f2bf((a.x + d.x) * inv);
  o.y = f2bf((a.y + d.y) * inv);
  o.z = f2bf((a.z + d.z) * inv);
  o.w = f2bf((a.w + d.w) * inv);
  ((ushort4*)rT)[(long)b * 262144 + (long)j * 64 + c4] = o;
}

// Convert the six 256x256 fp32 weight matrices to bf16 (contiguous dst).
__global__ __launch_bounds__(256) void convert6(
    const float* __restrict__ a0, const float* __restrict__ a1,
    const float* __restrict__ a2, const float* __restrict__ a3,
    const float* __restrict__ a4, const float* __restrict__ a5,
    unsigned short* __restrict__ dst) {
  int idx = blockIdx.x * 256 + threadIdx.x;
  int m = idx >> 16, r = idx & 65535;
  const float* s;
  switch (m) {
    case 0: s = a0; break;
    case 1: s = a1; break;
    case 2: s = a2; break;
    case 3: s = a3; break;
    case 4: s = a4; break;
    default: s = a5; break;
  }
  dst[idx] = f2bf(s[r]);
}

// Sinusoidal table: embed[t,d] = sin/cos(t * 10000^(-d/128)), d even->sin.
__global__ __launch_bounds__(256) void embed_k(unsigned short* __restrict__ e) {
  int idx = blockIdx.x * 256 + threadIdx.x;
  int t = idx >> 8, d = idx & 255;
  float freq = powf(10000.0f, -(float)d * (1.0f / 128.0f));
  float w = (float)t * freq;
  float r = (d & 1) ? cosf(w) : sinf(w);
  e[idx] = f2bf(r);
}

// x [4][256][4096] fp32  ->  XT [4][4096][256] bf16
__global__ void transpose_x(const float* __restrict__ x,
                            unsigned short* __restrict__ xt) {
  __shared__ float tile[32][33];
  const int b = blockIdx.z;
  const int s0 = blockIdx.x * 32, c0 = blockIdx.y * 32;
  const int tx = threadIdx.x, ty = threadIdx.y;
  const float* xb = x + (long)b * 256 * 4096;
#pragma unroll
  for (int r = 0; r < 32; r += 8)
    tile[ty + r][tx] = xb[(long)(c0 + ty + r) * 4096 + s0 + tx];
  __syncthreads();
  unsigned short* xtb = xt + (long)b * 4096 * 256;
#pragma unroll
  for (int r = 0; r < 32; r += 8)
    xtb[(long)(s0 + ty + r) * 256 + c0 + tx] = f2bf(tile[tx][ty + r]);
}

// ---------------------------------------------------------------------------
extern "C" void kernel_launch(void* const* d_in, const int* in_sizes, int n_in,
                              void* d_out, int out_size, void* d_ws,
                              size_t ws_size, hipStream_t stream) {
  const float* x  = (const float*)d_in[0];
  const float* wq = (const float*)d_in[1];
  const float* bq = (const float*)d_in[2];
  const float* wk = (const float*)d_in[3];
  const float* bk = (const float*)d_in[4];
  const float* wv = (const float*)d_in[5];
  const float* bv = (const float*)d_in[6];
  const float* wo = (const float*)d_in[7];
  const float* bo = (const float*)d_in[8];
  const float* w1 = (const float*)d_in[9];
  const float* b1 = (const float*)d_in[10];
  const float* w2 = (const float*)d_in[11];
  const float* b2 = (const float*)d_in[12];
  float* out = (float*)d_out;

  char* ws = (char*)d_ws;
  unsigned short* wqb = (unsigned short*)(ws + 0);         // 6x 256x256 bf16
  unsigned short* wkb = (unsigned short*)(ws + 131072);
  unsigned short* wvb = (unsigned short*)(ws + 262144);
  unsigned short* wob = (unsigned short*)(ws + 393216);
  unsigned short* w1b = (unsigned short*)(ws + 524288);
  unsigned short* w2b = (unsigned short*)(ws + 655360);
  unsigned short* emb = (unsigned short*)(ws + 786432);    // [4096][256] bf16
  unsigned short* h1b = (unsigned short*)(ws + 2883584);   // [4096][256] bf16
  float*          peF = (float*)(ws + 4980736);            // [4096][256] fp32
  unsigned short* XT  = (unsigned short*)(ws + 9175040);   // [4][4096][256]
  unsigned short* qT  = (unsigned short*)(ws + 17563648);  // [4][4096][256]
  unsigned short* kT  = (unsigned short*)(ws + 25952256);  // [4][4096][256]
  unsigned short* vB  = (unsigned short*)(ws + 34340864);  // [4][256][4096]
  unsigned short* rT  = (unsigned short*)(ws + 42729472);  // [4][4096][256]
  float*          oP  = (float*)(ws + 51118080);           // [8][4096][256] f32
  float*          lP  = (float*)(ws + 84672512);           // [8][4096] f32
  (void)ws_size; (void)in_sizes; (void)n_in; (void)out_size;

  const dim3 B256(256);
  const long S = 1048576;  // 4096*256 (= 256*4096) element batch stride

  convert6<<<1536, B256, 0, stream>>>(wq, wk, wv, wo, w1, w2, wqb);
  embed_k<<<4096, B256, 0, stream>>>(emb);
  // pe MLP: h1 = silu(embed @ w1^T + b1); peF = h1 @ w2^T + b2  (fp32 out)
  gemm_nt<1, 2, 0, 1><<<dim3(32, 2, 1), B256, 0, stream>>>(
      emb, w1b, h1b, 256, 256, 256, 0, 0, 0, b1, nullptr, 1.0f);
  gemm_nt<0, 2, 0, 0><<<dim3(32, 2, 1), B256, 0, stream>>>(
      h1b, w2b, peF, 256, 256, 256, 0, 0, 0, b2, nullptr, 1.0f);
  transpose_x<<<dim3(128, 8, 4), dim3(32, 8), 0, stream>>>(x, XT);
  // Fused q+k projections (shared XT staging).
  gemm_qk<<<dim3(32, 2, 4), B256, 0, stream>>>(XT, wqb, wkb, qT, kT, bq, bk,
                                               peF);
  // v[o,s] = wv.XT + bv[o] + pe[o*4096+s]    (pe mode 1: row-major index)
  gemm_nt<1, 1, 1, 0><<<dim3(2, 32, 4), B256, 0, stream>>>(
      wvb, XT, vB, 256, 4096, 256, 0, S, S, bv, peF, 1.0f);

  // Fused attention: logits + softmax(axis i) + PV; i split across 2 blocks.
  flash_attn<<<256, dim3(512), 0, stream>>>(qT, kT, vB, oP, lP);
  combine_o<<<4096, B256, 0, stream>>>(oP, lP, rT);

  // out[o,s] = wout . resT + b_out[o]  (fp32 -> d_out)
  gemm_nt<0, 1, 0, 0><<<dim3(2, 32, 4), B256, 0, stream>>>(
      wob, rT, out, 256, 4096, 256, 0, S, S, bo, nullptr, 1.0f);
}

// Round 12
// 162.050 us; speedup vs baseline: 1.1155x; 1.0319x over previous
//
#include <hip/hip_runtime.h>
#include <cstdint>

// ---------------------------------------------------------------------------
// SAGAN self-attention block, bf16-MFMA pipeline, flash-fused attention.
// GEMMs are NT form: C[m,n] = sum_k Arow[m][k] * Brow[n][k].
// Verified fragment conventions (R2-passing gemm, 16x16x32):
//   A-frag: lane holds A[row = lane&15][k = (lane>>4)*8 + q], q=0..7
//   B-frag: lane holds B[col = lane&15][k = (lane>>4)*8 + q]
//   C/D:    lane holds C[row = (lane>>4)*4 + r][col = lane&15], r=0..3
// ---------------------------------------------------------------------------

typedef short s8v __attribute__((ext_vector_type(8)));   // 8 bf16 bits (4 VGPR)
typedef float f32x4 __attribute__((ext_vector_type(4)));
typedef unsigned int u32x2 __attribute__((ext_vector_type(2)));
typedef unsigned int u32x4 __attribute__((ext_vector_type(4)));

#define DEVI static __device__ __forceinline__

DEVI unsigned short f2bf(float f) {
  union { float f; uint32_t u; } x; x.f = f;
  uint32_t u = x.u;
  return (unsigned short)((u + 0x7fffu + ((u >> 16) & 1u)) >> 16);  // RNE
}

// v_permlane32_swap_b32: a' = [a(0:31)|b(0:31)], b' = [a(32:63)|b(32:63)].
DEVI void pl32swap(uint32_t& a, uint32_t& b) {
#if __has_builtin(__builtin_amdgcn_permlane32_swap)
  u32x2 r = __builtin_amdgcn_permlane32_swap(a, b, false, false);
  a = r[0]; b = r[1];
#else
  asm("v_permlane32_swap_b32 %0, %1" : "+v"(a), "+v"(b));
#endif
}

DEVI void gl_lds16(const void* g, void* l) {
  // async global->LDS, 16B per lane; LDS dest must be wave-uniform base.
  __builtin_amdgcn_global_load_lds(
      (const __attribute__((address_space(1))) void*)g,
      (__attribute__((address_space(3))) void*)l,
      16, 0, 0);
}

// Stage a [64 rows][32 k] bf16 tile (4KB), linear LDS layout (gemm_nt).
DEVI void stage(const unsigned short* src, int ld, unsigned short* lds, int t) {
  gl_lds16(src + (long)(t >> 2) * ld + (t & 3) * 8, lds + (t >> 6) * 512);
}

// ---------------------------------------------------------------------------
// NT GEMM: 128x128 tile, 4 waves (2x2), each wave 64x64 = 4x4 frags of
// 16x16x32 bf16 MFMA. (Unchanged from R2/R3 passing version.)
// ---------------------------------------------------------------------------
template <int OBF, int BIAS, int PEM, int SILU>
__global__ __launch_bounds__(256) void gemm_nt(
    const unsigned short* __restrict__ A, const unsigned short* __restrict__ B,
    void* __restrict__ Cp, int K, int N, int ld, long sA, long sB, long sC,
    const float* __restrict__ bias, const float* __restrict__ pe, float scale) {
  const int bz = blockIdx.z;
  const unsigned short* Ab = A + (long)bz * sA;
  const unsigned short* Bb = B + (long)bz * sB;
  const int m0 = blockIdx.x * 128, n0 = blockIdx.y * 128;
  __shared__ __align__(16) unsigned short As[4096], Bs[4096];  // [128][32]
  const int t = threadIdx.x;
  const int wave = t >> 6, lane = t & 63;
  const int wr = wave >> 1, wc = wave & 1;

  f32x4 acc[4][4];
#pragma unroll
  for (int i = 0; i < 4; i++)
#pragma unroll
    for (int j = 0; j < 4; j++) acc[i][j] = f32x4{0.f, 0.f, 0.f, 0.f};

  const int rl = lane & 15, kp = (lane >> 4) * 8;

  for (int k0 = 0; k0 < K; k0 += 32) {
    stage(Ab + (long)m0 * ld + k0, ld, As, t);
    stage(Ab + (long)(m0 + 64) * ld + k0, ld, As + 2048, t);
    stage(Bb + (long)n0 * ld + k0, ld, Bs, t);
    stage(Bb + (long)(n0 + 64) * ld + k0, ld, Bs + 2048, t);
    __syncthreads();  // drains vmcnt before barrier -> LDS valid

    s8v af[4], bfr[4];
#pragma unroll
    for (int i = 0; i < 4; i++)
      af[i] = *(const s8v*)(As + (wr * 64 + i * 16 + rl) * 32 + kp);
#pragma unroll
    for (int j = 0; j < 4; j++)
      bfr[j] = *(const s8v*)(Bs + (wc * 64 + j * 16 + rl) * 32 + kp);
#pragma unroll
    for (int i = 0; i < 4; i++)
#pragma unroll
      for (int j = 0; j < 4; j++)
        acc[i][j] = __builtin_amdgcn_mfma_f32_16x16x32_bf16(af[i], bfr[j],
                                                            acc[i][j], 0, 0, 0);
    __syncthreads();
  }

  const long cb = (long)bz * sC;
#pragma unroll
  for (int i = 0; i < 4; i++) {
    const int r0 = m0 + wr * 64 + i * 16 + (lane >> 4) * 4;
#pragma unroll
    for (int j = 0; j < 4; j++) {
      const int col = n0 + wc * 64 + j * 16 + (lane & 15);
#pragma unroll
      for (int r = 0; r < 4; r++) {
        const int row = r0 + r;
        float val = acc[i][j][r] * scale;
        if (BIAS == 1) val += bias[row];
        if (BIAS == 2) val += bias[col];
        if (PEM == 1) val += pe[(long)row * 4096 + col];
        if (PEM == 2) val += pe[(long)col * 4096 + row];
        if (SILU) val = val / (1.0f + __expf(-val));
        const long ci = cb + (long)row * N + col;
        if (OBF)
          ((unsigned short*)Cp)[ci] = f2bf(val);
        else
          ((float*)Cp)[ci] = val;
      }
    }
  }
}

// ---------------------------------------------------------------------------
// Fused q+k projections: same structure as gemm_nt (BIAS=2, PEM=2, OBF=1)
// but ONE staging of the A (XT) tile feeds both weight matrices.
// ---------------------------------------------------------------------------
__global__ __launch_bounds__(256) void gemm_qk(
    const unsigned short* __restrict__ XT, const unsigned short* __restrict__ wqb,
    const unsigned short* __restrict__ wkb, unsigned short* __restrict__ qT,
    unsigned short* __restrict__ kT, const float* __restrict__ bq,
    const float* __restrict__ bk, const float* __restrict__ pe) {
  const int bz = blockIdx.z;
  const unsigned short* Ab = XT + (long)bz * 1048576;
  const int m0 = blockIdx.x * 128, n0 = blockIdx.y * 128;
  __shared__ __align__(16) unsigned short As[4096], Bq[4096], Bk[4096];
  const int t = threadIdx.x;
  const int wave = t >> 6, lane = t & 63;
  const int wr = wave >> 1, wc = wave & 1;

  f32x4 aq[4][4], ak[4][4];
#pragma unroll
  for (int i = 0; i < 4; i++)
#pragma unroll
    for (int j = 0; j < 4; j++) {
      aq[i][j] = f32x4{0.f, 0.f, 0.f, 0.f};
      ak[i][j] = f32x4{0.f, 0.f, 0.f, 0.f};
    }

  const int rl = lane & 15, kp = (lane >> 4) * 8;

  for (int k0 = 0; k0 < 256; k0 += 32) {
    stage(Ab + (long)m0 * 256 + k0, 256, As, t);
    stage(Ab + (long)(m0 + 64) * 256 + k0, 256, As + 2048, t);
    stage(wqb + (long)n0 * 256 + k0, 256, Bq, t);
    stage(wqb + (long)(n0 + 64) * 256 + k0, 256, Bq + 2048, t);
    stage(wkb + (long)n0 * 256 + k0, 256, Bk, t);
    stage(wkb + (long)(n0 + 64) * 256 + k0, 256, Bk + 2048, t);
    __syncthreads();

    s8v af[4], bq4[4], bk4[4];
#pragma unroll
    for (int i = 0; i < 4; i++)
      af[i] = *(const s8v*)(As + (wr * 64 + i * 16 + rl) * 32 + kp);
#pragma unroll
    for (int j = 0; j < 4; j++) {
      bq4[j] = *(const s8v*)(Bq + (wc * 64 + j * 16 + rl) * 32 + kp);
      bk4[j] = *(const s8v*)(Bk + (wc * 64 + j * 16 + rl) * 32 + kp);
    }
#pragma unroll
    for (int i = 0; i < 4; i++)
#pragma unroll
      for (int j = 0; j < 4; j++) {
        aq[i][j] = __builtin_amdgcn_mfma_f32_16x16x32_bf16(af[i], bq4[j],
                                                           aq[i][j], 0, 0, 0);
        ak[i][j] = __builtin_amdgcn_mfma_f32_16x16x32_bf16(af[i], bk4[j],
                                                           ak[i][j], 0, 0, 0);
      }
    __syncthreads();
  }

  const long cb = (long)bz * 1048576;
#pragma unroll
  for (int i = 0; i < 4; i++) {
    const int r0 = m0 + wr * 64 + i * 16 + (lane >> 4) * 4;
#pragma unroll
    for (int j = 0; j < 4; j++) {
      const int col = n0 + wc * 64 + j * 16 + (lane & 15);
#pragma unroll
      for (int r = 0; r < 4; r++) {
        const int row = r0 + r;
        const float p = pe[(long)col * 4096 + row];
        qT[cb + (long)row * 256 + col] = f2bf(aq[i][j][r] + bq[col] + p);
        kT[cb + (long)row * 256 + col] = f2bf(ak[i][j][r] + bk[col] + p);
      }
    }
  }
}

// ---------------------------------------------------------------------------
// Output projection with FUSED i-half combine: B rows are built on the fly
// from the two oPart planes + lPart (resT[j][c] = (O0+O1)[j][c] / (l0+l1)[j])
// and written to LDS in the exact linear layout the verified B-frag reads
// expect. A (wob) keeps the gl_lds path. Replaces combine_o + gemm_nt.
// out[o][s] = sum_c wob[o][c] * resT[s][c] + bo[o]  (fp32 -> d_out)
// ---------------------------------------------------------------------------
__global__ __launch_bounds__(256) void gemm_out_f(
    const unsigned short* __restrict__ wob, const float* __restrict__ oPart,
    const float* __restrict__ lPart, const float* __restrict__ bo,
    float* __restrict__ out) {
  const int bz = blockIdx.z;  // batch
  const int m0 = blockIdx.x * 128, n0 = blockIdx.y * 128;  // o rows, j cols
  __shared__ __align__(16) unsigned short As[4096], Bs[4096];
  const int t = threadIdx.x;
  const int wave = t >> 6, lane = t & 63;
  const int wr = wave >> 1, wc = wave & 1;

  f32x4 acc[4][4];
#pragma unroll
  for (int i = 0; i < 4; i++)
#pragma unroll
    for (int j = 0; j < 4; j++) acc[i][j] = f32x4{0.f, 0.f, 0.f, 0.f};

  const int rl = lane & 15, kp = (lane >> 4) * 8;
  const int tr = t >> 2, tc8 = (t & 3) * 8;  // staging row/col-chunk

  // Per-thread fixed B rows (j) across the whole k-loop: hoist inv(lsum).
  const int j0_ = n0 + tr, j1_ = n0 + 64 + tr;
  const float* l0p = lPart + (long)(bz * 2) * 4096;
  const float* l1p = lPart + (long)(bz * 2 + 1) * 4096;
  const float inv0 = 1.0f / (l0p[j0_] + l1p[j0_]);
  const float inv1 = 1.0f / (l0p[j1_] + l1p[j1_]);
  const float* oP0 = oPart + (long)(bz * 2) * 1048576;
  const float* oP1 = oPart + (long)(bz * 2 + 1) * 1048576;

  for (int k0 = 0; k0 < 256; k0 += 32) {
    stage(wob + (long)m0 * 256 + k0, 256, As, t);
    stage(wob + (long)(m0 + 64) * 256 + k0, 256, As + 2048, t);
    // B fold: resT rows j0_/j1_, c-chunk [k0+tc8, +8) from 2 fp32 planes.
#pragma unroll
    for (int h = 0; h < 2; h++) {
      const int j = h ? j1_ : j0_;
      const float inv = h ? inv1 : inv0;
      const float4* a4 = (const float4*)(oP0 + (long)j * 256 + k0 + tc8);
      const float4* d4 = (const float4*)(oP1 + (long)j * 256 + k0 + tc8);
      const float4 a0 = a4[0], a1 = a4[1], d0 = d4[0], d1 = d4[1];
      s8v pk;
      pk[0] = (short)f2bf((a0.x + d0.x) * inv);
      pk[1] = (short)f2bf((a0.y + d0.y) * inv);
      pk[2] = (short)f2bf((a0.z + d0.z) * inv);
      pk[3] = (short)f2bf((a0.w + d0.w) * inv);
      pk[4] = (short)f2bf((a1.x + d1.x) * inv);
      pk[5] = (short)f2bf((a1.y + d1.y) * inv);
      pk[6] = (short)f2bf((a1.z + d1.z) * inv);
      pk[7] = (short)f2bf((a1.w + d1.w) * inv);
      *(s8v*)(Bs + h * 2048 + tr * 32 + tc8) = pk;
    }
    __syncthreads();  // drains vmcnt (A gl_lds) + lgkmcnt (B ds_write)

    s8v af[4], bfr[4];
#pragma unroll
    for (int i = 0; i < 4; i++)
      af[i] = *(const s8v*)(As + (wr * 64 + i * 16 + rl) * 32 + kp);
#pragma unroll
    for (int j = 0; j < 4; j++)
      bfr[j] = *(const s8v*)(Bs + (wc * 64 + j * 16 + rl) * 32 + kp);
#pragma unroll
    for (int i = 0; i < 4; i++)
#pragma unroll
      for (int j = 0; j < 4; j++)
        acc[i][j] = __builtin_amdgcn_mfma_f32_16x16x32_bf16(af[i], bfr[j],
                                                            acc[i][j], 0, 0, 0);
    __syncthreads();
  }

  const long cb = (long)bz * 1048576;
#pragma unroll
  for (int i = 0; i < 4; i++) {
    const int r0 = m0 + wr * 64 + i * 16 + (lane >> 4) * 4;
#pragma unroll
    for (int j = 0; j < 4; j++) {
      const int col = n0 + wc * 64 + j * 16 + (lane & 15);
#pragma unroll
      for (int r = 0; r < 4; r++) {
        const int row = r0 + r;
        out[cb + (long)row * 4096 + col] = acc[i][j][r] + bo[row];
      }
    }
  }
}

// ---------------------------------------------------------------------------
// Flash-fused attention v8 (FROZEN from R11; structural plateau ~97 us):
// in-register P via bit-swapped Q rows + permlane32_swap; K=32 PV.
// ---------------------------------------------------------------------------
__global__ __launch_bounds__(512, 2) void flash_attn(
    const unsigned short* __restrict__ qTp, const unsigned short* __restrict__ kTp,
    const unsigned short* __restrict__ vBp, float* __restrict__ oPart,
    float* __restrict__ lPart) {
  const int bid = blockIdx.x;
  const int xcd = bid & 7;
  const int b = xcd >> 1, ihalf = xcd & 1;
  const int j0 = (bid >> 3) * 128;
  const long S = 1048576;
  const long ibase = (long)ihalf * 2048;
  const unsigned short* q = qTp + (long)b * S;
  const unsigned short* k = kTp + (long)b * S;
  const unsigned short* v = vBp + (long)b * S;
  const int ob = b * 2 + ihalf;  // output plane

  __shared__ __align__(16) unsigned char ldsb[131584];

  const int t = threadIdx.x;
  const int wave = t >> 6, lane = t & 63;
  const int jq = wave & 3, ch = wave >> 2;
  const int rl = lane & 15, g = lane >> 4;
  const int kp = g * 8;
  const int ksw = ((g ^ ((rl >> 1) & 3)) << 3);   // swizzled k-off (row=rl)
  const int qrow = (rl & 3) | ((rl & 4) << 1) | ((rl & 8) >> 1);  // bs(rl)
  const int kswq = ((g ^ ((qrow >> 1) & 3)) << 3);
  const int th = t >> 8, tt = t & 255;            // staging split

  const unsigned short* krow = k + (long)(j0 + jq * 32 + rl) * 256 + kp;
  s8v kreg[2][8];
#pragma unroll
  for (int jf = 0; jf < 2; jf++)
#pragma unroll
    for (int s = 0; s < 8; s++)
      kreg[jf][s] = *(const s8v*)(krow + jf * 16 * 256 + s * 32);

  f32x4 oacc[16][2];  // O^T: rows c = cf*16+4g+r, cols j = jq*32+jf*16+rl
#pragma unroll
  for (int cf = 0; cf < 16; cf++)
#pragma unroll
    for (int jf = 0; jf < 2; jf++) oacc[cf][jf] = f32x4{0.f, 0.f, 0.f, 0.f};
  float plsum[2] = {0.f, 0.f};

  const int tr = tt >> 2, tc = tt & 3;
  const int sc = (tc ^ ((tr >> 1) & 3)) * 8;
  const unsigned short* qsrc[4];
  const unsigned short* vsrc[4];
  const int dsto = (tt >> 6) * 512;  // wave-uniform LDS sub-offset
#pragma unroll
  for (int ss = 0; ss < 4; ss++) {
    const int s_ = ss * 2 + th;
    qsrc[ss] = q + ibase * 256 + s_ * 32 + (long)tr * 256 + sc;
    vsrc[ss] = v + (long)((s_ >> 1) * 64) * 4096 + ibase + (s_ & 1) * 32 +
               (long)tr * 4096 + sc;
  }

#define STAGE_QV(bufsel)                                                     \
  {                                                                          \
    unsigned short* qD = (unsigned short*)(ldsb + ((bufsel) << 15));         \
    unsigned short* vD = (unsigned short*)(ldsb + 65536 + ((bufsel) << 15)); \
    _Pragma("unroll") for (int ss = 0; ss < 4; ss++) {                       \
      const int s_ = ss * 2 + th;                                            \
      gl_lds16(qsrc[ss], qD + s_ * 2048 + dsto);                             \
      gl_lds16(vsrc[ss], vD + s_ * 2048 + dsto);                             \
      qsrc[ss] += 16384;                                                     \
      vsrc[ss] += 64;                                                        \
    }                                                                        \
  }

  STAGE_QV(0)

  for (int n = 0; n < 32; ++n) {
    const int cur = n & 1;
    __syncthreads();
    STAGE_QV(cur ^ 1)

    f32x4 sa[2][2];
#pragma unroll
    for (int kk = 0; kk < 2; kk++)
#pragma unroll
      for (int jf = 0; jf < 2; jf++) sa[kk][jf] = f32x4{0.f, 0.f, 0.f, 0.f};
    const unsigned short* qbase =
        (const unsigned short*)(ldsb + (cur << 15)) +
        (ch * 32 + qrow) * 32 + kswq;
#pragma unroll
    for (int s = 0; s < 8; s++) {
      s8v qf0 = *(const s8v*)(qbase + s * 2048);
      s8v qf1 = *(const s8v*)(qbase + s * 2048 + 512);
      sa[0][0] = __builtin_amdgcn_mfma_f32_16x16x32_bf16(qf0, kreg[0][s],
                                                         sa[0][0], 0, 0, 0);
      sa[0][1] = __builtin_amdgcn_mfma_f32_16x16x32_bf16(qf0, kreg[1][s],
                                                         sa[0][1], 0, 0, 0);
      sa[1][0] = __builtin_amdgcn_mfma_f32_16x16x32_bf16(qf1, kreg[0][s],
                                                         sa[1][0], 0, 0, 0);
      sa[1][1] = __builtin_amdgcn_mfma_f32_16x16x32_bf16(qf1, kreg[1][s],
                                                         sa[1][1], 0, 0, 0);
    }

    uint32_t pd[2][2][2];
#pragma unroll
    for (int kk = 0; kk < 2; kk++)
#pragma unroll
      for (int jf = 0; jf < 2; jf++) {
        const float p0 = exp2f(sa[kk][jf][0] * 0.09016844005556021f);
        const float p1 = exp2f(sa[kk][jf][1] * 0.09016844005556021f);
        const float p2 = exp2f(sa[kk][jf][2] * 0.09016844005556021f);
        const float p3 = exp2f(sa[kk][jf][3] * 0.09016844005556021f);
        plsum[jf] += (p0 + p1) + (p2 + p3);
        pd[kk][jf][0] = (uint32_t)f2bf(p0) | ((uint32_t)f2bf(p1) << 16);
        pd[kk][jf][1] = (uint32_t)f2bf(p2) | ((uint32_t)f2bf(p3) << 16);
      }

    s8v pB[2];
#pragma unroll
    for (int jf = 0; jf < 2; jf++) {
      uint32_t a0 = pd[0][jf][0], b0 = pd[1][jf][0];
      uint32_t a1 = pd[0][jf][1], b1 = pd[1][jf][1];
      pl32swap(a0, b0);
      pl32swap(a1, b1);
      u32x4 w4 = {a0, a1, b0, b1};
      pB[jf] = __builtin_bit_cast(s8v, w4);
    }

    const unsigned short* vbase =
        (const unsigned short*)(ldsb + 65536 + (cur << 15)) + ch * 2048 +
        rl * 32 + ksw;
#pragma unroll
    for (int cf = 0; cf < 16; cf++) {
      s8v vb = *(const s8v*)(vbase + (cf >> 2) * 4096 + (cf & 3) * 512);
      oacc[cf][0] = __builtin_amdgcn_mfma_f32_16x16x32_bf16(vb, pB[0],
                                                            oacc[cf][0], 0, 0, 0);
      oacc[cf][1] = __builtin_amdgcn_mfma_f32_16x16x32_bf16(vb, pB[1],
                                                            oacc[cf][1], 0, 0, 0);
    }
  }

#pragma unroll
  for (int jf = 0; jf < 2; jf++) {
    plsum[jf] += __shfl_xor(plsum[jf], 16);
    plsum[jf] += __shfl_xor(plsum[jf], 32);
  }

  __syncthreads();  // loop LDS dead; safe to alias
  float4* ex = (float4*)ldsb;           // [4 jq][32 j][64 c4]
  float* exl = (float*)(ldsb + 131072); // [4 jq][32 j]
  if (ch == 1) {
#pragma unroll
    for (int jf = 0; jf < 2; jf++) {
#pragma unroll
      for (int cf = 0; cf < 16; cf++)
        ex[jq * 2048 + (jf * 16 + rl) * 64 + cf * 4 + g] =
            float4{oacc[cf][jf][0], oacc[cf][jf][1], oacc[cf][jf][2],
                   oacc[cf][jf][3]};
      if (g == 0) exl[jq * 32 + jf * 16 + rl] = plsum[jf];
    }
  }
  __syncthreads();
  if (ch == 0) {
    float4* op4 = (float4*)(oPart + (long)ob * 1048576);
#pragma unroll
    for (int jf = 0; jf < 2; jf++) {
      const int jl = jq * 32 + jf * 16 + rl;
      if (g == 0)
        lPart[(long)ob * 4096 + j0 + jl] = plsum[jf] + exl[jl];
#pragma unroll
      for (int cf = 0; cf < 16; cf++) {
        const float4 o = ex[jq * 2048 + (jf * 16 + rl) * 64 + cf * 4 + g];
        op4[(long)(j0 + jl) * 64 + cf * 4 + g] =
            float4{oacc[cf][jf][0] + o.x, oacc[cf][jf][1] + o.y,
                   oacc[cf][jf][2] + o.z, oacc[cf][jf][3] + o.w};
      }
    }
  }
#undef STAGE_QV
}

// Convert the six 256x256 fp32 weight matrices to bf16 (contiguous dst).
__global__ __launch_bounds__(256) void convert6(
    const float* __restrict__ a0, const float* __restrict__ a1,
    const float* __restrict__ a2, const float* __restrict__ a3,
    const float* __restrict__ a4, const float* __restrict__ a5,
    unsigned short* __restrict__ dst) {
  int idx = blockIdx.x * 256 + threadIdx.x;
  int m = idx >> 16, r = idx & 65535;
  const float* s;
  switch (m) {
    case 0: s = a0; break;
    case 1: s = a1; break;
    case 2: s = a2; break;
    case 3: s = a3; break;
    case 4: s = a4; break;
    default: s = a5; break;
  }
  dst[idx] = f2bf(s[r]);
}

// Sinusoidal table: embed[t,d] = sin/cos(t * 10000^(-d/128)), d even->sin.
// powf -> exp2f identity; __sincosf fast path.
__global__ __launch_bounds__(256) void embed_k(unsigned short* __restrict__ e) {
  int idx = blockIdx.x * 256 + threadIdx.x;
  int t = idx >> 8, d = idx & 255;
  // 10000^(-d/128) = 2^(-d * log2(10000)/128), log2(10000)/128 = 0.103810253
  float freq = exp2f((float)d * -0.10381025296573598f);
  float w = (float)t * freq;
  float s, c;
  __sincosf(w, &s, &c);
  e[idx] = f2bf((d & 1) ? c : s);
}

// x [4][256][4096] fp32  ->  XT [4][4096][256] bf16
__global__ void transpose_x(const float* __restrict__ x,
                            unsigned short* __restrict__ xt) {
  __shared__ float tile[32][33];
  const int b = blockIdx.z;
  const int s0 = blockIdx.x * 32, c0 = blockIdx.y * 32;
  const int tx = threadIdx.x, ty = threadIdx.y;
  const float* xb = x + (long)b * 256 * 4096;
#pragma unroll
  for (int r = 0; r < 32; r += 8)
    tile[ty + r][tx] = xb[(long)(c0 + ty + r) * 4096 + s0 + tx];
  __syncthreads();
  unsigned short* xtb = xt + (long)b * 4096 * 256;
#pragma unroll
  for (int r = 0; r < 32; r += 8)
    xtb[(long)(s0 + ty + r) * 256 + c0 + tx] = f2bf(tile[tx][ty + r]);
}

// ---------------------------------------------------------------------------
extern "C" void kernel_launch(void* const* d_in, const int* in_sizes, int n_in,
                              void* d_out, int out_size, void* d_ws,
                              size_t ws_size, hipStream_t stream) {
  const float* x  = (const float*)d_in[0];
  const float* wq = (const float*)d_in[1];
  const float* bq = (const float*)d_in[2];
  const float* wk = (const float*)d_in[3];
  const float* bk = (const float*)d_in[4];
  const float* wv = (const float*)d_in[5];
  const float* bv = (const float*)d_in[6];
  const float* wo = (const float*)d_in[7];
  const float* bo = (const float*)d_in[8];
  const float* w1 = (const float*)d_in[9];
  const float* b1 = (const float*)d_in[10];
  const float* w2 = (const float*)d_in[11];
  const float* b2 = (const float*)d_in[12];
  float* out = (float*)d_out;

  char* ws = (char*)d_ws;
  unsigned short* wqb = (unsigned short*)(ws + 0);         // 6x 256x256 bf16
  unsigned short* wkb = (unsigned short*)(ws + 131072);
  unsigned short* wvb = (unsigned short*)(ws + 262144);
  unsigned short* wob = (unsigned short*)(ws + 393216);
  unsigned short* w1b = (unsigned short*)(ws + 524288);
  unsigned short* w2b = (unsigned short*)(ws + 655360);
  unsigned short* emb = (unsigned short*)(ws + 786432);    // [4096][256] bf16
  unsigned short* h1b = (unsigned short*)(ws + 2883584);   // [4096][256] bf16
  float*          peF = (float*)(ws + 4980736);            // [4096][256] fp32
  unsigned short* XT  = (unsigned short*)(ws + 9175040);   // [4][4096][256]
  unsigned short* qT  = (unsigned short*)(ws + 17563648);  // [4][4096][256]
  unsigned short* kT  = (unsigned short*)(ws + 25952256);  // [4][4096][256]
  unsigned short* vB  = (unsigned short*)(ws + 34340864);  // [4][256][4096]
  float*          oP  = (float*)(ws + 51118080);           // [8][4096][256] f32
  float*          lP  = (float*)(ws + 84672512);           // [8][4096] f32
  (void)ws_size; (void)in_sizes; (void)n_in; (void)out_size;

  const dim3 B256(256);
  const long S = 1048576;  // 4096*256 (= 256*4096) element batch stride

  convert6<<<1536, B256, 0, stream>>>(wq, wk, wv, wo, w1, w2, wqb);
  embed_k<<<4096, B256, 0, stream>>>(emb);
  // pe MLP: h1 = silu(embed @ w1^T + b1); peF = h1 @ w2^T + b2  (fp32 out)
  gemm_nt<1, 2, 0, 1><<<dim3(32, 2, 1), B256, 0, stream>>>(
      emb, w1b, h1b, 256, 256, 256, 0, 0, 0, b1, nullptr, 1.0f);
  gemm_nt<0, 2, 0, 0><<<dim3(32, 2, 1), B256, 0, stream>>>(
      h1b, w2b, peF, 256, 256, 256, 0, 0, 0, b2, nullptr, 1.0f);
  transpose_x<<<dim3(128, 8, 4), dim3(32, 8), 0, stream>>>(x, XT);
  // Fused q+k projections (shared XT staging).
  gemm_qk<<<dim3(32, 2, 4), B256, 0, stream>>>(XT, wqb, wkb, qT, kT, bq, bk,
                                               peF);
  // v[o,s] = wv.XT + bv[o] + pe[o*4096+s]    (pe mode 1: row-major index)
  gemm_nt<1, 1, 1, 0><<<dim3(2, 32, 4), B256, 0, stream>>>(
      wvb, XT, vB, 256, 4096, 256, 0, S, S, bv, peF, 1.0f);

  // Fused attention: logits + softmax(axis i) + PV; i split across 2 blocks.
  flash_attn<<<256, dim3(512), 0, stream>>>(qT, kT, vB, oP, lP);

  // Output projection with fused i-half combine (replaces combine_o + gemm).
  gemm_out_f<<<dim3(2, 32, 4), B256, 0, stream>>>(wob, oP, lP, bo, out);
}

// Round 13
// 148.554 us; speedup vs baseline: 1.2168x; 1.0908x over previous
//
#include <hip/hip_runtime.h>
#include <cstdint>

// ---------------------------------------------------------------------------
// SAGAN self-attention block, bf16-MFMA pipeline, flash-fused attention.
// GEMMs are NT form: C[m,n] = sum_k Arow[m][k] * Brow[n][k].
// Verified fragment conventions (R2-passing gemm, 16x16x32):
//   A-frag: lane holds A[row = lane&15][k = (lane>>4)*8 + q], q=0..7
//   B-frag: lane holds B[col = lane&15][k = (lane>>4)*8 + q]
//   C/D:    lane holds C[row = (lane>>4)*4 + r][col = lane&15], r=0..3
// ---------------------------------------------------------------------------

typedef short s8v __attribute__((ext_vector_type(8)));   // 8 bf16 bits (4 VGPR)
typedef float f32x4 __attribute__((ext_vector_type(4)));
typedef unsigned int u32x2 __attribute__((ext_vector_type(2)));
typedef unsigned int u32x4 __attribute__((ext_vector_type(4)));

#define DEVI static __device__ __forceinline__

DEVI unsigned short f2bf(float f) {
  union { float f; uint32_t u; } x; x.f = f;
  uint32_t u = x.u;
  return (unsigned short)((u + 0x7fffu + ((u >> 16) & 1u)) >> 16);  // RNE
}

// v_permlane32_swap_b32: a' = [a(0:31)|b(0:31)], b' = [a(32:63)|b(32:63)].
DEVI void pl32swap(uint32_t& a, uint32_t& b) {
#if __has_builtin(__builtin_amdgcn_permlane32_swap)
  u32x2 r = __builtin_amdgcn_permlane32_swap(a, b, false, false);
  a = r[0]; b = r[1];
#else
  asm("v_permlane32_swap_b32 %0, %1" : "+v"(a), "+v"(b));
#endif
}

DEVI void gl_lds16(const void* g, void* l) {
  // async global->LDS, 16B per lane; LDS dest must be wave-uniform base.
  __builtin_amdgcn_global_load_lds(
      (const __attribute__((address_space(1))) void*)g,
      (__attribute__((address_space(3))) void*)l,
      16, 0, 0);
}

// Stage a [64 rows][32 k] bf16 tile (4KB), linear LDS layout. t in 0..255.
DEVI void stage(const unsigned short* src, int ld, unsigned short* lds, int t) {
  gl_lds16(src + (long)(t >> 2) * ld + (t & 3) * 8, lds + (t >> 6) * 512);
}

// ---------------------------------------------------------------------------
// NT GEMM: 128x128 tile, 4 waves (2x2), each wave 64x64 = 4x4 frags of
// 16x16x32 bf16 MFMA. (Unchanged from R2/R3 passing version; used by MLP.)
// ---------------------------------------------------------------------------
template <int OBF, int BIAS, int PEM, int SILU>
__global__ __launch_bounds__(256) void gemm_nt(
    const unsigned short* __restrict__ A, const unsigned short* __restrict__ B,
    void* __restrict__ Cp, int K, int N, int ld, long sA, long sB, long sC,
    const float* __restrict__ bias, const float* __restrict__ pe, float scale) {
  const int bz = blockIdx.z;
  const unsigned short* Ab = A + (long)bz * sA;
  const unsigned short* Bb = B + (long)bz * sB;
  const int m0 = blockIdx.x * 128, n0 = blockIdx.y * 128;
  __shared__ __align__(16) unsigned short As[4096], Bs[4096];  // [128][32]
  const int t = threadIdx.x;
  const int wave = t >> 6, lane = t & 63;
  const int wr = wave >> 1, wc = wave & 1;

  f32x4 acc[4][4];
#pragma unroll
  for (int i = 0; i < 4; i++)
#pragma unroll
    for (int j = 0; j < 4; j++) acc[i][j] = f32x4{0.f, 0.f, 0.f, 0.f};

  const int rl = lane & 15, kp = (lane >> 4) * 8;

  for (int k0 = 0; k0 < K; k0 += 32) {
    stage(Ab + (long)m0 * ld + k0, ld, As, t);
    stage(Ab + (long)(m0 + 64) * ld + k0, ld, As + 2048, t);
    stage(Bb + (long)n0 * ld + k0, ld, Bs, t);
    stage(Bb + (long)(n0 + 64) * ld + k0, ld, Bs + 2048, t);
    __syncthreads();  // drains vmcnt before barrier -> LDS valid

    s8v af[4], bfr[4];
#pragma unroll
    for (int i = 0; i < 4; i++)
      af[i] = *(const s8v*)(As + (wr * 64 + i * 16 + rl) * 32 + kp);
#pragma unroll
    for (int j = 0; j < 4; j++)
      bfr[j] = *(const s8v*)(Bs + (wc * 64 + j * 16 + rl) * 32 + kp);
#pragma unroll
    for (int i = 0; i < 4; i++)
#pragma unroll
      for (int j = 0; j < 4; j++)
        acc[i][j] = __builtin_amdgcn_mfma_f32_16x16x32_bf16(af[i], bfr[j],
                                                            acc[i][j], 0, 0, 0);
    __syncthreads();
  }

  const long cb = (long)bz * sC;
#pragma unroll
  for (int i = 0; i < 4; i++) {
    const int r0 = m0 + wr * 64 + i * 16 + (lane >> 4) * 4;
#pragma unroll
    for (int j = 0; j < 4; j++) {
      const int col = n0 + wc * 64 + j * 16 + (lane & 15);
#pragma unroll
      for (int r = 0; r < 4; r++) {
        const int row = r0 + r;
        float val = acc[i][j][r] * scale;
        if (BIAS == 1) val += bias[row];
        if (BIAS == 2) val += bias[col];
        if (PEM == 1) val += pe[(long)row * 4096 + col];
        if (PEM == 2) val += pe[(long)col * 4096 + row];
        if (SILU) val = val / (1.0f + __expf(-val));
        const long ci = cb + (long)row * N + col;
        if (OBF)
          ((unsigned short*)Cp)[ci] = f2bf(val);
        else
          ((float*)Cp)[ci] = val;
      }
    }
  }
}

// ---------------------------------------------------------------------------
// Fused q+k+v projections: ONE XT staging feeds three weight matrices.
// All three share NT form with A = XT rows (m = s), B = weight rows (n = o):
//   qT[s][o] = acc_q + bq[o] + pe[o*4096+s]   (row-major store)
//   kT[s][o] = acc_k + bk[o] + pe[o*4096+s]
//   vB[o][s] = acc_v + bv[o] + pe[o*4096+s]   (transposed store; the 4
//              consecutive s-rows a lane holds = contiguous 8B ushort4)
// 512 thr = 8 waves (wm 0..1 x wn 0..3); per-wave 64m x 32n per output.
// ---------------------------------------------------------------------------
__global__ __launch_bounds__(512) void gemm_qkv(
    const unsigned short* __restrict__ XT, const unsigned short* __restrict__ wqb,
    const unsigned short* __restrict__ wkb, const unsigned short* __restrict__ wvb,
    unsigned short* __restrict__ qT, unsigned short* __restrict__ kT,
    unsigned short* __restrict__ vB, const float* __restrict__ bq,
    const float* __restrict__ bk, const float* __restrict__ bv,
    const float* __restrict__ pe) {
  const int bz = blockIdx.z;
  const unsigned short* Ab = XT + (long)bz * 1048576;
  const int m0 = blockIdx.x * 128, n0 = blockIdx.y * 128;
  __shared__ __align__(16) unsigned short As[4096], Bq[4096], Bk[4096],
      Bv[4096];
  const int t = threadIdx.x;
  const int wave = t >> 6, lane = t & 63;
  const int wm = wave >> 2, wn = wave & 3;
  const int rl = lane & 15, kp = (lane >> 4) * 8;
  const int th = t >> 8, tt = t & 255;  // staging split: th picks tile half

  f32x4 aq[4][2], ak[4][2], av[4][2];
#pragma unroll
  for (int i = 0; i < 4; i++)
#pragma unroll
    for (int j = 0; j < 2; j++) {
      aq[i][j] = f32x4{0.f, 0.f, 0.f, 0.f};
      ak[i][j] = f32x4{0.f, 0.f, 0.f, 0.f};
      av[i][j] = f32x4{0.f, 0.f, 0.f, 0.f};
    }

  for (int k0 = 0; k0 < 256; k0 += 32) {
    const long ro = (long)(th * 64) * 256 + k0;
    stage(Ab + (long)m0 * 256 + ro, 256, As + th * 2048, tt);
    stage(wqb + (long)n0 * 256 + ro, 256, Bq + th * 2048, tt);
    stage(wkb + (long)n0 * 256 + ro, 256, Bk + th * 2048, tt);
    stage(wvb + (long)n0 * 256 + ro, 256, Bv + th * 2048, tt);
    __syncthreads();

    s8v af[4], b0[2], b1[2], b2[2];
#pragma unroll
    for (int i = 0; i < 4; i++)
      af[i] = *(const s8v*)(As + (wm * 64 + i * 16 + rl) * 32 + kp);
#pragma unroll
    for (int j = 0; j < 2; j++) {
      b0[j] = *(const s8v*)(Bq + (wn * 32 + j * 16 + rl) * 32 + kp);
      b1[j] = *(const s8v*)(Bk + (wn * 32 + j * 16 + rl) * 32 + kp);
      b2[j] = *(const s8v*)(Bv + (wn * 32 + j * 16 + rl) * 32 + kp);
    }
#pragma unroll
    for (int i = 0; i < 4; i++)
#pragma unroll
      for (int j = 0; j < 2; j++) {
        aq[i][j] = __builtin_amdgcn_mfma_f32_16x16x32_bf16(af[i], b0[j],
                                                           aq[i][j], 0, 0, 0);
        ak[i][j] = __builtin_amdgcn_mfma_f32_16x16x32_bf16(af[i], b1[j],
                                                           ak[i][j], 0, 0, 0);
        av[i][j] = __builtin_amdgcn_mfma_f32_16x16x32_bf16(af[i], b2[j],
                                                           av[i][j], 0, 0, 0);
      }
    __syncthreads();
  }

  const long cb = (long)bz * 1048576;
#pragma unroll
  for (int i = 0; i < 4; i++) {
    const int row0 = m0 + wm * 64 + i * 16 + (lane >> 4) * 4;
#pragma unroll
    for (int j = 0; j < 2; j++) {
      const int col = n0 + wn * 32 + j * 16 + rl;
      const float4 p4 = *(const float4*)(pe + (long)col * 4096 + row0);
      const float bqc = bq[col], bkc = bk[col], bvc = bv[col];
      ushort4 vpk;
      const float pv[4] = {p4.x, p4.y, p4.z, p4.w};
#pragma unroll
      for (int r = 0; r < 4; r++) {
        const int row = row0 + r;
        qT[cb + (long)row * 256 + col] = f2bf(aq[i][j][r] + bqc + pv[r]);
        kT[cb + (long)row * 256 + col] = f2bf(ak[i][j][r] + bkc + pv[r]);
      }
      vpk.x = f2bf(av[i][j][0] + bvc + pv[0]);
      vpk.y = f2bf(av[i][j][1] + bvc + pv[1]);
      vpk.z = f2bf(av[i][j][2] + bvc + pv[2]);
      vpk.w = f2bf(av[i][j][3] + bvc + pv[3]);
      *(ushort4*)(vB + cb + (long)col * 4096 + row0) = vpk;
    }
  }
}

// ---------------------------------------------------------------------------
// Output projection with FUSED i-half combine (unchanged from R12).
// ---------------------------------------------------------------------------
__global__ __launch_bounds__(256) void gemm_out_f(
    const unsigned short* __restrict__ wob, const float* __restrict__ oPart,
    const float* __restrict__ lPart, const float* __restrict__ bo,
    float* __restrict__ out) {
  const int bz = blockIdx.z;  // batch
  const int m0 = blockIdx.x * 128, n0 = blockIdx.y * 128;  // o rows, j cols
  __shared__ __align__(16) unsigned short As[4096], Bs[4096];
  const int t = threadIdx.x;
  const int wave = t >> 6, lane = t & 63;
  const int wr = wave >> 1, wc = wave & 1;

  f32x4 acc[4][4];
#pragma unroll
  for (int i = 0; i < 4; i++)
#pragma unroll
    for (int j = 0; j < 4; j++) acc[i][j] = f32x4{0.f, 0.f, 0.f, 0.f};

  const int rl = lane & 15, kp = (lane >> 4) * 8;
  const int tr = t >> 2, tc8 = (t & 3) * 8;  // staging row/col-chunk

  const int j0_ = n0 + tr, j1_ = n0 + 64 + tr;
  const float* l0p = lPart + (long)(bz * 2) * 4096;
  const float* l1p = lPart + (long)(bz * 2 + 1) * 4096;
  const float inv0 = 1.0f / (l0p[j0_] + l1p[j0_]);
  const float inv1 = 1.0f / (l0p[j1_] + l1p[j1_]);
  const float* oP0 = oPart + (long)(bz * 2) * 1048576;
  const float* oP1 = oPart + (long)(bz * 2 + 1) * 1048576;

  for (int k0 = 0; k0 < 256; k0 += 32) {
    stage(wob + (long)m0 * 256 + k0, 256, As, t);
    stage(wob + (long)(m0 + 64) * 256 + k0, 256, As + 2048, t);
#pragma unroll
    for (int h = 0; h < 2; h++) {
      const int j = h ? j1_ : j0_;
      const float inv = h ? inv1 : inv0;
      const float4* a4 = (const float4*)(oP0 + (long)j * 256 + k0 + tc8);
      const float4* d4 = (const float4*)(oP1 + (long)j * 256 + k0 + tc8);
      const float4 a0 = a4[0], a1 = a4[1], d0 = d4[0], d1 = d4[1];
      s8v pk;
      pk[0] = (short)f2bf((a0.x + d0.x) * inv);
      pk[1] = (short)f2bf((a0.y + d0.y) * inv);
      pk[2] = (short)f2bf((a0.z + d0.z) * inv);
      pk[3] = (short)f2bf((a0.w + d0.w) * inv);
      pk[4] = (short)f2bf((a1.x + d1.x) * inv);
      pk[5] = (short)f2bf((a1.y + d1.y) * inv);
      pk[6] = (short)f2bf((a1.z + d1.z) * inv);
      pk[7] = (short)f2bf((a1.w + d1.w) * inv);
      *(s8v*)(Bs + h * 2048 + tr * 32 + tc8) = pk;
    }
    __syncthreads();  // drains vmcnt (A gl_lds) + lgkmcnt (B ds_write)

    s8v af[4], bfr[4];
#pragma unroll
    for (int i = 0; i < 4; i++)
      af[i] = *(const s8v*)(As + (wr * 64 + i * 16 + rl) * 32 + kp);
#pragma unroll
    for (int j = 0; j < 4; j++)
      bfr[j] = *(const s8v*)(Bs + (wc * 64 + j * 16 + rl) * 32 + kp);
#pragma unroll
    for (int i = 0; i < 4; i++)
#pragma unroll
      for (int j = 0; j < 4; j++)
        acc[i][j] = __builtin_amdgcn_mfma_f32_16x16x32_bf16(af[i], bfr[j],
                                                            acc[i][j], 0, 0, 0);
    __syncthreads();
  }

  const long cb = (long)bz * 1048576;
#pragma unroll
  for (int i = 0; i < 4; i++) {
    const int r0 = m0 + wr * 64 + i * 16 + (lane >> 4) * 4;
#pragma unroll
    for (int j = 0; j < 4; j++) {
      const int col = n0 + wc * 64 + j * 16 + (lane & 15);
#pragma unroll
      for (int r = 0; r < 4; r++) {
        const int row = r0 + r;
        out[cb + (long)row * 4096 + col] = acc[i][j][r] + bo[row];
      }
    }
  }
}

// ---------------------------------------------------------------------------
// Flash-fused attention v8 (FROZEN from R11; structural plateau ~97 us).
// ---------------------------------------------------------------------------
__global__ __launch_bounds__(512, 2) void flash_attn(
    const unsigned short* __restrict__ qTp, const unsigned short* __restrict__ kTp,
    const unsigned short* __restrict__ vBp, float* __restrict__ oPart,
    float* __restrict__ lPart) {
  const int bid = blockIdx.x;
  const int xcd = bid & 7;
  const int b = xcd >> 1, ihalf = xcd & 1;
  const int j0 = (bid >> 3) * 128;
  const long S = 1048576;
  const long ibase = (long)ihalf * 2048;
  const unsigned short* q = qTp + (long)b * S;
  const unsigned short* k = kTp + (long)b * S;
  const unsigned short* v = vBp + (long)b * S;
  const int ob = b * 2 + ihalf;  // output plane

  __shared__ __align__(16) unsigned char ldsb[131584];

  const int t = threadIdx.x;
  const int wave = t >> 6, lane = t & 63;
  const int jq = wave & 3, ch = wave >> 2;
  const int rl = lane & 15, g = lane >> 4;
  const int kp = g * 8;
  const int ksw = ((g ^ ((rl >> 1) & 3)) << 3);   // swizzled k-off (row=rl)
  const int qrow = (rl & 3) | ((rl & 4) << 1) | ((rl & 8) >> 1);  // bs(rl)
  const int kswq = ((g ^ ((qrow >> 1) & 3)) << 3);
  const int th = t >> 8, tt = t & 255;            // staging split

  const unsigned short* krow = k + (long)(j0 + jq * 32 + rl) * 256 + kp;
  s8v kreg[2][8];
#pragma unroll
  for (int jf = 0; jf < 2; jf++)
#pragma unroll
    for (int s = 0; s < 8; s++)
      kreg[jf][s] = *(const s8v*)(krow + jf * 16 * 256 + s * 32);

  f32x4 oacc[16][2];  // O^T: rows c = cf*16+4g+r, cols j = jq*32+jf*16+rl
#pragma unroll
  for (int cf = 0; cf < 16; cf++)
#pragma unroll
    for (int jf = 0; jf < 2; jf++) oacc[cf][jf] = f32x4{0.f, 0.f, 0.f, 0.f};
  float plsum[2] = {0.f, 0.f};

  const int tr = tt >> 2, tc = tt & 3;
  const int sc = (tc ^ ((tr >> 1) & 3)) * 8;
  const unsigned short* qsrc[4];
  const unsigned short* vsrc[4];
  const int dsto = (tt >> 6) * 512;  // wave-uniform LDS sub-offset
#pragma unroll
  for (int ss = 0; ss < 4; ss++) {
    const int s_ = ss * 2 + th;
    qsrc[ss] = q + ibase * 256 + s_ * 32 + (long)tr * 256 + sc;
    vsrc[ss] = v + (long)((s_ >> 1) * 64) * 4096 + ibase + (s_ & 1) * 32 +
               (long)tr * 4096 + sc;
  }

#define STAGE_QV(bufsel)                                                     \
  {                                                                          \
    unsigned short* qD = (unsigned short*)(ldsb + ((bufsel) << 15));         \
    unsigned short* vD = (unsigned short*)(ldsb + 65536 + ((bufsel) << 15)); \
    _Pragma("unroll") for (int ss = 0; ss < 4; ss++) {                       \
      const int s_ = ss * 2 + th;                                            \
      gl_lds16(qsrc[ss], qD + s_ * 2048 + dsto);                             \
      gl_lds16(vsrc[ss], vD + s_ * 2048 + dsto);                             \
      qsrc[ss] += 16384;                                                     \
      vsrc[ss] += 64;                                                        \
    }                                                                        \
  }

  STAGE_QV(0)

  for (int n = 0; n < 32; ++n) {
    const int cur = n & 1;
    __syncthreads();
    STAGE_QV(cur ^ 1)

    f32x4 sa[2][2];
#pragma unroll
    for (int kk = 0; kk < 2; kk++)
#pragma unroll
      for (int jf = 0; jf < 2; jf++) sa[kk][jf] = f32x4{0.f, 0.f, 0.f, 0.f};
    const unsigned short* qbase =
        (const unsigned short*)(ldsb + (cur << 15)) +
        (ch * 32 + qrow) * 32 + kswq;
#pragma unroll
    for (int s = 0; s < 8; s++) {
      s8v qf0 = *(const s8v*)(qbase + s * 2048);
      s8v qf1 = *(const s8v*)(qbase + s * 2048 + 512);
      sa[0][0] = __builtin_amdgcn_mfma_f32_16x16x32_bf16(qf0, kreg[0][s],
                                                         sa[0][0], 0, 0, 0);
      sa[0][1] = __builtin_amdgcn_mfma_f32_16x16x32_bf16(qf0, kreg[1][s],
                                                         sa[0][1], 0, 0, 0);
      sa[1][0] = __builtin_amdgcn_mfma_f32_16x16x32_bf16(qf1, kreg[0][s],
                                                         sa[1][0], 0, 0, 0);
      sa[1][1] = __builtin_amdgcn_mfma_f32_16x16x32_bf16(qf1, kreg[1][s],
                                                         sa[1][1], 0, 0, 0);
    }

    uint32_t pd[2][2][2];
#pragma unroll
    for (int kk = 0; kk < 2; kk++)
#pragma unroll
      for (int jf = 0; jf < 2; jf++) {
        const float p0 = exp2f(sa[kk][jf][0] * 0.09016844005556021f);
        const float p1 = exp2f(sa[kk][jf][1] * 0.09016844005556021f);
        const float p2 = exp2f(sa[kk][jf][2] * 0.09016844005556021f);
        const float p3 = exp2f(sa[kk][jf][3] * 0.09016844005556021f);
        plsum[jf] += (p0 + p1) + (p2 + p3);
        pd[kk][jf][0] = (uint32_t)f2bf(p0) | ((uint32_t)f2bf(p1) << 16);
        pd[kk][jf][1] = (uint32_t)f2bf(p2) | ((uint32_t)f2bf(p3) << 16);
      }

    s8v pB[2];
#pragma unroll
    for (int jf = 0; jf < 2; jf++) {
      uint32_t a0 = pd[0][jf][0], b0 = pd[1][jf][0];
      uint32_t a1 = pd[0][jf][1], b1 = pd[1][jf][1];
      pl32swap(a0, b0);
      pl32swap(a1, b1);
      u32x4 w4 = {a0, a1, b0, b1};
      pB[jf] = __builtin_bit_cast(s8v, w4);
    }

    const unsigned short* vbase =
        (const unsigned short*)(ldsb + 65536 + (cur << 15)) + ch * 2048 +
        rl * 32 + ksw;
#pragma unroll
    for (int cf = 0; cf < 16; cf++) {
      s8v vb = *(const s8v*)(vbase + (cf >> 2) * 4096 + (cf & 3) * 512);
      oacc[cf][0] = __builtin_amdgcn_mfma_f32_16x16x32_bf16(vb, pB[0],
                                                            oacc[cf][0], 0, 0, 0);
      oacc[cf][1] = __builtin_amdgcn_mfma_f32_16x16x32_bf16(vb, pB[1],
                                                            oacc[cf][1], 0, 0, 0);
    }
  }

#pragma unroll
  for (int jf = 0; jf < 2; jf++) {
    plsum[jf] += __shfl_xor(plsum[jf], 16);
    plsum[jf] += __shfl_xor(plsum[jf], 32);
  }

  __syncthreads();  // loop LDS dead; safe to alias
  float4* ex = (float4*)ldsb;           // [4 jq][32 j][64 c4]
  float* exl = (float*)(ldsb + 131072); // [4 jq][32 j]
  if (ch == 1) {
#pragma unroll
    for (int jf = 0; jf < 2; jf++) {
#pragma unroll
      for (int cf = 0; cf < 16; cf++)
        ex[jq * 2048 + (jf * 16 + rl) * 64 + cf * 4 + g] =
            float4{oacc[cf][jf][0], oacc[cf][jf][1], oacc[cf][jf][2],
                   oacc[cf][jf][3]};
      if (g == 0) exl[jq * 32 + jf * 16 + rl] = plsum[jf];
    }
  }
  __syncthreads();
  if (ch == 0) {
    float4* op4 = (float4*)(oPart + (long)ob * 1048576);
#pragma unroll
    for (int jf = 0; jf < 2; jf++) {
      const int jl = jq * 32 + jf * 16 + rl;
      if (g == 0)
        lPart[(long)ob * 4096 + j0 + jl] = plsum[jf] + exl[jl];
#pragma unroll
      for (int cf = 0; cf < 16; cf++) {
        const float4 o = ex[jq * 2048 + (jf * 16 + rl) * 64 + cf * 4 + g];
        op4[(long)(j0 + jl) * 64 + cf * 4 + g] =
            float4{oacc[cf][jf][0] + o.x, oacc[cf][jf][1] + o.y,
                   oacc[cf][jf][2] + o.z, oacc[cf][jf][3] + o.w};
      }
    }
  }
#undef STAGE_QV
}

// ---------------------------------------------------------------------------
// prep_all: convert6 (blocks [0,1536)) U embed_k ([1536,5632)) U transpose_x
// ([5632,9728)). Independent work; branch is block-uniform.
// ---------------------------------------------------------------------------
__global__ __launch_bounds__(256) void prep_all(
    const float* __restrict__ a0, const float* __restrict__ a1,
    const float* __restrict__ a2, const float* __restrict__ a3,
    const float* __restrict__ a4, const float* __restrict__ a5,
    unsigned short* __restrict__ wdst, unsigned short* __restrict__ emb,
    const float* __restrict__ x, unsigned short* __restrict__ xt) {
  __shared__ float tile[32][33];
  const int bid = blockIdx.x;
  const int t = threadIdx.x;
  if (bid < 1536) {
    // convert6: six 256x256 fp32 weights -> contiguous bf16.
    int idx = bid * 256 + t;
    int m = idx >> 16, r = idx & 65535;
    const float* s;
    switch (m) {
      case 0: s = a0; break;
      case 1: s = a1; break;
      case 2: s = a2; break;
      case 3: s = a3; break;
      case 4: s = a4; break;
      default: s = a5; break;
    }
    wdst[idx] = f2bf(s[r]);
  } else if (bid < 5632) {
    // embed: e[t,d] = sin/cos(t * 10000^(-d/128)).
    int idx = (bid - 1536) * 256 + t;
    int tt_ = idx >> 8, d = idx & 255;
    float freq = exp2f((float)d * -0.10381025296573598f);
    float w = (float)tt_ * freq;
    float sn, cs;
    __sincosf(w, &sn, &cs);
    emb[idx] = f2bf((d & 1) ? cs : sn);
  } else {
    // transpose_x: x [4][256][4096] fp32 -> XT [4][4096][256] bf16.
    const int bid2 = bid - 5632;
    const int s0 = (bid2 & 127) * 32, c0 = ((bid2 >> 7) & 7) * 32;
    const int b = bid2 >> 10;
    const int tx = t & 31, ty = t >> 5;
    const float* xb = x + (long)b * 256 * 4096;
#pragma unroll
    for (int r = 0; r < 32; r += 8)
      tile[ty + r][tx] = xb[(long)(c0 + ty + r) * 4096 + s0 + tx];
    __syncthreads();
    unsigned short* xtb = xt + (long)b * 4096 * 256;
#pragma unroll
    for (int r = 0; r < 32; r += 8)
      xtb[(long)(s0 + ty + r) * 256 + c0 + tx] = f2bf(tile[tx][ty + r]);
  }
}

// ---------------------------------------------------------------------------
extern "C" void kernel_launch(void* const* d_in, const int* in_sizes, int n_in,
                              void* d_out, int out_size, void* d_ws,
                              size_t ws_size, hipStream_t stream) {
  const float* x  = (const float*)d_in[0];
  const float* wq = (const float*)d_in[1];
  const float* bq = (const float*)d_in[2];
  const float* wk = (const float*)d_in[3];
  const float* bk = (const float*)d_in[4];
  const float* wv = (const float*)d_in[5];
  const float* bv = (const float*)d_in[6];
  const float* wo = (const float*)d_in[7];
  const float* bo = (const float*)d_in[8];
  const float* w1 = (const float*)d_in[9];
  const float* b1 = (const float*)d_in[10];
  const float* w2 = (const float*)d_in[11];
  const float* b2 = (const float*)d_in[12];
  float* out = (float*)d_out;

  char* ws = (char*)d_ws;
  unsigned short* wqb = (unsigned short*)(ws + 0);         // 6x 256x256 bf16
  unsigned short* wkb = (unsigned short*)(ws + 131072);
  unsigned short* wvb = (unsigned short*)(ws + 262144);
  unsigned short* wob = (unsigned short*)(ws + 393216);
  unsigned short* w1b = (unsigned short*)(ws + 524288);
  unsigned short* w2b = (unsigned short*)(ws + 655360);
  unsigned short* emb = (unsigned short*)(ws + 786432);    // [4096][256] bf16
  unsigned short* h1b = (unsigned short*)(ws + 2883584);   // [4096][256] bf16
  float*          peF = (float*)(ws + 4980736);            // [4096][256] fp32
  unsigned short* XT  = (unsigned short*)(ws + 9175040);   // [4][4096][256]
  unsigned short* qT  = (unsigned short*)(ws + 17563648);  // [4][4096][256]
  unsigned short* kT  = (unsigned short*)(ws + 25952256);  // [4][4096][256]
  unsigned short* vB  = (unsigned short*)(ws + 34340864);  // [4][256][4096]
  float*          oP  = (float*)(ws + 51118080);           // [8][4096][256] f32
  float*          lP  = (float*)(ws + 84672512);           // [8][4096] f32
  (void)ws_size; (void)in_sizes; (void)n_in; (void)out_size;

  const dim3 B256(256);

  // convert6 U embed U transpose_x (independent; one launch).
  prep_all<<<9728, B256, 0, stream>>>(wq, wk, wv, wo, w1, w2, wqb, emb, x, XT);
  // pe MLP: h1 = silu(embed @ w1^T + b1); peF = h1 @ w2^T + b2  (fp32 out)
  gemm_nt<1, 2, 0, 1><<<dim3(32, 2, 1), B256, 0, stream>>>(
      emb, w1b, h1b, 256, 256, 256, 0, 0, 0, b1, nullptr, 1.0f);
  gemm_nt<0, 2, 0, 0><<<dim3(32, 2, 1), B256, 0, stream>>>(
      h1b, w2b, peF, 256, 256, 256, 0, 0, 0, b2, nullptr, 1.0f);
  // Fused q+k+v projections (ONE XT staging, v stored transposed).
  gemm_qkv<<<dim3(32, 2, 4), dim3(512), 0, stream>>>(
      XT, wqb, wkb, wvb, qT, kT, vB, bq, bk, bv, peF);
  // Fused attention: logits + softmax(axis i) + PV; i split across 2 blocks.
  flash_attn<<<256, dim3(512), 0, stream>>>(qT, kT, vB, oP, lP);
  // Output projection with fused i-half combine.
  gemm_out_f<<<dim3(2, 32, 4), B256, 0, stream>>>(wob, oP, lP, bo, out);
}

// Round 14
// 144.578 us; speedup vs baseline: 1.2503x; 1.0275x over previous
//
#include <hip/hip_runtime.h>
#include <cstdint>

// ---------------------------------------------------------------------------
// SAGAN self-attention block, bf16-MFMA pipeline, flash-fused attention.
// GEMMs are NT form: C[m,n] = sum_k Arow[m][k] * Brow[n][k].
// Verified fragment conventions (R2-passing gemm, 16x16x32):
//   A-frag: lane holds A[row = lane&15][k = (lane>>4)*8 + q], q=0..7
//   B-frag: lane holds B[col = lane&15][k = (lane>>4)*8 + q]
//   C/D:    lane holds C[row = (lane>>4)*4 + r][col = lane&15], r=0..3
// ---------------------------------------------------------------------------

typedef short s8v __attribute__((ext_vector_type(8)));   // 8 bf16 bits (4 VGPR)
typedef float f32x4 __attribute__((ext_vector_type(4)));

#define DEVI static __device__ __forceinline__

DEVI unsigned short f2bf(float f) {
  union { float f; uint32_t u; } x; x.f = f;
  uint32_t u = x.u;
  return (unsigned short)((u + 0x7fffu + ((u >> 16) & 1u)) >> 16);  // RNE
}

DEVI void gl_lds16(const void* g, void* l) {
  // async global->LDS, 16B per lane; LDS dest must be wave-uniform base.
  __builtin_amdgcn_global_load_lds(
      (const __attribute__((address_space(1))) void*)g,
      (__attribute__((address_space(3))) void*)l,
      16, 0, 0);
}

// Stage a [64 rows][32 k] bf16 tile (4KB), linear LDS layout. t in 0..255.
DEVI void stage(const unsigned short* src, int ld, unsigned short* lds, int t) {
  gl_lds16(src + (long)(t >> 2) * ld + (t & 3) * 8, lds + (t >> 6) * 512);
}

// ---------------------------------------------------------------------------
// NT GEMM: 128x128 tile, 4 waves (2x2), each wave 64x64 = 4x4 frags of
// 16x16x32 bf16 MFMA. (Unchanged from R2/R3 passing version; used by MLP.)
// ---------------------------------------------------------------------------
template <int OBF, int BIAS, int PEM, int SILU>
__global__ __launch_bounds__(256) void gemm_nt(
    const unsigned short* __restrict__ A, const unsigned short* __restrict__ B,
    void* __restrict__ Cp, int K, int N, int ld, long sA, long sB, long sC,
    const float* __restrict__ bias, const float* __restrict__ pe, float scale) {
  const int bz = blockIdx.z;
  const unsigned short* Ab = A + (long)bz * sA;
  const unsigned short* Bb = B + (long)bz * sB;
  const int m0 = blockIdx.x * 128, n0 = blockIdx.y * 128;
  __shared__ __align__(16) unsigned short As[4096], Bs[4096];  // [128][32]
  const int t = threadIdx.x;
  const int wave = t >> 6, lane = t & 63;
  const int wr = wave >> 1, wc = wave & 1;

  f32x4 acc[4][4];
#pragma unroll
  for (int i = 0; i < 4; i++)
#pragma unroll
    for (int j = 0; j < 4; j++) acc[i][j] = f32x4{0.f, 0.f, 0.f, 0.f};

  const int rl = lane & 15, kp = (lane >> 4) * 8;

  for (int k0 = 0; k0 < K; k0 += 32) {
    stage(Ab + (long)m0 * ld + k0, ld, As, t);
    stage(Ab + (long)(m0 + 64) * ld + k0, ld, As + 2048, t);
    stage(Bb + (long)n0 * ld + k0, ld, Bs, t);
    stage(Bb + (long)(n0 + 64) * ld + k0, ld, Bs + 2048, t);
    __syncthreads();  // drains vmcnt before barrier -> LDS valid

    s8v af[4], bfr[4];
#pragma unroll
    for (int i = 0; i < 4; i++)
      af[i] = *(const s8v*)(As + (wr * 64 + i * 16 + rl) * 32 + kp);
#pragma unroll
    for (int j = 0; j < 4; j++)
      bfr[j] = *(const s8v*)(Bs + (wc * 64 + j * 16 + rl) * 32 + kp);
#pragma unroll
    for (int i = 0; i < 4; i++)
#pragma unroll
      for (int j = 0; j < 4; j++)
        acc[i][j] = __builtin_amdgcn_mfma_f32_16x16x32_bf16(af[i], bfr[j],
                                                            acc[i][j], 0, 0, 0);
    __syncthreads();
  }

  const long cb = (long)bz * sC;
#pragma unroll
  for (int i = 0; i < 4; i++) {
    const int r0 = m0 + wr * 64 + i * 16 + (lane >> 4) * 4;
#pragma unroll
    for (int j = 0; j < 4; j++) {
      const int col = n0 + wc * 64 + j * 16 + (lane & 15);
#pragma unroll
      for (int r = 0; r < 4; r++) {
        const int row = r0 + r;
        float val = acc[i][j][r] * scale;
        if (BIAS == 1) val += bias[row];
        if (BIAS == 2) val += bias[col];
        if (PEM == 1) val += pe[(long)row * 4096 + col];
        if (PEM == 2) val += pe[(long)col * 4096 + row];
        if (SILU) val = val / (1.0f + __expf(-val));
        const long ci = cb + (long)row * N + col;
        if (OBF)
          ((unsigned short*)Cp)[ci] = f2bf(val);
        else
          ((float*)Cp)[ci] = val;
      }
    }
  }
}

// ---------------------------------------------------------------------------
// Fused q+k+v projections (unchanged from R13).
// ---------------------------------------------------------------------------
__global__ __launch_bounds__(512) void gemm_qkv(
    const unsigned short* __restrict__ XT, const unsigned short* __restrict__ wqb,
    const unsigned short* __restrict__ wkb, const unsigned short* __restrict__ wvb,
    unsigned short* __restrict__ qT, unsigned short* __restrict__ kT,
    unsigned short* __restrict__ vB, const float* __restrict__ bq,
    const float* __restrict__ bk, const float* __restrict__ bv,
    const float* __restrict__ pe) {
  const int bz = blockIdx.z;
  const unsigned short* Ab = XT + (long)bz * 1048576;
  const int m0 = blockIdx.x * 128, n0 = blockIdx.y * 128;
  __shared__ __align__(16) unsigned short As[4096], Bq[4096], Bk[4096],
      Bv[4096];
  const int t = threadIdx.x;
  const int wave = t >> 6, lane = t & 63;
  const int wm = wave >> 2, wn = wave & 3;
  const int rl = lane & 15, kp = (lane >> 4) * 8;
  const int th = t >> 8, tt = t & 255;  // staging split: th picks tile half

  f32x4 aq[4][2], ak[4][2], av[4][2];
#pragma unroll
  for (int i = 0; i < 4; i++)
#pragma unroll
    for (int j = 0; j < 2; j++) {
      aq[i][j] = f32x4{0.f, 0.f, 0.f, 0.f};
      ak[i][j] = f32x4{0.f, 0.f, 0.f, 0.f};
      av[i][j] = f32x4{0.f, 0.f, 0.f, 0.f};
    }

  for (int k0 = 0; k0 < 256; k0 += 32) {
    const long ro = (long)(th * 64) * 256 + k0;
    stage(Ab + (long)m0 * 256 + ro, 256, As + th * 2048, tt);
    stage(wqb + (long)n0 * 256 + ro, 256, Bq + th * 2048, tt);
    stage(wkb + (long)n0 * 256 + ro, 256, Bk + th * 2048, tt);
    stage(wvb + (long)n0 * 256 + ro, 256, Bv + th * 2048, tt);
    __syncthreads();

    s8v af[4], b0[2], b1[2], b2[2];
#pragma unroll
    for (int i = 0; i < 4; i++)
      af[i] = *(const s8v*)(As + (wm * 64 + i * 16 + rl) * 32 + kp);
#pragma unroll
    for (int j = 0; j < 2; j++) {
      b0[j] = *(const s8v*)(Bq + (wn * 32 + j * 16 + rl) * 32 + kp);
      b1[j] = *(const s8v*)(Bk + (wn * 32 + j * 16 + rl) * 32 + kp);
      b2[j] = *(const s8v*)(Bv + (wn * 32 + j * 16 + rl) * 32 + kp);
    }
#pragma unroll
    for (int i = 0; i < 4; i++)
#pragma unroll
      for (int j = 0; j < 2; j++) {
        aq[i][j] = __builtin_amdgcn_mfma_f32_16x16x32_bf16(af[i], b0[j],
                                                           aq[i][j], 0, 0, 0);
        ak[i][j] = __builtin_amdgcn_mfma_f32_16x16x32_bf16(af[i], b1[j],
                                                           ak[i][j], 0, 0, 0);
        av[i][j] = __builtin_amdgcn_mfma_f32_16x16x32_bf16(af[i], b2[j],
                                                           av[i][j], 0, 0, 0);
      }
    __syncthreads();
  }

  const long cb = (long)bz * 1048576;
#pragma unroll
  for (int i = 0; i < 4; i++) {
    const int row0 = m0 + wm * 64 + i * 16 + (lane >> 4) * 4;
#pragma unroll
    for (int j = 0; j < 2; j++) {
      const int col = n0 + wn * 32 + j * 16 + rl;
      const float4 p4 = *(const float4*)(pe + (long)col * 4096 + row0);
      const float bqc = bq[col], bkc = bk[col], bvc = bv[col];
      ushort4 vpk;
      const float pv[4] = {p4.x, p4.y, p4.z, p4.w};
#pragma unroll
      for (int r = 0; r < 4; r++) {
        const int row = row0 + r;
        qT[cb + (long)row * 256 + col] = f2bf(aq[i][j][r] + bqc + pv[r]);
        kT[cb + (long)row * 256 + col] = f2bf(ak[i][j][r] + bkc + pv[r]);
      }
      vpk.x = f2bf(av[i][j][0] + bvc + pv[0]);
      vpk.y = f2bf(av[i][j][1] + bvc + pv[1]);
      vpk.z = f2bf(av[i][j][2] + bvc + pv[2]);
      vpk.w = f2bf(av[i][j][3] + bvc + pv[3]);
      *(ushort4*)(vB + cb + (long)col * 4096 + row0) = vpk;
    }
  }
}

// ---------------------------------------------------------------------------
// Output projection with FUSED i-half combine, v2: grid (1,64,4) — each
// block covers ALL 256 o-rows x 64 j-cols, so each oP element is read
// exactly ONCE (R13's (2,32,4) read the oP slab twice). wob (128KB) is
// re-read per block but L2-resident.
// ---------------------------------------------------------------------------
__global__ __launch_bounds__(256) void gemm_out_f(
    const unsigned short* __restrict__ wob, const float* __restrict__ oPart,
    const float* __restrict__ lPart, const float* __restrict__ bo,
    float* __restrict__ out) {
  const int bz = blockIdx.z;          // batch
  const int n0 = blockIdx.y * 64;     // j cols (64 per block)
  __shared__ __align__(16) unsigned short As[8192], Bs[2048];
  // As: [4 tiles][64 m][32 k] = 256 o-rows; Bs: [64 j][32 k]
  const int t = threadIdx.x;
  const int wave = t >> 6, lane = t & 63;
  const int rl = lane & 15, kp = (lane >> 4) * 8;
  const int tr = t >> 2, tc8 = (t & 3) * 8;  // B fold: row 0..63, chunk

  f32x4 acc[4][4];
#pragma unroll
  for (int i = 0; i < 4; i++)
#pragma unroll
    for (int j = 0; j < 4; j++) acc[i][j] = f32x4{0.f, 0.f, 0.f, 0.f};

  const int j_ = n0 + tr;  // this thread's fixed fold row
  const float* l0p = lPart + (long)(bz * 2) * 4096;
  const float* l1p = lPart + (long)(bz * 2 + 1) * 4096;
  const float inv = 1.0f / (l0p[j_] + l1p[j_]);
  const float* oP0 = oPart + (long)(bz * 2) * 1048576;
  const float* oP1 = oPart + (long)(bz * 2 + 1) * 1048576;

  for (int k0 = 0; k0 < 256; k0 += 32) {
#pragma unroll
    for (int s_ = 0; s_ < 4; s_++)
      stage(wob + (long)(s_ * 64) * 256 + k0, 256, As + s_ * 2048, t);
    // B fold: resT row j_, c-chunk [k0+tc8, +8) from the 2 fp32 planes.
    {
      const float4* a4 = (const float4*)(oP0 + (long)j_ * 256 + k0 + tc8);
      const float4* d4 = (const float4*)(oP1 + (long)j_ * 256 + k0 + tc8);
      const float4 a0 = a4[0], a1 = a4[1], d0 = d4[0], d1 = d4[1];
      s8v pk;
      pk[0] = (short)f2bf((a0.x + d0.x) * inv);
      pk[1] = (short)f2bf((a0.y + d0.y) * inv);
      pk[2] = (short)f2bf((a0.z + d0.z) * inv);
      pk[3] = (short)f2bf((a0.w + d0.w) * inv);
      pk[4] = (short)f2bf((a1.x + d1.x) * inv);
      pk[5] = (short)f2bf((a1.y + d1.y) * inv);
      pk[6] = (short)f2bf((a1.z + d1.z) * inv);
      pk[7] = (short)f2bf((a1.w + d1.w) * inv);
      *(s8v*)(Bs + tr * 32 + tc8) = pk;
    }
    __syncthreads();  // drains vmcnt (A gl_lds) + lgkmcnt (B ds_write)

    s8v af[4], bfr[4];
#pragma unroll
    for (int i = 0; i < 4; i++)
      af[i] = *(const s8v*)(As + (wave * 64 + i * 16 + rl) * 32 + kp);
#pragma unroll
    for (int j = 0; j < 4; j++)
      bfr[j] = *(const s8v*)(Bs + (j * 16 + rl) * 32 + kp);
#pragma unroll
    for (int i = 0; i < 4; i++)
#pragma unroll
      for (int j = 0; j < 4; j++)
        acc[i][j] = __builtin_amdgcn_mfma_f32_16x16x32_bf16(af[i], bfr[j],
                                                            acc[i][j], 0, 0, 0);
    __syncthreads();
  }

  const long cb = (long)bz * 1048576;
#pragma unroll
  for (int i = 0; i < 4; i++) {
    const int r0 = wave * 64 + i * 16 + (lane >> 4) * 4;
#pragma unroll
    for (int j = 0; j < 4; j++) {
      const int col = n0 + j * 16 + (lane & 15);
#pragma unroll
      for (int r = 0; r < 4; r++) {
        const int row = r0 + r;
        out[cb + (long)row * 4096 + col] = acc[i][j][r] + bo[row];
      }
    }
  }
}

// ---------------------------------------------------------------------------
// Flash-fused attention v5 (REVERT to the R7/R8-benched champion, 93.8 us):
// 256 blocks x 512 thr; block = (jblk, ihalf, b) = 128 j x 2048 i; wave =
// (jq, ch) = 32 j-rows, i-subhalf; P via wave-private pL (stride 40); one
// __syncthreads per iter; deferred lsum; ch-pair merge epilogue.
// (The R10/R11 in-register-P variants measured 3.8us SLOWER — reverted.)
// ---------------------------------------------------------------------------
__global__ __launch_bounds__(512, 2) void flash_attn(
    const unsigned short* __restrict__ qTp, const unsigned short* __restrict__ kTp,
    const unsigned short* __restrict__ vBp, float* __restrict__ oPart,
    float* __restrict__ lPart) {
  const int bid = blockIdx.x;
  // XCD-aware mapping: xcd = bid&7 -> (b, ihalf); per-XCD L2 set ~4MB.
  const int xcd = bid & 7;
  const int b = xcd >> 1, ihalf = xcd & 1;
  const int j0 = (bid >> 3) * 128;
  const long S = 1048576;
  const long ibase = (long)ihalf * 2048;
  const unsigned short* q = qTp + (long)b * S;
  const unsigned short* k = kTp + (long)b * S;
  const unsigned short* v = vBp + (long)b * S;
  const int ob = b * 2 + ihalf;  // output plane

  // LDS: [0,64K) qL dbuf, [64K,128K) vL dbuf, [128K, +20480) pL.
  // Epilogue aliases: [0,128K) = O exchange (fp32), [128K,+512) = lsum exch.
  __shared__ __align__(16) unsigned char ldsb[151552];

  const int t = threadIdx.x;
  const int wave = t >> 6, lane = t & 63;
  const int jq = wave & 3, ch = wave >> 2;
  const int rl = lane & 15, g = lane >> 4;
  const int kp = g * 8;
  const int ksw = ((g ^ ((rl >> 1) & 3)) << 3);          // swizzled k-offset
  const int th = t >> 8, tt = t & 255;                   // staging split
  unsigned short* pL = (unsigned short*)(ldsb + 131072);
  unsigned short* pLw = pL + wave * 1280;                // [2 jf][16 j][40]

  // K-strip -> registers: wave owns rows j0 + jq*32 + jf*16 + rl.
  const unsigned short* krow = k + (long)(j0 + jq * 32 + rl) * 256 + kp;
  s8v kreg[2][8];
#pragma unroll
  for (int jf = 0; jf < 2; jf++)
#pragma unroll
    for (int s = 0; s < 8; s++)
      kreg[jf][s] = *(const s8v*)(krow + jf * 16 * 256 + s * 32);

  f32x4 oacc[2][16];
#pragma unroll
  for (int jf = 0; jf < 2; jf++)
#pragma unroll
    for (int cf = 0; cf < 16; cf++) oacc[jf][cf] = f32x4{0.f, 0.f, 0.f, 0.f};
  float plsum[2][4] = {{0.f, 0.f, 0.f, 0.f}, {0.f, 0.f, 0.f, 0.f}};

  // Pre-swizzled, pre-offset staging pointers (bumped per iter; source
  // swizzle: slot chunk c holds global chunk c ^ ((row>>1)&3); LDS linear).
  const int tr = tt >> 2, tc = tt & 3;
  const int sc = (tc ^ ((tr >> 1) & 3)) * 8;
  const unsigned short* qsrc[4];
  const unsigned short* vsrc[4];
  const int dsto = (tt >> 6) * 512;  // wave-uniform LDS sub-offset
#pragma unroll
  for (int ss = 0; ss < 4; ss++) {
    const int s_ = ss * 2 + th;
    qsrc[ss] = q + ibase * 256 + s_ * 32 + (long)tr * 256 + sc;
    vsrc[ss] = v + (long)((s_ >> 1) * 64) * 4096 + ibase + (s_ & 1) * 32 +
               (long)tr * 4096 + sc;
  }

#define STAGE_QV(bufsel)                                                     \
  {                                                                          \
    unsigned short* qD = (unsigned short*)(ldsb + ((bufsel) << 15));         \
    unsigned short* vD = (unsigned short*)(ldsb + 65536 + ((bufsel) << 15)); \
    _Pragma("unroll") for (int ss = 0; ss < 4; ss++) {                       \
      const int s_ = ss * 2 + th;                                            \
      gl_lds16(qsrc[ss], qD + s_ * 2048 + dsto);                             \
      gl_lds16(vsrc[ss], vD + s_ * 2048 + dsto);                             \
      qsrc[ss] += 16384;  /* next i-tile: +64*256 elems */                   \
      vsrc[ss] += 64;     /* next i-tile: +64 elems     */                   \
    }                                                                        \
  }

  STAGE_QV(0)

  for (int n = 0; n < 32; ++n) {
    const int cur = n & 1;
    __syncthreads();  // buf[cur] staged; all waves done with buf[cur^1]
    if (n + 1 < 32) STAGE_QV(cur ^ 1)  // overlaps with compute

    const unsigned short* qLb = (const unsigned short*)(ldsb + (cur << 15));
    const unsigned short* vLb =
        (const unsigned short*)(ldsb + 65536 + (cur << 15));

    // QK^T: own i-subhalf (32 i): 16 B-frag reads, 32 MFMA (2 jf x 2 if x 8s).
    f32x4 sa[2][2];
#pragma unroll
    for (int jf = 0; jf < 2; jf++)
#pragma unroll
      for (int f = 0; f < 2; f++) sa[jf][f] = f32x4{0.f, 0.f, 0.f, 0.f};
    const unsigned short* qbase = qLb + (ch * 32 + rl) * 32 + ksw;
#pragma unroll
    for (int s = 0; s < 8; s++) {
#pragma unroll
      for (int f = 0; f < 2; f++) {
        s8v bf = *(const s8v*)(qbase + s * 2048 + f * 512);
        sa[0][f] = __builtin_amdgcn_mfma_f32_16x16x32_bf16(kreg[0][s], bf,
                                                           sa[0][f], 0, 0, 0);
        sa[1][f] = __builtin_amdgcn_mfma_f32_16x16x32_bf16(kreg[1][s], bf,
                                                           sa[1][f], 0, 0, 0);
      }
    }

    // Static-max softmax (|logit| << 88), deferred lsum; P -> wave-private
    // LDS in A-frag layout, padded row stride 40 (<=2-way conflicts).
#pragma unroll
    for (int jf = 0; jf < 2; jf++)
#pragma unroll
      for (int f = 0; f < 2; f++)
#pragma unroll
        for (int r = 0; r < 4; r++) {
          const float p = __expf(sa[jf][f][r] * 0.0625f);
          plsum[jf][r] += p;
          pLw[jf * 640 + (g * 4 + r) * 40 + f * 16 + rl] = f2bf(p);
        }

    // PV over own i-subhalf (K=32): 16 v-frag reads, 32 MFMA (16 cf x 2 jf).
    s8v pa0 = *(const s8v*)(pLw + rl * 40 + kp);
    s8v pa1 = *(const s8v*)(pLw + 640 + rl * 40 + kp);
    const unsigned short* vbase = vLb + ch * 2048 + rl * 32 + ksw;
#pragma unroll
    for (int cf = 0; cf < 16; cf++) {
      s8v vb = *(const s8v*)(vbase + (cf >> 2) * 4096 + (cf & 3) * 512);
      oacc[0][cf] = __builtin_amdgcn_mfma_f32_16x16x32_bf16(pa0, vb,
                                                            oacc[0][cf], 0, 0, 0);
      oacc[1][cf] = __builtin_amdgcn_mfma_f32_16x16x32_bf16(pa1, vb,
                                                            oacc[1][cf], 0, 0, 0);
    }
  }

  // Deferred lsum: butterfly over the 16-lane i-groups.
#pragma unroll
  for (int jf = 0; jf < 2; jf++)
#pragma unroll
    for (int r = 0; r < 4; r++) {
      plsum[jf][r] += __shfl_xor(plsum[jf][r], 1);
      plsum[jf][r] += __shfl_xor(plsum[jf][r], 2);
      plsum[jf][r] += __shfl_xor(plsum[jf][r], 4);
      plsum[jf][r] += __shfl_xor(plsum[jf][r], 8);
    }

  // Merge ch-pairs (complementary i-subhalves) through LDS, then write
  // unnormalized O-partials + lsum partials.
  __syncthreads();  // loop LDS dead; safe to alias
  float* ex = (float*)ldsb;             // [4 jq][32 j][256 c]
  float* exl = (float*)(ldsb + 131072); // [4 jq][32 j]
  if (ch == 1) {
    float* exw = ex + jq * 8192;
#pragma unroll
    for (int jf = 0; jf < 2; jf++) {
#pragma unroll
      for (int cf = 0; cf < 16; cf++)
#pragma unroll
        for (int r = 0; r < 4; r++)
          exw[(jf * 16 + g * 4 + r) * 256 + cf * 16 + rl] = oacc[jf][cf][r];
      if (rl == 0) {
#pragma unroll
        for (int r = 0; r < 4; r++)
          exl[jq * 32 + jf * 16 + g * 4 + r] = plsum[jf][r];
      }
    }
  }
  __syncthreads();
  if (ch == 0) {
    float* exw = ex + jq * 8192;
    float* op = oPart + (long)ob * 1048576;
#pragma unroll
    for (int jf = 0; jf < 2; jf++) {
      if (rl == 0) {
#pragma unroll
        for (int r = 0; r < 4; r++) {
          const int jl = jq * 32 + jf * 16 + g * 4 + r;
          lPart[(long)ob * 4096 + j0 + jl] = plsum[jf][r] + exl[jl];
        }
      }
#pragma unroll
      for (int cf = 0; cf < 16; cf++)
#pragma unroll
        for (int r = 0; r < 4; r++) {
          const int jl2 = jf * 16 + g * 4 + r;
          op[(long)(j0 + jq * 32 + jl2) * 256 + cf * 16 + rl] =
              oacc[jf][cf][r] + exw[jl2 * 256 + cf * 16 + rl];
        }
    }
  }
#undef STAGE_QV
}

// ---------------------------------------------------------------------------
// prep_all: convert6 (blocks [0,1536)) U embed_k ([1536,5632)) U transpose_x
// ([5632,9728)). Independent work; branch is block-uniform.
// ---------------------------------------------------------------------------
__global__ __launch_bounds__(256) void prep_all(
    const float* __restrict__ a0, const float* __restrict__ a1,
    const float* __restrict__ a2, const float* __restrict__ a3,
    const float* __restrict__ a4, const float* __restrict__ a5,
    unsigned short* __restrict__ wdst, unsigned short* __restrict__ emb,
    const float* __restrict__ x, unsigned short* __restrict__ xt) {
  __shared__ float tile[32][33];
  const int bid = blockIdx.x;
  const int t = threadIdx.x;
  if (bid < 1536) {
    // convert6: six 256x256 fp32 weights -> contiguous bf16.
    int idx = bid * 256 + t;
    int m = idx >> 16, r = idx & 65535;
    const float* s;
    switch (m) {
      case 0: s = a0; break;
      case 1: s = a1; break;
      case 2: s = a2; break;
      case 3: s = a3; break;
      case 4: s = a4; break;
      default: s = a5; break;
    }
    wdst[idx] = f2bf(s[r]);
  } else if (bid < 5632) {
    // embed: e[t,d] = sin/cos(t * 10000^(-d/128)).
    int idx = (bid - 1536) * 256 + t;
    int tt_ = idx >> 8, d = idx & 255;
    float freq = exp2f((float)d * -0.10381025296573598f);
    float w = (float)tt_ * freq;
    float sn, cs;
    __sincosf(w, &sn, &cs);
    emb[idx] = f2bf((d & 1) ? cs : sn);
  } else {
    // transpose_x: x [4][256][4096] fp32 -> XT [4][4096][256] bf16.
    const int bid2 = bid - 5632;
    const int s0 = (bid2 & 127) * 32, c0 = ((bid2 >> 7) & 7) * 32;
    const int b = bid2 >> 10;
    const int tx = t & 31, ty = t >> 5;
    const float* xb = x + (long)b * 256 * 4096;
#pragma unroll
    for (int r = 0; r < 32; r += 8)
      tile[ty + r][tx] = xb[(long)(c0 + ty + r) * 4096 + s0 + tx];
    __syncthreads();
    unsigned short* xtb = xt + (long)b * 4096 * 256;
#pragma unroll
    for (int r = 0; r < 32; r += 8)
      xtb[(long)(s0 + ty + r) * 256 + c0 + tx] = f2bf(tile[tx][ty + r]);
  }
}

// ---------------------------------------------------------------------------
extern "C" void kernel_launch(void* const* d_in, const int* in_sizes, int n_in,
                              void* d_out, int out_size, void* d_ws,
                              size_t ws_size, hipStream_t stream) {
  const float* x  = (const float*)d_in[0];
  const float* wq = (const float*)d_in[1];
  const float* bq = (const float*)d_in[2];
  const float* wk = (const float*)d_in[3];
  const float* bk = (const float*)d_in[4];
  const float* wv = (const float*)d_in[5];
  const float* bv = (const float*)d_in[6];
  const float* wo = (const float*)d_in[7];
  const float* bo = (const float*)d_in[8];
  const float* w1 = (const float*)d_in[9];
  const float* b1 = (const float*)d_in[10];
  const float* w2 = (const float*)d_in[11];
  const float* b2 = (const float*)d_in[12];
  float* out = (float*)d_out;

  char* ws = (char*)d_ws;
  unsigned short* wqb = (unsigned short*)(ws + 0);         // 6x 256x256 bf16
  unsigned short* wkb = (unsigned short*)(ws + 131072);
  unsigned short* wvb = (unsigned short*)(ws + 262144);
  unsigned short* wob = (unsigned short*)(ws + 393216);
  unsigned short* w1b = (unsigned short*)(ws + 524288);
  unsigned short* w2b = (unsigned short*)(ws + 655360);
  unsigned short* emb = (unsigned short*)(ws + 786432);    // [4096][256] bf16
  unsigned short* h1b = (unsigned short*)(ws + 2883584);   // [4096][256] bf16
  float*          peF = (float*)(ws + 4980736);            // [4096][256] fp32
  unsigned short* XT  = (unsigned short*)(ws + 9175040);   // [4][4096][256]
  unsigned short* qT  = (unsigned short*)(ws + 17563648);  // [4][4096][256]
  unsigned short* kT  = (unsigned short*)(ws + 25952256);  // [4][4096][256]
  unsigned short* vB  = (unsigned short*)(ws + 34340864);  // [4][256][4096]
  float*          oP  = (float*)(ws + 51118080);           // [8][4096][256] f32
  float*          lP  = (float*)(ws + 84672512);           // [8][4096] f32
  (void)ws_size; (void)in_sizes; (void)n_in; (void)out_size;

  const dim3 B256(256);

  // convert6 U embed U transpose_x (independent; one launch).
  prep_all<<<9728, B256, 0, stream>>>(wq, wk, wv, wo, w1, w2, wqb, emb, x, XT);
  // pe MLP: h1 = silu(embed @ w1^T + b1); peF = h1 @ w2^T + b2  (fp32 out)
  gemm_nt<1, 2, 0, 1><<<dim3(32, 2, 1), B256, 0, stream>>>(
      emb, w1b, h1b, 256, 256, 256, 0, 0, 0, b1, nullptr, 1.0f);
  gemm_nt<0, 2, 0, 0><<<dim3(32, 2, 1), B256, 0, stream>>>(
      h1b, w2b, peF, 256, 256, 256, 0, 0, 0, b2, nullptr, 1.0f);
  // Fused q+k+v projections (ONE XT staging, v stored transposed).
  gemm_qkv<<<dim3(32, 2, 4), dim3(512), 0, stream>>>(
      XT, wqb, wkb, wvb, qT, kT, vB, bq, bk, bv, peF);
  // Fused attention: logits + softmax(axis i) + PV; i split across 2 blocks.
  flash_attn<<<256, dim3(512), 0, stream>>>(qT, kT, vB, oP, lP);
  // Output projection with fused i-half combine (oP read exactly once).
  gemm_out_f<<<dim3(1, 64, 4), B256, 0, stream>>>(wob, oP, lP, bo, out);
}

// Round 15
// 143.320 us; speedup vs baseline: 1.2612x; 1.0088x over previous
//
#include <hip/hip_runtime.h>
#include <cstdint>

// ---------------------------------------------------------------------------
// SAGAN self-attention block, bf16-MFMA pipeline, flash-fused attention.
// GEMMs are NT form: C[m,n] = sum_k Arow[m][k] * Brow[n][k].
// Verified fragment conventions (R2-passing gemm, 16x16x32):
//   A-frag: lane holds A[row = lane&15][k = (lane>>4)*8 + q], q=0..7
//   B-frag: lane holds B[col = lane&15][k = (lane>>4)*8 + q]
//   C/D:    lane holds C[row = (lane>>4)*4 + r][col = lane&15], r=0..3
// ---------------------------------------------------------------------------

typedef short s8v __attribute__((ext_vector_type(8)));   // 8 bf16 bits (4 VGPR)
typedef float f32x4 __attribute__((ext_vector_type(4)));

#define DEVI static __device__ __forceinline__

DEVI unsigned short f2bf(float f) {
  union { float f; uint32_t u; } x; x.f = f;
  uint32_t u = x.u;
  return (unsigned short)((u + 0x7fffu + ((u >> 16) & 1u)) >> 16);  // RNE
}

DEVI float bf2f(unsigned short u) {
  union { uint32_t u; float f; } x;
  x.u = (uint32_t)u << 16;
  return x.f;
}

DEVI void gl_lds16(const void* g, void* l) {
  // async global->LDS, 16B per lane; LDS dest must be wave-uniform base.
  __builtin_amdgcn_global_load_lds(
      (const __attribute__((address_space(1))) void*)g,
      (__attribute__((address_space(3))) void*)l,
      16, 0, 0);
}

// Stage a [64 rows][32 k] bf16 tile (4KB), linear LDS layout. t in 0..255.
DEVI void stage(const unsigned short* src, int ld, unsigned short* lds, int t) {
  gl_lds16(src + (long)(t >> 2) * ld + (t & 3) * 8, lds + (t >> 6) * 512);
}

// ---------------------------------------------------------------------------
// NT GEMM: 128x128 tile, 4 waves (2x2), each wave 64x64 = 4x4 frags of
// 16x16x32 bf16 MFMA. (Unchanged from R2/R3 passing version; used by MLP.)
// ---------------------------------------------------------------------------
template <int OBF, int BIAS, int PEM, int SILU>
__global__ __launch_bounds__(256) void gemm_nt(
    const unsigned short* __restrict__ A, const unsigned short* __restrict__ B,
    void* __restrict__ Cp, int K, int N, int ld, long sA, long sB, long sC,
    const float* __restrict__ bias, const float* __restrict__ pe, float scale) {
  const int bz = blockIdx.z;
  const unsigned short* Ab = A + (long)bz * sA;
  const unsigned short* Bb = B + (long)bz * sB;
  const int m0 = blockIdx.x * 128, n0 = blockIdx.y * 128;
  __shared__ __align__(16) unsigned short As[4096], Bs[4096];  // [128][32]
  const int t = threadIdx.x;
  const int wave = t >> 6, lane = t & 63;
  const int wr = wave >> 1, wc = wave & 1;

  f32x4 acc[4][4];
#pragma unroll
  for (int i = 0; i < 4; i++)
#pragma unroll
    for (int j = 0; j < 4; j++) acc[i][j] = f32x4{0.f, 0.f, 0.f, 0.f};

  const int rl = lane & 15, kp = (lane >> 4) * 8;

  for (int k0 = 0; k0 < K; k0 += 32) {
    stage(Ab + (long)m0 * ld + k0, ld, As, t);
    stage(Ab + (long)(m0 + 64) * ld + k0, ld, As + 2048, t);
    stage(Bb + (long)n0 * ld + k0, ld, Bs, t);
    stage(Bb + (long)(n0 + 64) * ld + k0, ld, Bs + 2048, t);
    __syncthreads();  // drains vmcnt before barrier -> LDS valid

    s8v af[4], bfr[4];
#pragma unroll
    for (int i = 0; i < 4; i++)
      af[i] = *(const s8v*)(As + (wr * 64 + i * 16 + rl) * 32 + kp);
#pragma unroll
    for (int j = 0; j < 4; j++)
      bfr[j] = *(const s8v*)(Bs + (wc * 64 + j * 16 + rl) * 32 + kp);
#pragma unroll
    for (int i = 0; i < 4; i++)
#pragma unroll
      for (int j = 0; j < 4; j++)
        acc[i][j] = __builtin_amdgcn_mfma_f32_16x16x32_bf16(af[i], bfr[j],
                                                            acc[i][j], 0, 0, 0);
    __syncthreads();
  }

  const long cb = (long)bz * sC;
#pragma unroll
  for (int i = 0; i < 4; i++) {
    const int r0 = m0 + wr * 64 + i * 16 + (lane >> 4) * 4;
#pragma unroll
    for (int j = 0; j < 4; j++) {
      const int col = n0 + wc * 64 + j * 16 + (lane & 15);
#pragma unroll
      for (int r = 0; r < 4; r++) {
        const int row = r0 + r;
        float val = acc[i][j][r] * scale;
        if (BIAS == 1) val += bias[row];
        if (BIAS == 2) val += bias[col];
        if (PEM == 1) val += pe[(long)row * 4096 + col];
        if (PEM == 2) val += pe[(long)col * 4096 + row];
        if (SILU) val = val / (1.0f + __expf(-val));
        const long ci = cb + (long)row * N + col;
        if (OBF)
          ((unsigned short*)Cp)[ci] = f2bf(val);
        else
          ((float*)Cp)[ci] = val;
      }
    }
  }
}

// ---------------------------------------------------------------------------
// Fused q+k+v projections. pe is now bf16 (halved read traffic).
// ---------------------------------------------------------------------------
__global__ __launch_bounds__(512) void gemm_qkv(
    const unsigned short* __restrict__ XT, const unsigned short* __restrict__ wqb,
    const unsigned short* __restrict__ wkb, const unsigned short* __restrict__ wvb,
    unsigned short* __restrict__ qT, unsigned short* __restrict__ kT,
    unsigned short* __restrict__ vB, const float* __restrict__ bq,
    const float* __restrict__ bk, const float* __restrict__ bv,
    const unsigned short* __restrict__ pe) {
  const int bz = blockIdx.z;
  const unsigned short* Ab = XT + (long)bz * 1048576;
  const int m0 = blockIdx.x * 128, n0 = blockIdx.y * 128;
  __shared__ __align__(16) unsigned short As[4096], Bq[4096], Bk[4096],
      Bv[4096];
  const int t = threadIdx.x;
  const int wave = t >> 6, lane = t & 63;
  const int wm = wave >> 2, wn = wave & 3;
  const int rl = lane & 15, kp = (lane >> 4) * 8;
  const int th = t >> 8, tt = t & 255;  // staging split: th picks tile half

  f32x4 aq[4][2], ak[4][2], av[4][2];
#pragma unroll
  for (int i = 0; i < 4; i++)
#pragma unroll
    for (int j = 0; j < 2; j++) {
      aq[i][j] = f32x4{0.f, 0.f, 0.f, 0.f};
      ak[i][j] = f32x4{0.f, 0.f, 0.f, 0.f};
      av[i][j] = f32x4{0.f, 0.f, 0.f, 0.f};
    }

  for (int k0 = 0; k0 < 256; k0 += 32) {
    const long ro = (long)(th * 64) * 256 + k0;
    stage(Ab + (long)m0 * 256 + ro, 256, As + th * 2048, tt);
    stage(wqb + (long)n0 * 256 + ro, 256, Bq + th * 2048, tt);
    stage(wkb + (long)n0 * 256 + ro, 256, Bk + th * 2048, tt);
    stage(wvb + (long)n0 * 256 + ro, 256, Bv + th * 2048, tt);
    __syncthreads();

    s8v af[4], b0[2], b1[2], b2[2];
#pragma unroll
    for (int i = 0; i < 4; i++)
      af[i] = *(const s8v*)(As + (wm * 64 + i * 16 + rl) * 32 + kp);
#pragma unroll
    for (int j = 0; j < 2; j++) {
      b0[j] = *(const s8v*)(Bq + (wn * 32 + j * 16 + rl) * 32 + kp);
      b1[j] = *(const s8v*)(Bk + (wn * 32 + j * 16 + rl) * 32 + kp);
      b2[j] = *(const s8v*)(Bv + (wn * 32 + j * 16 + rl) * 32 + kp);
    }
#pragma unroll
    for (int i = 0; i < 4; i++)
#pragma unroll
      for (int j = 0; j < 2; j++) {
        aq[i][j] = __builtin_amdgcn_mfma_f32_16x16x32_bf16(af[i], b0[j],
                                                           aq[i][j], 0, 0, 0);
        ak[i][j] = __builtin_amdgcn_mfma_f32_16x16x32_bf16(af[i], b1[j],
                                                           ak[i][j], 0, 0, 0);
        av[i][j] = __builtin_amdgcn_mfma_f32_16x16x32_bf16(af[i], b2[j],
                                                           av[i][j], 0, 0, 0);
      }
    __syncthreads();
  }

  const long cb = (long)bz * 1048576;
#pragma unroll
  for (int i = 0; i < 4; i++) {
    const int row0 = m0 + wm * 64 + i * 16 + (lane >> 4) * 4;
#pragma unroll
    for (int j = 0; j < 2; j++) {
      const int col = n0 + wn * 32 + j * 16 + rl;
      const ushort4 p4 = *(const ushort4*)(pe + (long)col * 4096 + row0);
      const float bqc = bq[col], bkc = bk[col], bvc = bv[col];
      ushort4 vpk;
      const float pv[4] = {bf2f(p4.x), bf2f(p4.y), bf2f(p4.z), bf2f(p4.w)};
#pragma unroll
      for (int r = 0; r < 4; r++) {
        const int row = row0 + r;
        qT[cb + (long)row * 256 + col] = f2bf(aq[i][j][r] + bqc + pv[r]);
        kT[cb + (long)row * 256 + col] = f2bf(ak[i][j][r] + bkc + pv[r]);
      }
      vpk.x = f2bf(av[i][j][0] + bvc + pv[0]);
      vpk.y = f2bf(av[i][j][1] + bvc + pv[1]);
      vpk.z = f2bf(av[i][j][2] + bvc + pv[2]);
      vpk.w = f2bf(av[i][j][3] + bvc + pv[3]);
      *(ushort4*)(vB + cb + (long)col * 4096 + row0) = vpk;
    }
  }
}

// ---------------------------------------------------------------------------
// Output projection with FUSED i-half combine, v3: grid (1,64,4); oPart is
// now bf16 (halved read traffic); sum + normalize in fp32.
// ---------------------------------------------------------------------------
__global__ __launch_bounds__(256) void gemm_out_f(
    const unsigned short* __restrict__ wob,
    const unsigned short* __restrict__ oPart, const float* __restrict__ lPart,
    const float* __restrict__ bo, float* __restrict__ out) {
  const int bz = blockIdx.z;          // batch
  const int n0 = blockIdx.y * 64;     // j cols (64 per block)
  __shared__ __align__(16) unsigned short As[8192], Bs[2048];
  // As: [4 tiles][64 m][32 k] = 256 o-rows; Bs: [64 j][32 k]
  const int t = threadIdx.x;
  const int wave = t >> 6, lane = t & 63;
  const int rl = lane & 15, kp = (lane >> 4) * 8;
  const int tr = t >> 2, tc8 = (t & 3) * 8;  // B fold: row 0..63, chunk

  f32x4 acc[4][4];
#pragma unroll
  for (int i = 0; i < 4; i++)
#pragma unroll
    for (int j = 0; j < 4; j++) acc[i][j] = f32x4{0.f, 0.f, 0.f, 0.f};

  const int j_ = n0 + tr;  // this thread's fixed fold row
  const float* l0p = lPart + (long)(bz * 2) * 4096;
  const float* l1p = lPart + (long)(bz * 2 + 1) * 4096;
  const float inv = 1.0f / (l0p[j_] + l1p[j_]);
  const unsigned short* oP0 = oPart + (long)(bz * 2) * 1048576;
  const unsigned short* oP1 = oPart + (long)(bz * 2 + 1) * 1048576;

  for (int k0 = 0; k0 < 256; k0 += 32) {
#pragma unroll
    for (int s_ = 0; s_ < 4; s_++)
      stage(wob + (long)(s_ * 64) * 256 + k0, 256, As + s_ * 2048, t);
    // B fold: resT row j_, c-chunk [k0+tc8, +8) from the 2 bf16 planes.
    {
      const s8v a8 = *(const s8v*)(oP0 + (long)j_ * 256 + k0 + tc8);
      const s8v d8 = *(const s8v*)(oP1 + (long)j_ * 256 + k0 + tc8);
      s8v pk;
#pragma unroll
      for (int e = 0; e < 8; e++)
        pk[e] = (short)f2bf((bf2f((unsigned short)a8[e]) +
                             bf2f((unsigned short)d8[e])) * inv);
      *(s8v*)(Bs + tr * 32 + tc8) = pk;
    }
    __syncthreads();  // drains vmcnt (A gl_lds) + lgkmcnt (B ds_write)

    s8v af[4], bfr[4];
#pragma unroll
    for (int i = 0; i < 4; i++)
      af[i] = *(const s8v*)(As + (wave * 64 + i * 16 + rl) * 32 + kp);
#pragma unroll
    for (int j = 0; j < 4; j++)
      bfr[j] = *(const s8v*)(Bs + (j * 16 + rl) * 32 + kp);
#pragma unroll
    for (int i = 0; i < 4; i++)
#pragma unroll
      for (int j = 0; j < 4; j++)
        acc[i][j] = __builtin_amdgcn_mfma_f32_16x16x32_bf16(af[i], bfr[j],
                                                            acc[i][j], 0, 0, 0);
    __syncthreads();
  }

  const long cb = (long)bz * 1048576;
#pragma unroll
  for (int i = 0; i < 4; i++) {
    const int r0 = wave * 64 + i * 16 + (lane >> 4) * 4;
#pragma unroll
    for (int j = 0; j < 4; j++) {
      const int col = n0 + j * 16 + (lane & 15);
#pragma unroll
      for (int r = 0; r < 4; r++) {
        const int row = r0 + r;
        out[cb + (long)row * 4096 + col] = acc[i][j][r] + bo[row];
      }
    }
  }
}

// ---------------------------------------------------------------------------
// Flash-fused attention v5 (champion, 93.5 us). Only change: oPart stores
// bf16 (halved epilogue write traffic). Loop/layouts byte-identical.
// ---------------------------------------------------------------------------
__global__ __launch_bounds__(512, 2) void flash_attn(
    const unsigned short* __restrict__ qTp, const unsigned short* __restrict__ kTp,
    const unsigned short* __restrict__ vBp, unsigned short* __restrict__ oPart,
    float* __restrict__ lPart) {
  const int bid = blockIdx.x;
  // XCD-aware mapping: xcd = bid&7 -> (b, ihalf); per-XCD L2 set ~4MB.
  const int xcd = bid & 7;
  const int b = xcd >> 1, ihalf = xcd & 1;
  const int j0 = (bid >> 3) * 128;
  const long S = 1048576;
  const long ibase = (long)ihalf * 2048;
  const unsigned short* q = qTp + (long)b * S;
  const unsigned short* k = kTp + (long)b * S;
  const unsigned short* v = vBp + (long)b * S;
  const int ob = b * 2 + ihalf;  // output plane

  // LDS: [0,64K) qL dbuf, [64K,128K) vL dbuf, [128K, +20480) pL.
  // Epilogue aliases: [0,128K) = O exchange (fp32), [128K,+512) = lsum exch.
  __shared__ __align__(16) unsigned char ldsb[151552];

  const int t = threadIdx.x;
  const int wave = t >> 6, lane = t & 63;
  const int jq = wave & 3, ch = wave >> 2;
  const int rl = lane & 15, g = lane >> 4;
  const int kp = g * 8;
  const int ksw = ((g ^ ((rl >> 1) & 3)) << 3);          // swizzled k-offset
  const int th = t >> 8, tt = t & 255;                   // staging split
  unsigned short* pL = (unsigned short*)(ldsb + 131072);
  unsigned short* pLw = pL + wave * 1280;                // [2 jf][16 j][40]

  // K-strip -> registers: wave owns rows j0 + jq*32 + jf*16 + rl.
  const unsigned short* krow = k + (long)(j0 + jq * 32 + rl) * 256 + kp;
  s8v kreg[2][8];
#pragma unroll
  for (int jf = 0; jf < 2; jf++)
#pragma unroll
    for (int s = 0; s < 8; s++)
      kreg[jf][s] = *(const s8v*)(krow + jf * 16 * 256 + s * 32);

  f32x4 oacc[2][16];
#pragma unroll
  for (int jf = 0; jf < 2; jf++)
#pragma unroll
    for (int cf = 0; cf < 16; cf++) oacc[jf][cf] = f32x4{0.f, 0.f, 0.f, 0.f};
  float plsum[2][4] = {{0.f, 0.f, 0.f, 0.f}, {0.f, 0.f, 0.f, 0.f}};

  // Pre-swizzled, pre-offset staging pointers (bumped per iter; source
  // swizzle: slot chunk c holds global chunk c ^ ((row>>1)&3); LDS linear).
  const int tr = tt >> 2, tc = tt & 3;
  const int sc = (tc ^ ((tr >> 1) & 3)) * 8;
  const unsigned short* qsrc[4];
  const unsigned short* vsrc[4];
  const int dsto = (tt >> 6) * 512;  // wave-uniform LDS sub-offset
#pragma unroll
  for (int ss = 0; ss < 4; ss++) {
    const int s_ = ss * 2 + th;
    qsrc[ss] = q + ibase * 256 + s_ * 32 + (long)tr * 256 + sc;
    vsrc[ss] = v + (long)((s_ >> 1) * 64) * 4096 + ibase + (s_ & 1) * 32 +
               (long)tr * 4096 + sc;
  }

#define STAGE_QV(bufsel)                                                     \
  {                                                                          \
    unsigned short* qD = (unsigned short*)(ldsb + ((bufsel) << 15));         \
    unsigned short* vD = (unsigned short*)(ldsb + 65536 + ((bufsel) << 15)); \
    _Pragma("unroll") for (int ss = 0; ss < 4; ss++) {                       \
      const int s_ = ss * 2 + th;                                            \
      gl_lds16(qsrc[ss], qD + s_ * 2048 + dsto);                             \
      gl_lds16(vsrc[ss], vD + s_ * 2048 + dsto);                             \
      qsrc[ss] += 16384;  /* next i-tile: +64*256 elems */                   \
      vsrc[ss] += 64;     /* next i-tile: +64 elems     */                   \
    }                                                                        \
  }

  STAGE_QV(0)

  for (int n = 0; n < 32; ++n) {
    const int cur = n & 1;
    __syncthreads();  // buf[cur] staged; all waves done with buf[cur^1]
    if (n + 1 < 32) STAGE_QV(cur ^ 1)  // overlaps with compute

    const unsigned short* qLb = (const unsigned short*)(ldsb + (cur << 15));
    const unsigned short* vLb =
        (const unsigned short*)(ldsb + 65536 + (cur << 15));

    // QK^T: own i-subhalf (32 i): 16 B-frag reads, 32 MFMA (2 jf x 2 if x 8s).
    f32x4 sa[2][2];
#pragma unroll
    for (int jf = 0; jf < 2; jf++)
#pragma unroll
      for (int f = 0; f < 2; f++) sa[jf][f] = f32x4{0.f, 0.f, 0.f, 0.f};
    const unsigned short* qbase = qLb + (ch * 32 + rl) * 32 + ksw;
#pragma unroll
    for (int s = 0; s < 8; s++) {
#pragma unroll
      for (int f = 0; f < 2; f++) {
        s8v bf = *(const s8v*)(qbase + s * 2048 + f * 512);
        sa[0][f] = __builtin_amdgcn_mfma_f32_16x16x32_bf16(kreg[0][s], bf,
                                                           sa[0][f], 0, 0, 0);
        sa[1][f] = __builtin_amdgcn_mfma_f32_16x16x32_bf16(kreg[1][s], bf,
                                                           sa[1][f], 0, 0, 0);
      }
    }

    // Static-max softmax (|logit| << 88), deferred lsum; P -> wave-private
    // LDS in A-frag layout, padded row stride 40 (<=2-way conflicts).
#pragma unroll
    for (int jf = 0; jf < 2; jf++)
#pragma unroll
      for (int f = 0; f < 2; f++)
#pragma unroll
        for (int r = 0; r < 4; r++) {
          const float p = __expf(sa[jf][f][r] * 0.0625f);
          plsum[jf][r] += p;
          pLw[jf * 640 + (g * 4 + r) * 40 + f * 16 + rl] = f2bf(p);
        }

    // PV over own i-subhalf (K=32): 16 v-frag reads, 32 MFMA (16 cf x 2 jf).
    s8v pa0 = *(const s8v*)(pLw + rl * 40 + kp);
    s8v pa1 = *(const s8v*)(pLw + 640 + rl * 40 + kp);
    const unsigned short* vbase = vLb + ch * 2048 + rl * 32 + ksw;
#pragma unroll
    for (int cf = 0; cf < 16; cf++) {
      s8v vb = *(const s8v*)(vbase + (cf >> 2) * 4096 + (cf & 3) * 512);
      oacc[0][cf] = __builtin_amdgcn_mfma_f32_16x16x32_bf16(pa0, vb,
                                                            oacc[0][cf], 0, 0, 0);
      oacc[1][cf] = __builtin_amdgcn_mfma_f32_16x16x32_bf16(pa1, vb,
                                                            oacc[1][cf], 0, 0, 0);
    }
  }

  // Deferred lsum: butterfly over the 16-lane i-groups.
#pragma unroll
  for (int jf = 0; jf < 2; jf++)
#pragma unroll
    for (int r = 0; r < 4; r++) {
      plsum[jf][r] += __shfl_xor(plsum[jf][r], 1);
      plsum[jf][r] += __shfl_xor(plsum[jf][r], 2);
      plsum[jf][r] += __shfl_xor(plsum[jf][r], 4);
      plsum[jf][r] += __shfl_xor(plsum[jf][r], 8);
    }

  // Merge ch-pairs (complementary i-subhalves) through LDS, then write
  // unnormalized O-partials (bf16) + lsum partials (fp32).
  __syncthreads();  // loop LDS dead; safe to alias
  float* ex = (float*)ldsb;             // [4 jq][32 j][256 c]
  float* exl = (float*)(ldsb + 131072); // [4 jq][32 j]
  if (ch == 1) {
    float* exw = ex + jq * 8192;
#pragma unroll
    for (int jf = 0; jf < 2; jf++) {
#pragma unroll
      for (int cf = 0; cf < 16; cf++)
#pragma unroll
        for (int r = 0; r < 4; r++)
          exw[(jf * 16 + g * 4 + r) * 256 + cf * 16 + rl] = oacc[jf][cf][r];
      if (rl == 0) {
#pragma unroll
        for (int r = 0; r < 4; r++)
          exl[jq * 32 + jf * 16 + g * 4 + r] = plsum[jf][r];
      }
    }
  }
  __syncthreads();
  if (ch == 0) {
    float* exw = ex + jq * 8192;
    unsigned short* op = oPart + (long)ob * 1048576;
#pragma unroll
    for (int jf = 0; jf < 2; jf++) {
      if (rl == 0) {
#pragma unroll
        for (int r = 0; r < 4; r++) {
          const int jl = jq * 32 + jf * 16 + g * 4 + r;
          lPart[(long)ob * 4096 + j0 + jl] = plsum[jf][r] + exl[jl];
        }
      }
#pragma unroll
      for (int cf = 0; cf < 16; cf++)
#pragma unroll
        for (int r = 0; r < 4; r++) {
          const int jl2 = jf * 16 + g * 4 + r;
          op[(long)(j0 + jq * 32 + jl2) * 256 + cf * 16 + rl] =
              f2bf(oacc[jf][cf][r] + exw[jl2 * 256 + cf * 16 + rl]);
        }
    }
  }
#undef STAGE_QV
}

// ---------------------------------------------------------------------------
// prep_all: convert6 (blocks [0,1536)) U embed_k ([1536,5632)) U transpose_x
// ([5632,9728)). Independent work; branch is block-uniform.
// ---------------------------------------------------------------------------
__global__ __launch_bounds__(256) void prep_all(
    const float* __restrict__ a0, const float* __restrict__ a1,
    const float* __restrict__ a2, const float* __restrict__ a3,
    const float* __restrict__ a4, const float* __restrict__ a5,
    unsigned short* __restrict__ wdst, unsigned short* __restrict__ emb,
    const float* __restrict__ x, unsigned short* __restrict__ xt) {
  __shared__ float tile[32][33];
  const int bid = blockIdx.x;
  const int t = threadIdx.x;
  if (bid < 1536) {
    // convert6: six 256x256 fp32 weights -> contiguous bf16.
    int idx = bid * 256 + t;
    int m = idx >> 16, r = idx & 65535;
    const float* s;
    switch (m) {
      case 0: s = a0; break;
      case 1: s = a1; break;
      case 2: s = a2; break;
      case 3: s = a3; break;
      case 4: s = a4; break;
      default: s = a5; break;
    }
    wdst[idx] = f2bf(s[r]);
  } else if (bid < 5632) {
    // embed: e[t,d] = sin/cos(t * 10000^(-d/128)).
    int idx = (bid - 1536) * 256 + t;
    int tt_ = idx >> 8, d = idx & 255;
    float freq = exp2f((float)d * -0.10381025296573598f);
    float w = (float)tt_ * freq;
    float sn, cs;
    __sincosf(w, &sn, &cs);
    emb[idx] = f2bf((d & 1) ? cs : sn);
  } else {
    // transpose_x: x [4][256][4096] fp32 -> XT [4][4096][256] bf16.
    const int bid2 = bid - 5632;
    const int s0 = (bid2 & 127) * 32, c0 = ((bid2 >> 7) & 7) * 32;
    const int b = bid2 >> 10;
    const int tx = t & 31, ty = t >> 5;
    const float* xb = x + (long)b * 256 * 4096;
#pragma unroll
    for (int r = 0; r < 32; r += 8)
      tile[ty + r][tx] = xb[(long)(c0 + ty + r) * 4096 + s0 + tx];
    __syncthreads();
    unsigned short* xtb = xt + (long)b * 4096 * 256;
#pragma unroll
    for (int r = 0; r < 32; r += 8)
      xtb[(long)(s0 + ty + r) * 256 + c0 + tx] = f2bf(tile[tx][ty + r]);
  }
}

// ---------------------------------------------------------------------------
extern "C" void kernel_launch(void* const* d_in, const int* in_sizes, int n_in,
                              void* d_out, int out_size, void* d_ws,
                              size_t ws_size, hipStream_t stream) {
  const float* x  = (const float*)d_in[0];
  const float* wq = (const float*)d_in[1];
  const float* bq = (const float*)d_in[2];
  const float* wk = (const float*)d_in[3];
  const float* bk = (const float*)d_in[4];
  const float* wv = (const float*)d_in[5];
  const float* bv = (const float*)d_in[6];
  const float* wo = (const float*)d_in[7];
  const float* bo = (const float*)d_in[8];
  const float* w1 = (const float*)d_in[9];
  const float* b1 = (const float*)d_in[10];
  const float* w2 = (const float*)d_in[11];
  const float* b2 = (const float*)d_in[12];
  float* out = (float*)d_out;

  char* ws = (char*)d_ws;
  unsigned short* wqb = (unsigned short*)(ws + 0);         // 6x 256x256 bf16
  unsigned short* wkb = (unsigned short*)(ws + 131072);
  unsigned short* wvb = (unsigned short*)(ws + 262144);
  unsigned short* wob = (unsigned short*)(ws + 393216);
  unsigned short* w1b = (unsigned short*)(ws + 524288);
  unsigned short* w2b = (unsigned short*)(ws + 655360);
  unsigned short* emb = (unsigned short*)(ws + 786432);    // [4096][256] bf16
  unsigned short* h1b = (unsigned short*)(ws + 2883584);   // [4096][256] bf16
  unsigned short* peB = (unsigned short*)(ws + 4980736);   // [4096][256] bf16
  unsigned short* XT  = (unsigned short*)(ws + 9175040);   // [4][4096][256]
  unsigned short* qT  = (unsigned short*)(ws + 17563648);  // [4][4096][256]
  unsigned short* kT  = (unsigned short*)(ws + 25952256);  // [4][4096][256]
  unsigned short* vB  = (unsigned short*)(ws + 34340864);  // [4][256][4096]
  unsigned short* oP  = (unsigned short*)(ws + 51118080);  // [8][4096][256] bf16
  float*          lP  = (float*)(ws + 84672512);           // [8][4096] f32
  (void)ws_size; (void)in_sizes; (void)n_in; (void)out_size;

  const dim3 B256(256);

  // convert6 U embed U transpose_x (independent; one launch).
  prep_all<<<9728, B256, 0, stream>>>(wq, wk, wv, wo, w1, w2, wqb, emb, x, XT);
  // pe MLP: h1 = silu(embed @ w1^T + b1); peB = h1 @ w2^T + b2  (bf16 out)
  gemm_nt<1, 2, 0, 1><<<dim3(32, 2, 1), B256, 0, stream>>>(
      emb, w1b, h1b, 256, 256, 256, 0, 0, 0, b1, nullptr, 1.0f);
  gemm_nt<1, 2, 0, 0><<<dim3(32, 2, 1), B256, 0, stream>>>(
      h1b, w2b, peB, 256, 256, 256, 0, 0, 0, b2, nullptr, 1.0f);
  // Fused q+k+v projections (ONE XT staging, v stored transposed; pe bf16).
  gemm_qkv<<<dim3(32, 2, 4), dim3(512), 0, stream>>>(
      XT, wqb, wkb, wvb, qT, kT, vB, bq, bk, bv, peB);
  // Fused attention: logits + softmax(axis i) + PV; i split across 2 blocks.
  flash_attn<<<256, dim3(512), 0, stream>>>(qT, kT, vB, oP, lP);
  // Output projection with fused i-half combine (oP bf16, read once).
  gemm_out_f<<<dim3(1, 64, 4), B256, 0, stream>>>(wob, oP, lP, bo, out);
}

// Round 16
// 139.339 us; speedup vs baseline: 1.2973x; 1.0286x over previous
//
#include <hip/hip_runtime.h>
#include <cstdint>

// ---------------------------------------------------------------------------
// SAGAN self-attention block, bf16-MFMA pipeline, flash-fused attention.
// GEMMs are NT form: C[m,n] = sum_k Arow[m][k] * Brow[n][k].
// Verified fragment conventions (R2-passing gemm, 16x16x32):
//   A-frag: lane holds A[row = lane&15][k = (lane>>4)*8 + q], q=0..7
//   B-frag: lane holds B[col = lane&15][k = (lane>>4)*8 + q]
//   C/D:    lane holds C[row = (lane>>4)*4 + r][col = lane&15], r=0..3
// ---------------------------------------------------------------------------

typedef short s8v __attribute__((ext_vector_type(8)));   // 8 bf16 bits (4 VGPR)
typedef float f32x4 __attribute__((ext_vector_type(4)));

#define DEVI static __device__ __forceinline__

DEVI unsigned short f2bf(float f) {
  union { float f; uint32_t u; } x; x.f = f;
  uint32_t u = x.u;
  return (unsigned short)((u + 0x7fffu + ((u >> 16) & 1u)) >> 16);  // RNE
}

DEVI float bf2f(unsigned short u) {
  union { uint32_t u; float f; } x;
  x.u = (uint32_t)u << 16;
  return x.f;
}

DEVI void gl_lds16(const void* g, void* l) {
  // async global->LDS, 16B per lane; LDS dest must be wave-uniform base.
  __builtin_amdgcn_global_load_lds(
      (const __attribute__((address_space(1))) void*)g,
      (__attribute__((address_space(3))) void*)l,
      16, 0, 0);
}

// Stage a [64 rows][32 k] bf16 tile (4KB), linear LDS layout. t in 0..255.
DEVI void stage(const unsigned short* src, int ld, unsigned short* lds, int t) {
  gl_lds16(src + (long)(t >> 2) * ld + (t & 3) * 8, lds + (t >> 6) * 512);
}

// ---------------------------------------------------------------------------
// Fused positional-embedding MLP: ONE kernel, h1 never leaves LDS.
//   h1[s][o1] = silu(emb[s][:] . w1[o1][:] + b1[o1])      (phase 1)
//   peB[s][o2] = h1[s][:] . w2[o2][:] + b2[o2]            (phase 2, bf16)
// Block = 64 s-rows; 4 waves; wave wc owns cols [wc*64, +64) (verbatim
// 64x64 per-wave fragment math of the verified gemm). h1 lives in LDS as
// [64][264] bf16 (padded stride: phase-2 A-reads are 2-way-conflict-free).
// Numerics identical to the old two-launch path (same f2bf/silu points).
// ---------------------------------------------------------------------------
__global__ __launch_bounds__(256) void mlp_pe(
    const unsigned short* __restrict__ emb, const unsigned short* __restrict__ w1b,
    const unsigned short* __restrict__ w2b, const float* __restrict__ b1,
    const float* __restrict__ b2, unsigned short* __restrict__ peB) {
  const int m0 = blockIdx.x * 64;
  __shared__ __align__(16) unsigned short As[2048];   // [64][32]
  __shared__ __align__(16) unsigned short Bs[8192];   // [256 n][32]
  __shared__ __align__(16) unsigned short h1L[16896]; // [64][264] padded
  const int t = threadIdx.x;
  const int wave = t >> 6, lane = t & 63;
  const int wc = wave;  // n-quarter
  const int rl = lane & 15, g = lane >> 4, kp = g * 8;

  // ---- Phase 1: h1 = silu(emb @ w1^T + b1), 64 x 256 ----
  f32x4 acc[4][4];
#pragma unroll
  for (int i = 0; i < 4; i++)
#pragma unroll
    for (int j = 0; j < 4; j++) acc[i][j] = f32x4{0.f, 0.f, 0.f, 0.f};

  for (int k0 = 0; k0 < 256; k0 += 32) {
    stage(emb + (long)m0 * 256 + k0, 256, As, t);
#pragma unroll
    for (int q = 0; q < 4; q++)
      stage(w1b + (long)(q * 64) * 256 + k0, 256, Bs + q * 2048, t);
    __syncthreads();

    s8v af[4], bfr[4];
#pragma unroll
    for (int i = 0; i < 4; i++)
      af[i] = *(const s8v*)(As + (i * 16 + rl) * 32 + kp);
#pragma unroll
    for (int j = 0; j < 4; j++)
      bfr[j] = *(const s8v*)(Bs + (wc * 64 + j * 16 + rl) * 32 + kp);
#pragma unroll
    for (int i = 0; i < 4; i++)
#pragma unroll
      for (int j = 0; j < 4; j++)
        acc[i][j] = __builtin_amdgcn_mfma_f32_16x16x32_bf16(af[i], bfr[j],
                                                            acc[i][j], 0, 0, 0);
    __syncthreads();
  }

  // h1 -> LDS with bias+silu (bf16, same rounding as old OBF=1 path).
#pragma unroll
  for (int i = 0; i < 4; i++) {
    const int r0 = i * 16 + g * 4;
#pragma unroll
    for (int j = 0; j < 4; j++) {
      const int col = wc * 64 + j * 16 + rl;
      const float bc = b1[col];
#pragma unroll
      for (int r = 0; r < 4; r++) {
        float val = acc[i][j][r] + bc;
        val = val / (1.0f + __expf(-val));
        h1L[(r0 + r) * 264 + col] = f2bf(val);
      }
    }
  }

  // ---- Phase 2: peB = h1 @ w2^T + b2, 64 x 256 ----
  f32x4 ac2[4][4];
#pragma unroll
  for (int i = 0; i < 4; i++)
#pragma unroll
    for (int j = 0; j < 4; j++) ac2[i][j] = f32x4{0.f, 0.f, 0.f, 0.f};

  for (int k0 = 0; k0 < 256; k0 += 32) {
#pragma unroll
    for (int q = 0; q < 4; q++)
      stage(w2b + (long)(q * 64) * 256 + k0, 256, Bs + q * 2048, t);
    __syncthreads();  // also guards h1L writes (lgkmcnt drained at barrier)

    s8v af[4], bfr[4];
#pragma unroll
    for (int i = 0; i < 4; i++)
      af[i] = *(const s8v*)(h1L + (i * 16 + rl) * 264 + k0 + kp);
#pragma unroll
    for (int j = 0; j < 4; j++)
      bfr[j] = *(const s8v*)(Bs + (wc * 64 + j * 16 + rl) * 32 + kp);
#pragma unroll
    for (int i = 0; i < 4; i++)
#pragma unroll
      for (int j = 0; j < 4; j++)
        ac2[i][j] = __builtin_amdgcn_mfma_f32_16x16x32_bf16(af[i], bfr[j],
                                                            ac2[i][j], 0, 0, 0);
    __syncthreads();
  }

#pragma unroll
  for (int i = 0; i < 4; i++) {
    const int r0 = m0 + i * 16 + g * 4;
#pragma unroll
    for (int j = 0; j < 4; j++) {
      const int col = wc * 64 + j * 16 + rl;
      const float bc = b2[col];
#pragma unroll
      for (int r = 0; r < 4; r++)
        peB[(long)(r0 + r) * 256 + col] = f2bf(ac2[i][j][r] + bc);
    }
  }
}

// ---------------------------------------------------------------------------
// Fused q+k+v projections (unchanged from R15).
// ---------------------------------------------------------------------------
__global__ __launch_bounds__(512) void gemm_qkv(
    const unsigned short* __restrict__ XT, const unsigned short* __restrict__ wqb,
    const unsigned short* __restrict__ wkb, const unsigned short* __restrict__ wvb,
    unsigned short* __restrict__ qT, unsigned short* __restrict__ kT,
    unsigned short* __restrict__ vB, const float* __restrict__ bq,
    const float* __restrict__ bk, const float* __restrict__ bv,
    const unsigned short* __restrict__ pe) {
  const int bz = blockIdx.z;
  const unsigned short* Ab = XT + (long)bz * 1048576;
  const int m0 = blockIdx.x * 128, n0 = blockIdx.y * 128;
  __shared__ __align__(16) unsigned short As[4096], Bq[4096], Bk[4096],
      Bv[4096];
  const int t = threadIdx.x;
  const int wave = t >> 6, lane = t & 63;
  const int wm = wave >> 2, wn = wave & 3;
  const int rl = lane & 15, kp = (lane >> 4) * 8;
  const int th = t >> 8, tt = t & 255;  // staging split: th picks tile half

  f32x4 aq[4][2], ak[4][2], av[4][2];
#pragma unroll
  for (int i = 0; i < 4; i++)
#pragma unroll
    for (int j = 0; j < 2; j++) {
      aq[i][j] = f32x4{0.f, 0.f, 0.f, 0.f};
      ak[i][j] = f32x4{0.f, 0.f, 0.f, 0.f};
      av[i][j] = f32x4{0.f, 0.f, 0.f, 0.f};
    }

  for (int k0 = 0; k0 < 256; k0 += 32) {
    const long ro = (long)(th * 64) * 256 + k0;
    stage(Ab + (long)m0 * 256 + ro, 256, As + th * 2048, tt);
    stage(wqb + (long)n0 * 256 + ro, 256, Bq + th * 2048, tt);
    stage(wkb + (long)n0 * 256 + ro, 256, Bk + th * 2048, tt);
    stage(wvb + (long)n0 * 256 + ro, 256, Bv + th * 2048, tt);
    __syncthreads();

    s8v af[4], b0[2], b1v[2], b2v[2];
#pragma unroll
    for (int i = 0; i < 4; i++)
      af[i] = *(const s8v*)(As + (wm * 64 + i * 16 + rl) * 32 + kp);
#pragma unroll
    for (int j = 0; j < 2; j++) {
      b0[j] = *(const s8v*)(Bq + (wn * 32 + j * 16 + rl) * 32 + kp);
      b1v[j] = *(const s8v*)(Bk + (wn * 32 + j * 16 + rl) * 32 + kp);
      b2v[j] = *(const s8v*)(Bv + (wn * 32 + j * 16 + rl) * 32 + kp);
    }
#pragma unroll
    for (int i = 0; i < 4; i++)
#pragma unroll
      for (int j = 0; j < 2; j++) {
        aq[i][j] = __builtin_amdgcn_mfma_f32_16x16x32_bf16(af[i], b0[j],
                                                           aq[i][j], 0, 0, 0);
        ak[i][j] = __builtin_amdgcn_mfma_f32_16x16x32_bf16(af[i], b1v[j],
                                                           ak[i][j], 0, 0, 0);
        av[i][j] = __builtin_amdgcn_mfma_f32_16x16x32_bf16(af[i], b2v[j],
                                                           av[i][j], 0, 0, 0);
      }
    __syncthreads();
  }

  const long cb = (long)bz * 1048576;
#pragma unroll
  for (int i = 0; i < 4; i++) {
    const int row0 = m0 + wm * 64 + i * 16 + (lane >> 4) * 4;
#pragma unroll
    for (int j = 0; j < 2; j++) {
      const int col = n0 + wn * 32 + j * 16 + rl;
      const ushort4 p4 = *(const ushort4*)(pe + (long)col * 4096 + row0);
      const float bqc = bq[col], bkc = bk[col], bvc = bv[col];
      ushort4 vpk;
      const float pv[4] = {bf2f(p4.x), bf2f(p4.y), bf2f(p4.z), bf2f(p4.w)};
#pragma unroll
      for (int r = 0; r < 4; r++) {
        const int row = row0 + r;
        qT[cb + (long)row * 256 + col] = f2bf(aq[i][j][r] + bqc + pv[r]);
        kT[cb + (long)row * 256 + col] = f2bf(ak[i][j][r] + bkc + pv[r]);
      }
      vpk.x = f2bf(av[i][j][0] + bvc + pv[0]);
      vpk.y = f2bf(av[i][j][1] + bvc + pv[1]);
      vpk.z = f2bf(av[i][j][2] + bvc + pv[2]);
      vpk.w = f2bf(av[i][j][3] + bvc + pv[3]);
      *(ushort4*)(vB + cb + (long)col * 4096 + row0) = vpk;
    }
  }
}

// ---------------------------------------------------------------------------
// Output projection with FUSED i-half combine (unchanged from R15).
// ---------------------------------------------------------------------------
__global__ __launch_bounds__(256) void gemm_out_f(
    const unsigned short* __restrict__ wob,
    const unsigned short* __restrict__ oPart, const float* __restrict__ lPart,
    const float* __restrict__ bo, float* __restrict__ out) {
  const int bz = blockIdx.z;          // batch
  const int n0 = blockIdx.y * 64;     // j cols (64 per block)
  __shared__ __align__(16) unsigned short As[8192], Bs[2048];
  // As: [4 tiles][64 m][32 k] = 256 o-rows; Bs: [64 j][32 k]
  const int t = threadIdx.x;
  const int wave = t >> 6, lane = t & 63;
  const int rl = lane & 15, kp = (lane >> 4) * 8;
  const int tr = t >> 2, tc8 = (t & 3) * 8;  // B fold: row 0..63, chunk

  f32x4 acc[4][4];
#pragma unroll
  for (int i = 0; i < 4; i++)
#pragma unroll
    for (int j = 0; j < 4; j++) acc[i][j] = f32x4{0.f, 0.f, 0.f, 0.f};

  const int j_ = n0 + tr;  // this thread's fixed fold row
  const float* l0p = lPart + (long)(bz * 2) * 4096;
  const float* l1p = lPart + (long)(bz * 2 + 1) * 4096;
  const float inv = 1.0f / (l0p[j_] + l1p[j_]);
  const unsigned short* oP0 = oPart + (long)(bz * 2) * 1048576;
  const unsigned short* oP1 = oPart + (long)(bz * 2 + 1) * 1048576;

  for (int k0 = 0; k0 < 256; k0 += 32) {
#pragma unroll
    for (int s_ = 0; s_ < 4; s_++)
      stage(wob + (long)(s_ * 64) * 256 + k0, 256, As + s_ * 2048, t);
    // B fold: resT row j_, c-chunk [k0+tc8, +8) from the 2 bf16 planes.
    {
      const s8v a8 = *(const s8v*)(oP0 + (long)j_ * 256 + k0 + tc8);
      const s8v d8 = *(const s8v*)(oP1 + (long)j_ * 256 + k0 + tc8);
      s8v pk;
#pragma unroll
      for (int e = 0; e < 8; e++)
        pk[e] = (short)f2bf((bf2f((unsigned short)a8[e]) +
                             bf2f((unsigned short)d8[e])) * inv);
      *(s8v*)(Bs + tr * 32 + tc8) = pk;
    }
    __syncthreads();  // drains vmcnt (A gl_lds) + lgkmcnt (B ds_write)

    s8v af[4], bfr[4];
#pragma unroll
    for (int i = 0; i < 4; i++)
      af[i] = *(const s8v*)(As + (wave * 64 + i * 16 + rl) * 32 + kp);
#pragma unroll
    for (int j = 0; j < 4; j++)
      bfr[j] = *(const s8v*)(Bs + (j * 16 + rl) * 32 + kp);
#pragma unroll
    for (int i = 0; i < 4; i++)
#pragma unroll
      for (int j = 0; j < 4; j++)
        acc[i][j] = __builtin_amdgcn_mfma_f32_16x16x32_bf16(af[i], bfr[j],
                                                            acc[i][j], 0, 0, 0);
    __syncthreads();
  }

  const long cb = (long)bz * 1048576;
#pragma unroll
  for (int i = 0; i < 4; i++) {
    const int r0 = wave * 64 + i * 16 + (lane >> 4) * 4;
#pragma unroll
    for (int j = 0; j < 4; j++) {
      const int col = n0 + j * 16 + (lane & 15);
#pragma unroll
      for (int r = 0; r < 4; r++) {
        const int row = r0 + r;
        out[cb + (long)row * 4096 + col] = acc[i][j][r] + bo[row];
      }
    }
  }
}

// ---------------------------------------------------------------------------
// Flash-fused attention v5 (champion; bf16 oPart). Unchanged from R15.
// ---------------------------------------------------------------------------
__global__ __launch_bounds__(512, 2) void flash_attn(
    const unsigned short* __restrict__ qTp, const unsigned short* __restrict__ kTp,
    const unsigned short* __restrict__ vBp, unsigned short* __restrict__ oPart,
    float* __restrict__ lPart) {
  const int bid = blockIdx.x;
  // XCD-aware mapping: xcd = bid&7 -> (b, ihalf); per-XCD L2 set ~4MB.
  const int xcd = bid & 7;
  const int b = xcd >> 1, ihalf = xcd & 1;
  const int j0 = (bid >> 3) * 128;
  const long S = 1048576;
  const long ibase = (long)ihalf * 2048;
  const unsigned short* q = qTp + (long)b * S;
  const unsigned short* k = kTp + (long)b * S;
  const unsigned short* v = vBp + (long)b * S;
  const int ob = b * 2 + ihalf;  // output plane

  // LDS: [0,64K) qL dbuf, [64K,128K) vL dbuf, [128K, +20480) pL.
  // Epilogue aliases: [0,128K) = O exchange (fp32), [128K,+512) = lsum exch.
  __shared__ __align__(16) unsigned char ldsb[151552];

  const int t = threadIdx.x;
  const int wave = t >> 6, lane = t & 63;
  const int jq = wave & 3, ch = wave >> 2;
  const int rl = lane & 15, g = lane >> 4;
  const int kp = g * 8;
  const int ksw = ((g ^ ((rl >> 1) & 3)) << 3);          // swizzled k-offset
  const int th = t >> 8, tt = t & 255;                   // staging split
  unsigned short* pL = (unsigned short*)(ldsb + 131072);
  unsigned short* pLw = pL + wave * 1280;                // [2 jf][16 j][40]

  // K-strip -> registers: wave owns rows j0 + jq*32 + jf*16 + rl.
  const unsigned short* krow = k + (long)(j0 + jq * 32 + rl) * 256 + kp;
  s8v kreg[2][8];
#pragma unroll
  for (int jf = 0; jf < 2; jf++)
#pragma unroll
    for (int s = 0; s < 8; s++)
      kreg[jf][s] = *(const s8v*)(krow + jf * 16 * 256 + s * 32);

  f32x4 oacc[2][16];
#pragma unroll
  for (int jf = 0; jf < 2; jf++)
#pragma unroll
    for (int cf = 0; cf < 16; cf++) oacc[jf][cf] = f32x4{0.f, 0.f, 0.f, 0.f};
  float plsum[2][4] = {{0.f, 0.f, 0.f, 0.f}, {0.f, 0.f, 0.f, 0.f}};

  // Pre-swizzled, pre-offset staging pointers (bumped per iter; source
  // swizzle: slot chunk c holds global chunk c ^ ((row>>1)&3); LDS linear).
  const int tr = tt >> 2, tc = tt & 3;
  const int sc = (tc ^ ((tr >> 1) & 3)) * 8;
  const unsigned short* qsrc[4];
  const unsigned short* vsrc[4];
  const int dsto = (tt >> 6) * 512;  // wave-uniform LDS sub-offset
#pragma unroll
  for (int ss = 0; ss < 4; ss++) {
    const int s_ = ss * 2 + th;
    qsrc[ss] = q + ibase * 256 + s_ * 32 + (long)tr * 256 + sc;
    vsrc[ss] = v + (long)((s_ >> 1) * 64) * 4096 + ibase + (s_ & 1) * 32 +
               (long)tr * 4096 + sc;
  }

#define STAGE_QV(bufsel)                                                     \
  {                                                                          \
    unsigned short* qD = (unsigned short*)(ldsb + ((bufsel) << 15));         \
    unsigned short* vD = (unsigned short*)(ldsb + 65536 + ((bufsel) << 15)); \
    _Pragma("unroll") for (int ss = 0; ss < 4; ss++) {                       \
      const int s_ = ss * 2 + th;                                            \
      gl_lds16(qsrc[ss], qD + s_ * 2048 + dsto);                             \
      gl_lds16(vsrc[ss], vD + s_ * 2048 + dsto);                             \
      qsrc[ss] += 16384;  /* next i-tile: +64*256 elems */                   \
      vsrc[ss] += 64;     /* next i-tile: +64 elems     */                   \
    }                                                                        \
  }

  STAGE_QV(0)

  for (int n = 0; n < 32; ++n) {
    const int cur = n & 1;
    __syncthreads();  // buf[cur] staged; all waves done with buf[cur^1]
    if (n + 1 < 32) STAGE_QV(cur ^ 1)  // overlaps with compute

    const unsigned short* qLb = (const unsigned short*)(ldsb + (cur << 15));
    const unsigned short* vLb =
        (const unsigned short*)(ldsb + 65536 + (cur << 15));

    // QK^T: own i-subhalf (32 i): 16 B-frag reads, 32 MFMA (2 jf x 2 if x 8s).
    f32x4 sa[2][2];
#pragma unroll
    for (int jf = 0; jf < 2; jf++)
#pragma unroll
      for (int f = 0; f < 2; f++) sa[jf][f] = f32x4{0.f, 0.f, 0.f, 0.f};
    const unsigned short* qbase = qLb + (ch * 32 + rl) * 32 + ksw;
#pragma unroll
    for (int s = 0; s < 8; s++) {
#pragma unroll
      for (int f = 0; f < 2; f++) {
        s8v bf = *(const s8v*)(qbase + s * 2048 + f * 512);
        sa[0][f] = __builtin_amdgcn_mfma_f32_16x16x32_bf16(kreg[0][s], bf,
                                                           sa[0][f], 0, 0, 0);
        sa[1][f] = __builtin_amdgcn_mfma_f32_16x16x32_bf16(kreg[1][s], bf,
                                                           sa[1][f], 0, 0, 0);
      }
    }

    // Static-max softmax (|logit| << 88), deferred lsum; P -> wave-private
    // LDS in A-frag layout, padded row stride 40 (<=2-way conflicts).
#pragma unroll
    for (int jf = 0; jf < 2; jf++)
#pragma unroll
      for (int f = 0; f < 2; f++)
#pragma unroll
        for (int r = 0; r < 4; r++) {
          const float p = __expf(sa[jf][f][r] * 0.0625f);
          plsum[jf][r] += p;
          pLw[jf * 640 + (g * 4 + r) * 40 + f * 16 + rl] = f2bf(p);
        }

    // PV over own i-subhalf (K=32): 16 v-frag reads, 32 MFMA (16 cf x 2 jf).
    s8v pa0 = *(const s8v*)(pLw + rl * 40 + kp);
    s8v pa1 = *(const s8v*)(pLw + 640 + rl * 40 + kp);
    const unsigned short* vbase = vLb + ch * 2048 + rl * 32 + ksw;
#pragma unroll
    for (int cf = 0; cf < 16; cf++) {
      s8v vb = *(const s8v*)(vbase + (cf >> 2) * 4096 + (cf & 3) * 512);
      oacc[0][cf] = __builtin_amdgcn_mfma_f32_16x16x32_bf16(pa0, vb,
                                                            oacc[0][cf], 0, 0, 0);
      oacc[1][cf] = __builtin_amdgcn_mfma_f32_16x16x32_bf16(pa1, vb,
                                                            oacc[1][cf], 0, 0, 0);
    }
  }

  // Deferred lsum: butterfly over the 16-lane i-groups.
#pragma unroll
  for (int jf = 0; jf < 2; jf++)
#pragma unroll
    for (int r = 0; r < 4; r++) {
      plsum[jf][r] += __shfl_xor(plsum[jf][r], 1);
      plsum[jf][r] += __shfl_xor(plsum[jf][r], 2);
      plsum[jf][r] += __shfl_xor(plsum[jf][r], 4);
      plsum[jf][r] += __shfl_xor(plsum[jf][r], 8);
    }

  // Merge ch-pairs (complementary i-subhalves) through LDS, then write
  // unnormalized O-partials (bf16) + lsum partials (fp32).
  __syncthreads();  // loop LDS dead; safe to alias
  float* ex = (float*)ldsb;             // [4 jq][32 j][256 c]
  float* exl = (float*)(ldsb + 131072); // [4 jq][32 j]
  if (ch == 1) {
    float* exw = ex + jq * 8192;
#pragma unroll
    for (int jf = 0; jf < 2; jf++) {
#pragma unroll
      for (int cf = 0; cf < 16; cf++)
#pragma unroll
        for (int r = 0; r < 4; r++)
          exw[(jf * 16 + g * 4 + r) * 256 + cf * 16 + rl] = oacc[jf][cf][r];
      if (rl == 0) {
#pragma unroll
        for (int r = 0; r < 4; r++)
          exl[jq * 32 + jf * 16 + g * 4 + r] = plsum[jf][r];
      }
    }
  }
  __syncthreads();
  if (ch == 0) {
    float* exw = ex + jq * 8192;
    unsigned short* op = oPart + (long)ob * 1048576;
#pragma unroll
    for (int jf = 0; jf < 2; jf++) {
      if (rl == 0) {
#pragma unroll
        for (int r = 0; r < 4; r++) {
          const int jl = jq * 32 + jf * 16 + g * 4 + r;
          lPart[(long)ob * 4096 + j0 + jl] = plsum[jf][r] + exl[jl];
        }
      }
#pragma unroll
      for (int cf = 0; cf < 16; cf++)
#pragma unroll
        for (int r = 0; r < 4; r++) {
          const int jl2 = jf * 16 + g * 4 + r;
          op[(long)(j0 + jq * 32 + jl2) * 256 + cf * 16 + rl] =
              f2bf(oacc[jf][cf][r] + exw[jl2 * 256 + cf * 16 + rl]);
        }
    }
  }
#undef STAGE_QV
}

// ---------------------------------------------------------------------------
// prep_all: convert6 (blocks [0,1536)) U embed_k ([1536,5632)) U transpose_x
// ([5632,9728)). Independent work; branch is block-uniform.
// ---------------------------------------------------------------------------
__global__ __launch_bounds__(256) void prep_all(
    const float* __restrict__ a0, const float* __restrict__ a1,
    const float* __restrict__ a2, const float* __restrict__ a3,
    const float* __restrict__ a4, const float* __restrict__ a5,
    unsigned short* __restrict__ wdst, unsigned short* __restrict__ emb,
    const float* __restrict__ x, unsigned short* __restrict__ xt) {
  __shared__ float tile[32][33];
  const int bid = blockIdx.x;
  const int t = threadIdx.x;
  if (bid < 1536) {
    // convert6: six 256x256 fp32 weights -> contiguous bf16.
    int idx = bid * 256 + t;
    int m = idx >> 16, r = idx & 65535;
    const float* s;
    switch (m) {
      case 0: s = a0; break;
      case 1: s = a1; break;
      case 2: s = a2; break;
      case 3: s = a3; break;
      case 4: s = a4; break;
      default: s = a5; break;
    }
    wdst[idx] = f2bf(s[r]);
  } else if (bid < 5632) {
    // embed: e[t,d] = sin/cos(t * 10000^(-d/128)).
    int idx = (bid - 1536) * 256 + t;
    int tt_ = idx >> 8, d = idx & 255;
    float freq = exp2f((float)d * -0.10381025296573598f);
    float w = (float)tt_ * freq;
    float sn, cs;
    __sincosf(w, &sn, &cs);
    emb[idx] = f2bf((d & 1) ? cs : sn);
  } else {
    // transpose_x: x [4][256][4096] fp32 -> XT [4][4096][256] bf16.
    const int bid2 = bid - 5632;
    const int s0 = (bid2 & 127) * 32, c0 = ((bid2 >> 7) & 7) * 32;
    const int b = bid2 >> 10;
    const int tx = t & 31, ty = t >> 5;
    const float* xb = x + (long)b * 256 * 4096;
#pragma unroll
    for (int r = 0; r < 32; r += 8)
      tile[ty + r][tx] = xb[(long)(c0 + ty + r) * 4096 + s0 + tx];
    __syncthreads();
    unsigned short* xtb = xt + (long)b * 4096 * 256;
#pragma unroll
    for (int r = 0; r < 32; r += 8)
      xtb[(long)(s0 + ty + r) * 256 + c0 + tx] = f2bf(tile[tx][ty + r]);
  }
}

// ---------------------------------------------------------------------------
extern "C" void kernel_launch(void* const* d_in, const int* in_sizes, int n_in,
                              void* d_out, int out_size, void* d_ws,
                              size_t ws_size, hipStream_t stream) {
  const float* x  = (const float*)d_in[0];
  const float* wq = (const float*)d_in[1];
  const float* bq = (const float*)d_in[2];
  const float* wk = (const float*)d_in[3];
  const float* bk = (const float*)d_in[4];
  const float* wv = (const float*)d_in[5];
  const float* bv = (const float*)d_in[6];
  const float* wo = (const float*)d_in[7];
  const float* bo = (const float*)d_in[8];
  const float* w1 = (const float*)d_in[9];
  const float* b1 = (const float*)d_in[10];
  const float* w2 = (const float*)d_in[11];
  const float* b2 = (const float*)d_in[12];
  float* out = (float*)d_out;

  char* ws = (char*)d_ws;
  unsigned short* wqb = (unsigned short*)(ws + 0);         // 6x 256x256 bf16
  unsigned short* wkb = (unsigned short*)(ws + 131072);
  unsigned short* wvb = (unsigned short*)(ws + 262144);
  unsigned short* wob = (unsigned short*)(ws + 393216);
  unsigned short* w1b = (unsigned short*)(ws + 524288);
  unsigned short* w2b = (unsigned short*)(ws + 655360);
  unsigned short* emb = (unsigned short*)(ws + 786432);    // [4096][256] bf16
  unsigned short* peB = (unsigned short*)(ws + 4980736);   // [4096][256] bf16
  unsigned short* XT  = (unsigned short*)(ws + 9175040);   // [4][4096][256]
  unsigned short* qT  = (unsigned short*)(ws + 17563648);  // [4][4096][256]
  unsigned short* kT  = (unsigned short*)(ws + 25952256);  // [4][4096][256]
  unsigned short* vB  = (unsigned short*)(ws + 34340864);  // [4][256][4096]
  unsigned short* oP  = (unsigned short*)(ws + 51118080);  // [8][4096][256] bf16
  float*          lP  = (float*)(ws + 84672512);           // [8][4096] f32
  (void)ws_size; (void)in_sizes; (void)n_in; (void)out_size;

  const dim3 B256(256);

  // convert6 U embed U transpose_x (independent; one launch).
  prep_all<<<9728, B256, 0, stream>>>(wq, wk, wv, wo, w1, w2, wqb, emb, x, XT);
  // Fused pe MLP (both layers, h1 via LDS): peB = mlp(embed)  (bf16 out).
  mlp_pe<<<64, B256, 0, stream>>>(emb, w1b, w2b, b1, b2, peB);
  // Fused q+k+v projections (ONE XT staging, v stored transposed; pe bf16).
  gemm_qkv<<<dim3(32, 2, 4), dim3(512), 0, stream>>>(
      XT, wqb, wkb, wvb, qT, kT, vB, bq, bk, bv, peB);
  // Fused attention: logits + softmax(axis i) + PV; i split across 2 blocks.
  flash_attn<<<256, dim3(512), 0, stream>>>(qT, kT, vB, oP, lP);
  // Output projection with fused i-half combine (oP bf16, read once).
  gemm_out_f<<<dim3(1, 64, 4), B256, 0, stream>>>(wob, oP, lP, bo, out);
}

// Round 18
// 139.010 us; speedup vs baseline: 1.3003x; 1.0024x over previous
//
#include <hip/hip_runtime.h>
#include <cstdint>

// ---------------------------------------------------------------------------
// SAGAN self-attention block, bf16-MFMA pipeline, flash-fused attention.
// GEMMs are NT form: C[m,n] = sum_k Arow[m][k] * Brow[n][k].
// Verified fragment conventions (R2-passing gemm, 16x16x32):
//   A-frag: lane holds A[row = lane&15][k = (lane>>4)*8 + q], q=0..7
//   B-frag: lane holds B[col = lane&15][k = (lane>>4)*8 + q]
//   C/D:    lane holds C[row = (lane>>4)*4 + r][col = lane&15], r=0..3
// R17 post-mortem: 2-blocks/CU flash variant is register-infeasible (unified
// VGPR/AGPR file: oacc+kreg alone = the whole CU register file at 16 waves).
// Flash v5 (93.5us) is the measured structural champion — frozen.
// ---------------------------------------------------------------------------

typedef short s8v __attribute__((ext_vector_type(8)));   // 8 bf16 bits (4 VGPR)
typedef float f32x4 __attribute__((ext_vector_type(4)));

#define DEVI static __device__ __forceinline__

DEVI unsigned short f2bf(float f) {
  union { float f; uint32_t u; } x; x.f = f;
  uint32_t u = x.u;
  return (unsigned short)((u + 0x7fffu + ((u >> 16) & 1u)) >> 16);  // RNE
}

DEVI float bf2f(unsigned short u) {
  union { uint32_t u; float f; } x;
  x.u = (uint32_t)u << 16;
  return x.f;
}

DEVI void gl_lds16(const void* g, void* l) {
  // async global->LDS, 16B per lane; LDS dest must be wave-uniform base.
  __builtin_amdgcn_global_load_lds(
      (const __attribute__((address_space(1))) void*)g,
      (__attribute__((address_space(3))) void*)l,
      16, 0, 0);
}

// Stage a [64 rows][32 k] bf16 tile (4KB), linear LDS layout. t in 0..255.
DEVI void stage(const unsigned short* src, int ld, unsigned short* lds, int t) {
  gl_lds16(src + (long)(t >> 2) * ld + (t & 3) * 8, lds + (t >> 6) * 512);
}

// ---------------------------------------------------------------------------
// Fused positional-embedding MLP: ONE kernel, h1 never leaves LDS.
// ---------------------------------------------------------------------------
__global__ __launch_bounds__(256) void mlp_pe(
    const unsigned short* __restrict__ emb, const unsigned short* __restrict__ w1b,
    const unsigned short* __restrict__ w2b, const float* __restrict__ b1,
    const float* __restrict__ b2, unsigned short* __restrict__ peB) {
  const int m0 = blockIdx.x * 64;
  __shared__ __align__(16) unsigned short As[2048];   // [64][32]
  __shared__ __align__(16) unsigned short Bs[8192];   // [256 n][32]
  __shared__ __align__(16) unsigned short h1L[16896]; // [64][264] padded
  const int t = threadIdx.x;
  const int wave = t >> 6, lane = t & 63;
  const int wc = wave;  // n-quarter
  const int rl = lane & 15, g = lane >> 4, kp = g * 8;

  // ---- Phase 1: h1 = silu(emb @ w1^T + b1), 64 x 256 ----
  f32x4 acc[4][4];
#pragma unroll
  for (int i = 0; i < 4; i++)
#pragma unroll
    for (int j = 0; j < 4; j++) acc[i][j] = f32x4{0.f, 0.f, 0.f, 0.f};

  for (int k0 = 0; k0 < 256; k0 += 32) {
    stage(emb + (long)m0 * 256 + k0, 256, As, t);
#pragma unroll
    for (int q = 0; q < 4; q++)
      stage(w1b + (long)(q * 64) * 256 + k0, 256, Bs + q * 2048, t);
    __syncthreads();

    s8v af[4], bfr[4];
#pragma unroll
    for (int i = 0; i < 4; i++)
      af[i] = *(const s8v*)(As + (i * 16 + rl) * 32 + kp);
#pragma unroll
    for (int j = 0; j < 4; j++)
      bfr[j] = *(const s8v*)(Bs + (wc * 64 + j * 16 + rl) * 32 + kp);
#pragma unroll
    for (int i = 0; i < 4; i++)
#pragma unroll
      for (int j = 0; j < 4; j++)
        acc[i][j] = __builtin_amdgcn_mfma_f32_16x16x32_bf16(af[i], bfr[j],
                                                            acc[i][j], 0, 0, 0);
    __syncthreads();
  }

#pragma unroll
  for (int i = 0; i < 4; i++) {
    const int r0 = i * 16 + g * 4;
#pragma unroll
    for (int j = 0; j < 4; j++) {
      const int col = wc * 64 + j * 16 + rl;
      const float bc = b1[col];
#pragma unroll
      for (int r = 0; r < 4; r++) {
        float val = acc[i][j][r] + bc;
        val = val / (1.0f + __expf(-val));
        h1L[(r0 + r) * 264 + col] = f2bf(val);
      }
    }
  }

  // ---- Phase 2: peB = h1 @ w2^T + b2, 64 x 256 ----
  f32x4 ac2[4][4];
#pragma unroll
  for (int i = 0; i < 4; i++)
#pragma unroll
    for (int j = 0; j < 4; j++) ac2[i][j] = f32x4{0.f, 0.f, 0.f, 0.f};

  for (int k0 = 0; k0 < 256; k0 += 32) {
#pragma unroll
    for (int q = 0; q < 4; q++)
      stage(w2b + (long)(q * 64) * 256 + k0, 256, Bs + q * 2048, t);
    __syncthreads();  // also guards h1L writes (lgkmcnt drained at barrier)

    s8v af[4], bfr[4];
#pragma unroll
    for (int i = 0; i < 4; i++)
      af[i] = *(const s8v*)(h1L + (i * 16 + rl) * 264 + k0 + kp);
#pragma unroll
    for (int j = 0; j < 4; j++)
      bfr[j] = *(const s8v*)(Bs + (wc * 64 + j * 16 + rl) * 32 + kp);
#pragma unroll
    for (int i = 0; i < 4; i++)
#pragma unroll
      for (int j = 0; j < 4; j++)
        ac2[i][j] = __builtin_amdgcn_mfma_f32_16x16x32_bf16(af[i], bfr[j],
                                                            ac2[i][j], 0, 0, 0);
    __syncthreads();
  }

#pragma unroll
  for (int i = 0; i < 4; i++) {
    const int r0 = m0 + i * 16 + g * 4;
#pragma unroll
    for (int j = 0; j < 4; j++) {
      const int col = wc * 64 + j * 16 + rl;
      const float bc = b2[col];
#pragma unroll
      for (int r = 0; r < 4; r++)
        peB[(long)(r0 + r) * 256 + col] = f2bf(ac2[i][j][r] + bc);
    }
  }
}

// ---------------------------------------------------------------------------
// Fused q+k+v projections (unchanged).
// ---------------------------------------------------------------------------
__global__ __launch_bounds__(512) void gemm_qkv(
    const unsigned short* __restrict__ XT, const unsigned short* __restrict__ wqb,
    const unsigned short* __restrict__ wkb, const unsigned short* __restrict__ wvb,
    unsigned short* __restrict__ qT, unsigned short* __restrict__ kT,
    unsigned short* __restrict__ vB, const float* __restrict__ bq,
    const float* __restrict__ bk, const float* __restrict__ bv,
    const unsigned short* __restrict__ pe) {
  const int bz = blockIdx.z;
  const unsigned short* Ab = XT + (long)bz * 1048576;
  const int m0 = blockIdx.x * 128, n0 = blockIdx.y * 128;
  __shared__ __align__(16) unsigned short As[4096], Bq[4096], Bk[4096],
      Bv[4096];
  const int t = threadIdx.x;
  const int wave = t >> 6, lane = t & 63;
  const int wm = wave >> 2, wn = wave & 3;
  const int rl = lane & 15, kp = (lane >> 4) * 8;
  const int th = t >> 8, tt = t & 255;  // staging split: th picks tile half

  f32x4 aq[4][2], ak[4][2], av[4][2];
#pragma unroll
  for (int i = 0; i < 4; i++)
#pragma unroll
    for (int j = 0; j < 2; j++) {
      aq[i][j] = f32x4{0.f, 0.f, 0.f, 0.f};
      ak[i][j] = f32x4{0.f, 0.f, 0.f, 0.f};
      av[i][j] = f32x4{0.f, 0.f, 0.f, 0.f};
    }

  for (int k0 = 0; k0 < 256; k0 += 32) {
    const long ro = (long)(th * 64) * 256 + k0;
    stage(Ab + (long)m0 * 256 + ro, 256, As + th * 2048, tt);
    stage(wqb + (long)n0 * 256 + ro, 256, Bq + th * 2048, tt);
    stage(wkb + (long)n0 * 256 + ro, 256, Bk + th * 2048, tt);
    stage(wvb + (long)n0 * 256 + ro, 256, Bv + th * 2048, tt);
    __syncthreads();

    s8v af[4], b0[2], b1v[2], b2v[2];
#pragma unroll
    for (int i = 0; i < 4; i++)
      af[i] = *(const s8v*)(As + (wm * 64 + i * 16 + rl) * 32 + kp);
#pragma unroll
    for (int j = 0; j < 2; j++) {
      b0[j] = *(const s8v*)(Bq + (wn * 32 + j * 16 + rl) * 32 + kp);
      b1v[j] = *(const s8v*)(Bk + (wn * 32 + j * 16 + rl) * 32 + kp);
      b2v[j] = *(const s8v*)(Bv + (wn * 32 + j * 16 + rl) * 32 + kp);
    }
#pragma unroll
    for (int i = 0; i < 4; i++)
#pragma unroll
      for (int j = 0; j < 2; j++) {
        aq[i][j] = __builtin_amdgcn_mfma_f32_16x16x32_bf16(af[i], b0[j],
                                                           aq[i][j], 0, 0, 0);
        ak[i][j] = __builtin_amdgcn_mfma_f32_16x16x32_bf16(af[i], b1v[j],
                                                           ak[i][j], 0, 0, 0);
        av[i][j] = __builtin_amdgcn_mfma_f32_16x16x32_bf16(af[i], b2v[j],
                                                           av[i][j], 0, 0, 0);
      }
    __syncthreads();
  }

  const long cb = (long)bz * 1048576;
#pragma unroll
  for (int i = 0; i < 4; i++) {
    const int row0 = m0 + wm * 64 + i * 16 + (lane >> 4) * 4;
#pragma unroll
    for (int j = 0; j < 2; j++) {
      const int col = n0 + wn * 32 + j * 16 + rl;
      const ushort4 p4 = *(const ushort4*)(pe + (long)col * 4096 + row0);
      const float bqc = bq[col], bkc = bk[col], bvc = bv[col];
      ushort4 vpk;
      const float pv[4] = {bf2f(p4.x), bf2f(p4.y), bf2f(p4.z), bf2f(p4.w)};
#pragma unroll
      for (int r = 0; r < 4; r++) {
        const int row = row0 + r;
        qT[cb + (long)row * 256 + col] = f2bf(aq[i][j][r] + bqc + pv[r]);
        kT[cb + (long)row * 256 + col] = f2bf(ak[i][j][r] + bkc + pv[r]);
      }
      vpk.x = f2bf(av[i][j][0] + bvc + pv[0]);
      vpk.y = f2bf(av[i][j][1] + bvc + pv[1]);
      vpk.z = f2bf(av[i][j][2] + bvc + pv[2]);
      vpk.w = f2bf(av[i][j][3] + bvc + pv[3]);
      *(ushort4*)(vB + cb + (long)col * 4096 + row0) = vpk;
    }
  }
}

// ---------------------------------------------------------------------------
// Output projection with FUSED i-half combine (two bf16 oP planes).
// ---------------------------------------------------------------------------
__global__ __launch_bounds__(256) void gemm_out_f(
    const unsigned short* __restrict__ wob,
    const unsigned short* __restrict__ oPart, const float* __restrict__ lPart,
    const float* __restrict__ bo, float* __restrict__ out) {
  const int bz = blockIdx.z;          // batch
  const int n0 = blockIdx.y * 64;     // j cols (64 per block)
  __shared__ __align__(16) unsigned short As[8192], Bs[2048];
  // As: [4 tiles][64 m][32 k] = 256 o-rows; Bs: [64 j][32 k]
  const int t = threadIdx.x;
  const int wave = t >> 6, lane = t & 63;
  const int rl = lane & 15, kp = (lane >> 4) * 8;
  const int tr = t >> 2, tc8 = (t & 3) * 8;  // B fold: row 0..63, chunk

  f32x4 acc[4][4];
#pragma unroll
  for (int i = 0; i < 4; i++)
#pragma unroll
    for (int j = 0; j < 4; j++) acc[i][j] = f32x4{0.f, 0.f, 0.f, 0.f};

  const int j_ = n0 + tr;  // this thread's fixed fold row
  const float* l0p = lPart + (long)(bz * 2) * 4096;
  const float* l1p = lPart + (long)(bz * 2 + 1) * 4096;
  const float inv = 1.0f / (l0p[j_] + l1p[j_]);
  const unsigned short* oP0 = oPart + (long)(bz * 2) * 1048576;
  const unsigned short* oP1 = oPart + (long)(bz * 2 + 1) * 1048576;

  for (int k0 = 0; k0 < 256; k0 += 32) {
#pragma unroll
    for (int s_ = 0; s_ < 4; s_++)
      stage(wob + (long)(s_ * 64) * 256 + k0, 256, As + s_ * 2048, t);
    // B fold: resT row j_, c-chunk [k0+tc8, +8) from the 2 bf16 planes.
    {
      const s8v a8 = *(const s8v*)(oP0 + (long)j_ * 256 + k0 + tc8);
      const s8v d8 = *(const s8v*)(oP1 + (long)j_ * 256 + k0 + tc8);
      s8v pk;
#pragma unroll
      for (int e = 0; e < 8; e++)
        pk[e] = (short)f2bf((bf2f((unsigned short)a8[e]) +
                             bf2f((unsigned short)d8[e])) * inv);
      *(s8v*)(Bs + tr * 32 + tc8) = pk;
    }
    __syncthreads();  // drains vmcnt (A gl_lds) + lgkmcnt (B ds_write)

    s8v af[4], bfr[4];
#pragma unroll
    for (int i = 0; i < 4; i++)
      af[i] = *(const s8v*)(As + (wave * 64 + i * 16 + rl) * 32 + kp);
#pragma unroll
    for (int j = 0; j < 4; j++)
      bfr[j] = *(const s8v*)(Bs + (j * 16 + rl) * 32 + kp);
#pragma unroll
    for (int i = 0; i < 4; i++)
#pragma unroll
      for (int j = 0; j < 4; j++)
        acc[i][j] = __builtin_amdgcn_mfma_f32_16x16x32_bf16(af[i], bfr[j],
                                                            acc[i][j], 0, 0, 0);
    __syncthreads();
  }

  const long cb = (long)bz * 1048576;
#pragma unroll
  for (int i = 0; i < 4; i++) {
    const int r0 = wave * 64 + i * 16 + (lane >> 4) * 4;
#pragma unroll
    for (int j = 0; j < 4; j++) {
      const int col = n0 + j * 16 + (lane & 15);
#pragma unroll
      for (int r = 0; r < 4; r++) {
        const int row = r0 + r;
        out[cb + (long)row * 4096 + col] = acc[i][j][r] + bo[row];
      }
    }
  }
}

// ---------------------------------------------------------------------------
// Flash-fused attention v5 (champion; bf16 oPart). FROZEN.
// ---------------------------------------------------------------------------
__global__ __launch_bounds__(512, 2) void flash_attn(
    const unsigned short* __restrict__ qTp, const unsigned short* __restrict__ kTp,
    const unsigned short* __restrict__ vBp, unsigned short* __restrict__ oPart,
    float* __restrict__ lPart) {
  const int bid = blockIdx.x;
  // XCD-aware mapping: xcd = bid&7 -> (b, ihalf); per-XCD L2 set ~4MB.
  const int xcd = bid & 7;
  const int b = xcd >> 1, ihalf = xcd & 1;
  const int j0 = (bid >> 3) * 128;
  const long S = 1048576;
  const long ibase = (long)ihalf * 2048;
  const unsigned short* q = qTp + (long)b * S;
  const unsigned short* k = kTp + (long)b * S;
  const unsigned short* v = vBp + (long)b * S;
  const int ob = b * 2 + ihalf;  // output plane

  // LDS: [0,64K) qL dbuf, [64K,128K) vL dbuf, [128K, +20480) pL.
  // Epilogue aliases: [0,128K) = O exchange (fp32), [128K,+512) = lsum exch.
  __shared__ __align__(16) unsigned char ldsb[151552];

  const int t = threadIdx.x;
  const int wave = t >> 6, lane = t & 63;
  const int jq = wave & 3, ch = wave >> 2;
  const int rl = lane & 15, g = lane >> 4;
  const int kp = g * 8;
  const int ksw = ((g ^ ((rl >> 1) & 3)) << 3);          // swizzled k-offset
  const int th = t >> 8, tt = t & 255;                   // staging split
  unsigned short* pL = (unsigned short*)(ldsb + 131072);
  unsigned short* pLw = pL + wave * 1280;                // [2 jf][16 j][40]

  // K-strip -> registers: wave owns rows j0 + jq*32 + jf*16 + rl.
  const unsigned short* krow = k + (long)(j0 + jq * 32 + rl) * 256 + kp;
  s8v kreg[2][8];
#pragma unroll
  for (int jf = 0; jf < 2; jf++)
#pragma unroll
    for (int s = 0; s < 8; s++)
      kreg[jf][s] = *(const s8v*)(krow + jf * 16 * 256 + s * 32);

  f32x4 oacc[2][16];
#pragma unroll
  for (int jf = 0; jf < 2; jf++)
#pragma unroll
    for (int cf = 0; cf < 16; cf++) oacc[jf][cf] = f32x4{0.f, 0.f, 0.f, 0.f};
  float plsum[2][4] = {{0.f, 0.f, 0.f, 0.f}, {0.f, 0.f, 0.f, 0.f}};

  // Pre-swizzled, pre-offset staging pointers (bumped per iter; source
  // swizzle: slot chunk c holds global chunk c ^ ((row>>1)&3); LDS linear).
  const int tr = tt >> 2, tc = tt & 3;
  const int sc = (tc ^ ((tr >> 1) & 3)) * 8;
  const unsigned short* qsrc[4];
  const unsigned short* vsrc[4];
  const int dsto = (tt >> 6) * 512;  // wave-uniform LDS sub-offset
#pragma unroll
  for (int ss = 0; ss < 4; ss++) {
    const int s_ = ss * 2 + th;
    qsrc[ss] = q + ibase * 256 + s_ * 32 + (long)tr * 256 + sc;
    vsrc[ss] = v + (long)((s_ >> 1) * 64) * 4096 + ibase + (s_ & 1) * 32 +
               (long)tr * 4096 + sc;
  }

#define STAGE_QV(bufsel)                                                     \
  {                                                                          \
    unsigned short* qD = (unsigned short*)(ldsb + ((bufsel) << 15));         \
    unsigned short* vD = (unsigned short*)(ldsb + 65536 + ((bufsel) << 15)); \
    _Pragma("unroll") for (int ss = 0; ss < 4; ss++) {                       \
      const int s_ = ss * 2 + th;                                            \
      gl_lds16(qsrc[ss], qD + s_ * 2048 + dsto);                             \
      gl_lds16(vsrc[ss], vD + s_ * 2048 + dsto);                             \
      qsrc[ss] += 16384;  /* next i-tile: +64*256 elems */                   \
      vsrc[ss] += 64;     /* next i-tile: +64 elems     */                   \
    }                                                                        \
  }

  STAGE_QV(0)

  for (int n = 0; n < 32; ++n) {
    const int cur = n & 1;
    __syncthreads();  // buf[cur] staged; all waves done with buf[cur^1]
    if (n + 1 < 32) STAGE_QV(cur ^ 1)  // overlaps with compute

    const unsigned short* qLb = (const unsigned short*)(ldsb + (cur << 15));
    const unsigned short* vLb =
        (const unsigned short*)(ldsb + 65536 + (cur << 15));

    // QK^T: own i-subhalf (32 i): 16 B-frag reads, 32 MFMA (2 jf x 2 if x 8s).
    f32x4 sa[2][2];
#pragma unroll
    for (int jf = 0; jf < 2; jf++)
#pragma unroll
      for (int f = 0; f < 2; f++) sa[jf][f] = f32x4{0.f, 0.f, 0.f, 0.f};
    const unsigned short* qbase = qLb + (ch * 32 + rl) * 32 + ksw;
#pragma unroll
    for (int s = 0; s < 8; s++) {
#pragma unroll
      for (int f = 0; f < 2; f++) {
        s8v bf = *(const s8v*)(qbase + s * 2048 + f * 512);
        sa[0][f] = __builtin_amdgcn_mfma_f32_16x16x32_bf16(kreg[0][s], bf,
                                                           sa[0][f], 0, 0, 0);
        sa[1][f] = __builtin_amdgcn_mfma_f32_16x16x32_bf16(kreg[1][s], bf,
                                                           sa[1][f], 0, 0, 0);
      }
    }

    // Static-max softmax (|logit| << 88), deferred lsum; P -> wave-private
    // LDS in A-frag layout, padded row stride 40 (<=2-way conflicts).
#pragma unroll
    for (int jf = 0; jf < 2; jf++)
#pragma unroll
      for (int f = 0; f < 2; f++)
#pragma unroll
        for (int r = 0; r < 4; r++) {
          const float p = __expf(sa[jf][f][r] * 0.0625f);
          plsum[jf][r] += p;
          pLw[jf * 640 + (g * 4 + r) * 40 + f * 16 + rl] = f2bf(p);
        }

    // PV over own i-subhalf (K=32): 16 v-frag reads, 32 MFMA (16 cf x 2 jf).
    s8v pa0 = *(const s8v*)(pLw + rl * 40 + kp);
    s8v pa1 = *(const s8v*)(pLw + 640 + rl * 40 + kp);
    const unsigned short* vbase = vLb + ch * 2048 + rl * 32 + ksw;
#pragma unroll
    for (int cf = 0; cf < 16; cf++) {
      s8v vb = *(const s8v*)(vbase + (cf >> 2) * 4096 + (cf & 3) * 512);
      oacc[0][cf] = __builtin_amdgcn_mfma_f32_16x16x32_bf16(pa0, vb,
                                                            oacc[0][cf], 0, 0, 0);
      oacc[1][cf] = __builtin_amdgcn_mfma_f32_16x16x32_bf16(pa1, vb,
                                                            oacc[1][cf], 0, 0, 0);
    }
  }

  // Deferred lsum: butterfly over the 16-lane i-groups.
#pragma unroll
  for (int jf = 0; jf < 2; jf++)
#pragma unroll
    for (int r = 0; r < 4; r++) {
      plsum[jf][r] += __shfl_xor(plsum[jf][r], 1);
      plsum[jf][r] += __shfl_xor(plsum[jf][r], 2);
      plsum[jf][r] += __shfl_xor(plsum[jf][r], 4);
      plsum[jf][r] += __shfl_xor(plsum[jf][r], 8);
    }

  // Merge ch-pairs (complementary i-subhalves) through LDS, then write
  // unnormalized O-partials (bf16) + lsum partials (fp32).
  __syncthreads();  // loop LDS dead; safe to alias
  float* ex = (float*)ldsb;             // [4 jq][32 j][256 c]
  float* exl = (float*)(ldsb + 131072); // [4 jq][32 j]
  if (ch == 1) {
    float* exw = ex + jq * 8192;
#pragma unroll
    for (int jf = 0; jf < 2; jf++) {
#pragma unroll
      for (int cf = 0; cf < 16; cf++)
#pragma unroll
        for (int r = 0; r < 4; r++)
          exw[(jf * 16 + g * 4 + r) * 256 + cf * 16 + rl] = oacc[jf][cf][r];
      if (rl == 0) {
#pragma unroll
        for (int r = 0; r < 4; r++)
          exl[jq * 32 + jf * 16 + g * 4 + r] = plsum[jf][r];
      }
    }
  }
  __syncthreads();
  if (ch == 0) {
    float* exw = ex + jq * 8192;
    unsigned short* op = oPart + (long)ob * 1048576;
#pragma unroll
    for (int jf = 0; jf < 2; jf++) {
      if (rl == 0) {
#pragma unroll
        for (int r = 0; r < 4; r++) {
          const int jl = jq * 32 + jf * 16 + g * 4 + r;
          lPart[(long)ob * 4096 + j0 + jl] = plsum[jf][r] + exl[jl];
        }
      }
#pragma unroll
      for (int cf = 0; cf < 16; cf++)
#pragma unroll
        for (int r = 0; r < 4; r++) {
          const int jl2 = jf * 16 + g * 4 + r;
          op[(long)(j0 + jq * 32 + jl2) * 256 + cf * 16 + rl] =
              f2bf(oacc[jf][cf][r] + exw[jl2 * 256 + cf * 16 + rl]);
        }
    }
  }
#undef STAGE_QV
}

// ---------------------------------------------------------------------------
// prep_all: convert6 (blocks [0,1536)) U embed_k ([1536,5632)) U transpose_x
// ([5632,9728)). Independent work; branch is block-uniform.
// ---------------------------------------------------------------------------
__global__ __launch_bounds__(256) void prep_all(
    const float* __restrict__ a0, const float* __restrict__ a1,
    const float* __restrict__ a2, const float* __restrict__ a3,
    const float* __restrict__ a4, const float* __restrict__ a5,
    unsigned short* __restrict__ wdst, unsigned short* __restrict__ emb,
    const float* __restrict__ x, unsigned short* __restrict__ xt) {
  __shared__ float tile[32][33];
  const int bid = blockIdx.x;
  const int t = threadIdx.x;
  if (bid < 1536) {
    // convert6: six 256x256 fp32 weights -> contiguous bf16.
    int idx = bid * 256 + t;
    int m = idx >> 16, r = idx & 65535;
    const float* s;
    switch (m) {
      case 0: s = a0; break;
      case 1: s = a1; break;
      case 2: s = a2; break;
      case 3: s = a3; break;
      case 4: s = a4; break;
      default: s = a5; break;
    }
    wdst[idx] = f2bf(s[r]);
  } else if (bid < 5632) {
    // embed: e[t,d] = sin/cos(t * 10000^(-d/128)).
    int idx = (bid - 1536) * 256 + t;
    int tt_ = idx >> 8, d = idx & 255;
    float freq = exp2f((float)d * -0.10381025296573598f);
    float w = (float)tt_ * freq;
    float sn, cs;
    __sincosf(w, &sn, &cs);
    emb[idx] = f2bf((d & 1) ? cs : sn);
  } else {
    // transpose_x: x [4][256][4096] fp32 -> XT [4][4096][256] bf16.
    const int bid2 = bid - 5632;
    const int s0 = (bid2 & 127) * 32, c0 = ((bid2 >> 7) & 7) * 32;
    const int b = bid2 >> 10;
    const int tx = t & 31, ty = t >> 5;
    const float* xb = x + (long)b * 256 * 4096;
#pragma unroll
    for (int r = 0; r < 32; r += 8)
      tile[ty + r][tx] = xb[(long)(c0 + ty + r) * 4096 + s0 + tx];
    __syncthreads();
    unsigned short* xtb = xt + (long)b * 4096 * 256;
#pragma unroll
    for (int r = 0; r < 32; r += 8)
      xtb[(long)(s0 + ty + r) * 256 + c0 + tx] = f2bf(tile[tx][ty + r]);
  }
}

// ---------------------------------------------------------------------------
extern "C" void kernel_launch(void* const* d_in, const int* in_sizes, int n_in,
                              void* d_out, int out_size, void* d_ws,
                              size_t ws_size, hipStream_t stream) {
  const float* x  = (const float*)d_in[0];
  const float* wq = (const float*)d_in[1];
  const float* bq = (const float*)d_in[2];
  const float* wk = (const float*)d_in[3];
  const float* bk = (const float*)d_in[4];
  const float* wv = (const float*)d_in[5];
  const float* bv = (const float*)d_in[6];
  const float* wo = (const float*)d_in[7];
  const float* bo = (const float*)d_in[8];
  const float* w1 = (const float*)d_in[9];
  const float* b1 = (const float*)d_in[10];
  const float* w2 = (const float*)d_in[11];
  const float* b2 = (const float*)d_in[12];
  float* out = (float*)d_out;

  char* ws = (char*)d_ws;
  unsigned short* wqb = (unsigned short*)(ws + 0);         // 6x 256x256 bf16
  unsigned short* wkb = (unsigned short*)(ws + 131072);
  unsigned short* wvb = (unsigned short*)(ws + 262144);
  unsigned short* wob = (unsigned short*)(ws + 393216);
  unsigned short* w1b = (unsigned short*)(ws + 524288);
  unsigned short* w2b = (unsigned short*)(ws + 655360);
  unsigned short* emb = (unsigned short*)(ws + 786432);    // [4096][256] bf16
  unsigned short* peB = (unsigned short*)(ws + 4980736);   // [4096][256] bf16
  unsigned short* XT  = (unsigned short*)(ws + 9175040);   // [4][4096][256]
  unsigned short* qT  = (unsigned short*)(ws + 17563648);  // [4][4096][256]
  unsigned short* kT  = (unsigned short*)(ws + 25952256);  // [4][4096][256]
  unsigned short* vB  = (unsigned short*)(ws + 34340864);  // [4][256][4096]
  unsigned short* oP  = (unsigned short*)(ws + 51118080);  // [8][4096][256] bf16
  float*          lP  = (float*)(ws + 84672512);           // [8][4096] f32
  (void)ws_size; (void)in_sizes; (void)n_in; (void)out_size;

  const dim3 B256(256);

  // convert6 U embed U transpose_x (independent; one launch).
  prep_all<<<9728, B256, 0, stream>>>(wq, wk, wv, wo, w1, w2, wqb, emb, x, XT);
  // Fused pe MLP (both layers, h1 via LDS): peB = mlp(embed)  (bf16 out).
  mlp_pe<<<64, B256, 0, stream>>>(emb, w1b, w2b, b1, b2, peB);
  // Fused q+k+v projections (ONE XT staging, v stored transposed; pe bf16).
  gemm_qkv<<<dim3(32, 2, 4), dim3(512), 0, stream>>>(
      XT, wqb, wkb, wvb, qT, kT, vB, bq, bk, bv, peB);
  // Fused attention: logits + softmax(axis i) + PV; i split across 2 blocks.
  flash_attn<<<256, dim3(512), 0, stream>>>(qT, kT, vB, oP, lP);
  // Output projection with fused i-half combine (oP bf16, read once).
  gemm_out_f<<<dim3(1, 64, 4), B256, 0, stream>>>(wob, oP, lP, bo, out);
}